// Round 13
// baseline (430.879 us; speedup 1.0000x reference)
//
#include <hip/hip_runtime.h>
#include <hip/hip_bf16.h>

#define NN   19
#define DIN  100
#define HID  128
#define TT   250
#define BB   64
#define NC   4
#define FEAT 2432          // NN*HID

typedef __attribute__((ext_vector_type(8))) short s8v;
typedef __attribute__((ext_vector_type(4))) float f4v;
typedef _Float16 h8v __attribute__((ext_vector_type(8)));
typedef _Float16 h4v __attribute__((ext_vector_type(4)));

// =============== V2 workspace layout (byte offsets) ===============
// BFI: W_ih MFMA B-frags f16  (19*8*4*4*512 halfs; per node 65536 halfs)
// BFH: W_hh MFMA B-frags f16  (same count)
// BIAS: combined b_ih+b_hh f32 (19*512)
// W1T: W1 transposed f32 (2432*128) ; HF: final hidden f32 (64*2432)
#define BFI_USH   1245184
#define V2_OFF_BFI  0ull
#define V2_OFF_BFH  2490368ull
#define V2_OFF_BIAS 4980736ull
#define V2_OFF_W1T  5019648ull
#define V2_OFF_HF   6264832ull
#define V2_NEED     6887424ull
#define PACK2_TOTAL (2*BFI_USH + 19*512 + FEAT*HID)

// =============== fallback (round-3) layout, float offsets =========
#define SZ_BF   (NN*8*4*8*512)
#define OFF_W1T_O (SZ_BF/2)
#define SZ_W1T  (FEAT*HID)
#define OFF_HF_O  (OFF_W1T_O + SZ_W1T)
#define PACK_TOTAL_O (SZ_BF + SZ_W1T)

__device__ __forceinline__ unsigned short f2bf(float x) {
    union { float f; unsigned u; } v; v.f = x;
    unsigned r = v.u + 0x7FFF + ((v.u >> 16) & 1);   // RNE
    return (unsigned short)(r >> 16);
}
#define LOG2E 1.4426950408889634f
__device__ __forceinline__ float sigf(float x) {
    return __builtin_amdgcn_rcpf(1.f + __builtin_amdgcn_exp2f(-LOG2E * x));
}
__device__ __forceinline__ float tnhf(float x) {
    return 1.f - 2.f * __builtin_amdgcn_rcpf(__builtin_amdgcn_exp2f(2.f * LOG2E * x) + 1.f);
}

// lgkm-only barrier: LDS ordered; global loads/stores stay in flight.
__device__ __forceinline__ void lgkm_barrier() {
    asm volatile("s_waitcnt lgkmcnt(0)" ::: "memory");
    __builtin_amdgcn_s_barrier();
    asm volatile("" ::: "memory");
}

// ======================= V2 kernels ===============================

// Pack W_ih frags, W_hh frags (f16), combined bias, W1T.
// Frag element (n, hb, nt, kt, lane, e) = W[k][g]:
// k = kt*32+(lane>>4)*8+e, g = nt*128+hb*16+(lane&15).
__global__ __launch_bounds__(256) void pack2_kernel(
        const float* __restrict__ W_ih, const float* __restrict__ W_hh,
        const float* __restrict__ b_ih, const float* __restrict__ b_hh,
        const float* __restrict__ W1, char* __restrict__ wsb) {
    int id = blockIdx.x * 256 + threadIdx.x;
    if (id < 2 * BFI_USH) {
        int which = id >= BFI_USH;                 // 0 = W_ih, 1 = W_hh
        int i = which ? id - BFI_USH : id;
        int e    = i & 7;
        int lane = (i >> 3) & 63;
        int kt   = (i >> 9) & 3;
        int nt   = (i >> 11) & 3;
        int hb   = (i >> 13) & 7;
        int n    = i >> 16;
        int k = kt * 32 + (lane >> 4) * 8 + e;
        int g = nt * 128 + hb * 16 + (lane & 15);
        float v;
        if (which) v = W_hh[((size_t)n * 512 + g) * HID + k];
        else       v = (k < DIN) ? W_ih[((size_t)n * 512 + g) * DIN + k] : 0.f;
        reinterpret_cast<_Float16*>(wsb)[id] = (_Float16)v;
        return;
    }
    int id2 = id - 2 * BFI_USH;
    if (id2 < NN * 512) {
        reinterpret_cast<float*>(wsb + V2_OFF_BIAS)[id2] = b_ih[id2] + b_hh[id2];
        return;
    }
    int id3 = id2 - NN * 512;
    if (id3 < FEAT * HID) {
        int j = id3 & 127, k = id3 >> 7;
        reinterpret_cast<float*>(wsb + V2_OFF_W1T)[id3] = W1[(size_t)j * FEAT + k];
    }
}

// Fused recurrence v10: PRODUCER/CONSUMER WAVE SPECIALIZATION.
// grid 152 = (n, batch-octet), 1024 thr = 16 waves (4/SIMD):
//  - h-waves (role 0, hb 0..7): W_hh frags in regs; per step read
//    partial(t) from LDS, 16 h-MFMA, nonlin, write h(t+1).
//  - x-waves (role 1, hb 0..7): W_ih frags in regs; run ONE STEP AHEAD:
//    compute partial(t+1) = bias + W_ih·x(t+1), store to LDS (f32, exact);
//    also stage x from global (f32->f16).
// Each SIMD hosts 2 h-waves + 2 x-waves: 4 independent streams hide the
// serial chains under the shared 64-MFMA/step pipe load.
// Tile map unchanged: tile row g4*4+q (q=0,1) holds real octet row
// R=(g4&1)*4+(g4>>1)*2+q; other rows stay zero. Sum order per gate
// identical to lstm9 -> bitwise-identical output.
__global__ __launch_bounds__(1024, 1) void lstm10_kernel(
        const char* __restrict__ wsb, const float* __restrict__ inp,
        float* __restrict__ hf) {
    __shared__ alignas(16) _Float16 xbuf[2][16 * 128];   // 2 x 4 KB
    __shared__ alignas(16) _Float16 hbuf[2][16 * 128];   // 2 x 4 KB
    __shared__ alignas(16) float partA[2][8][64][4];     // 16 KB
    __shared__ alignas(16) float partB[2][8][64][4];     // 16 KB

    const int tid  = threadIdx.x;
    const int lane = tid & 63;
    const int w16  = tid >> 6;          // 0..15
    const int role = w16 >> 3;          // 0 = h-wave, 1 = x-wave
    const int hb   = w16 & 7;
    const int l15  = lane & 15;
    const int g4   = lane >> 4;
    const int n    = blockIdx.x >> 3;
    const int oct  = blockIdx.x & 7;
    const int bq   = oct >> 1;
    const int hi   = oct & 1;
    const int j    = hb * 16 + l15;

    // weight frags in regs: W_hh for h-waves, W_ih for x-waves (16 h8v)
    h8v bf[4][4];
    {
        const _Float16* wp = reinterpret_cast<const _Float16*>(
                wsb + (role ? V2_OFF_BFI : V2_OFF_BFH)) + (size_t)lane * 8;
        #pragma unroll
        for (int nt = 0; nt < 4; ++nt)
            #pragma unroll
            for (int kt = 0; kt < 4; ++kt)
                bf[nt][kt] = *reinterpret_cast<const h8v*>(
                    wp + ((size_t)((n * 8 + hb) * 16 + nt * 4 + kt)) * 512);
    }
    float bs[4];
    #pragma unroll
    for (int nt = 0; nt < 4; ++nt)
        bs[nt] = reinterpret_cast<const float*>(wsb + V2_OFF_BIAS)[n * 512 + nt * 128 + j];

    // zero x/h buffers (dead rows + k>=100 pad must stay 0)
    for (int i = tid; i < 16 * 128; i += 1024) {
        xbuf[0][i] = (_Float16)0.f; xbuf[1][i] = (_Float16)0.f;
        hbuf[0][i] = (_Float16)0.f; hbuf[1][i] = (_Float16)0.f;
    }

    // x staging: 200 threads drawn from the x-waves (tid 512..711)
    const bool st = (tid >= 512) && (tid < 512 + 200);
    const int sid = st ? tid - 512 : 0;
    const int sr  = st ? sid / 25 : 0;
    const int c4  = st ? sid - sr * 25 : 0;
    const int g4s = sr >> 1, qs = sr & 1;
    const int tr  = g4s * 4 + qs;                         // live tile row
    const int Rr  = (g4s & 1) * 4 + (g4s >> 1) * 2 + qs;  // real octet row
    const float* xb = inp + (size_t)((bq * 16 + hi * 8 + Rr) * NN + n) * (TT * DIN)
                      + c4 * 4;
    const int wofs_x = tr * 256 + ((c4 * 8) ^ ((tr & 7) << 4));

    const int arow = l15 * 256;
    const int aswz = (l15 & 7) << 4;
    const int wr0 = (g4 * 4) * 256 + ((2 * j) ^ (((g4 * 4) & 7) << 4));
    const int wr1 = (g4 * 4 + 1) * 256 + ((2 * j) ^ (((g4 * 4 + 1) & 7) << 4));

    float c2[2] = {0.f, 0.f};
    float h2[2] = {0.f, 0.f};

    __syncthreads();    // zero-init complete
    if (st) {   // stage x(0) -> xbuf[0], x(1) -> xbuf[1]
        float4 v0 = *reinterpret_cast<const float4*>(xb);
        float4 v1 = *reinterpret_cast<const float4*>(xb + DIN);
        h4v p0 = {(_Float16)v0.x, (_Float16)v0.y, (_Float16)v0.z, (_Float16)v0.w};
        h4v p1 = {(_Float16)v1.x, (_Float16)v1.y, (_Float16)v1.z, (_Float16)v1.w};
        *reinterpret_cast<h4v*>(reinterpret_cast<char*>(xbuf[0]) + wofs_x) = p0;
        *reinterpret_cast<h4v*>(reinterpret_cast<char*>(xbuf[1]) + wofs_x) = p1;
    }
    __syncthreads();

    // prologue: x-waves compute part[0] = bias + W_ih.x(0)
    if (role == 1) {
        f4v acc[4];
        #pragma unroll
        for (int nt = 0; nt < 4; ++nt)
            acc[nt] = (f4v){bs[nt], bs[nt], 0.f, 0.f};
        const char* rcX = reinterpret_cast<const char*>(xbuf[0]);
        h8v ax0 = *reinterpret_cast<const h8v*>(rcX + arow + ((0 * 64 + g4 * 16) ^ aswz));
        h8v ax1 = *reinterpret_cast<const h8v*>(rcX + arow + ((1 * 64 + g4 * 16) ^ aswz));
        h8v ax2 = *reinterpret_cast<const h8v*>(rcX + arow + ((2 * 64 + g4 * 16) ^ aswz));
        h8v ax3 = *reinterpret_cast<const h8v*>(rcX + arow + ((3 * 64 + g4 * 16) ^ aswz));
        #pragma unroll
        for (int nt = 0; nt < 4; ++nt) {
            acc[nt] = __builtin_amdgcn_mfma_f32_16x16x32_f16(ax0, bf[nt][0], acc[nt], 0, 0, 0);
            acc[nt] = __builtin_amdgcn_mfma_f32_16x16x32_f16(ax1, bf[nt][1], acc[nt], 0, 0, 0);
            acc[nt] = __builtin_amdgcn_mfma_f32_16x16x32_f16(ax2, bf[nt][2], acc[nt], 0, 0, 0);
            acc[nt] = __builtin_amdgcn_mfma_f32_16x16x32_f16(ax3, bf[nt][3], acc[nt], 0, 0, 0);
        }
        f4v pA = (f4v){acc[0][0], acc[0][1], acc[1][0], acc[1][1]};
        f4v pB = (f4v){acc[2][0], acc[2][1], acc[3][0], acc[3][1]};
        *reinterpret_cast<f4v*>(&partA[0][hb][lane][0]) = pA;
        *reinterpret_cast<f4v*>(&partB[0][hb][lane][0]) = pB;
    }
    __syncthreads();

    for (int t = 0; t < TT; ++t) {
        if (role == 0) {
            // ---------- h-wave: consume partial(t), produce h(t+1) ----------
            const char* rcH = reinterpret_cast<const char*>(hbuf[t & 1]);
            char*       wcH = reinterpret_cast<char*>(hbuf[(t + 1) & 1]);

            f4v pA = *reinterpret_cast<const f4v*>(&partA[t & 1][hb][lane][0]);
            f4v pB = *reinterpret_cast<const f4v*>(&partB[t & 1][hb][lane][0]);
            f4v acc[4];
            acc[0] = (f4v){pA[0], pA[1], 0.f, 0.f};
            acc[1] = (f4v){pA[2], pA[3], 0.f, 0.f};
            acc[2] = (f4v){pB[0], pB[1], 0.f, 0.f};
            acc[3] = (f4v){pB[2], pB[3], 0.f, 0.f};

            h8v ah0 = *reinterpret_cast<const h8v*>(rcH + arow + ((0 * 64 + g4 * 16) ^ aswz));
            h8v ah1 = *reinterpret_cast<const h8v*>(rcH + arow + ((1 * 64 + g4 * 16) ^ aswz));
            h8v ah2 = *reinterpret_cast<const h8v*>(rcH + arow + ((2 * 64 + g4 * 16) ^ aswz));
            h8v ah3 = *reinterpret_cast<const h8v*>(rcH + arow + ((3 * 64 + g4 * 16) ^ aswz));

            acc[0] = __builtin_amdgcn_mfma_f32_16x16x32_f16(ah0, bf[0][0], acc[0], 0, 0, 0);
            acc[0] = __builtin_amdgcn_mfma_f32_16x16x32_f16(ah1, bf[0][1], acc[0], 0, 0, 0);
            acc[0] = __builtin_amdgcn_mfma_f32_16x16x32_f16(ah2, bf[0][2], acc[0], 0, 0, 0);
            acc[0] = __builtin_amdgcn_mfma_f32_16x16x32_f16(ah3, bf[0][3], acc[0], 0, 0, 0);
            float ii0 = sigf(acc[0][0]);
            float ii1 = sigf(acc[0][1]);

            acc[1] = __builtin_amdgcn_mfma_f32_16x16x32_f16(ah0, bf[1][0], acc[1], 0, 0, 0);
            acc[1] = __builtin_amdgcn_mfma_f32_16x16x32_f16(ah1, bf[1][1], acc[1], 0, 0, 0);
            acc[1] = __builtin_amdgcn_mfma_f32_16x16x32_f16(ah2, bf[1][2], acc[1], 0, 0, 0);
            acc[1] = __builtin_amdgcn_mfma_f32_16x16x32_f16(ah3, bf[1][3], acc[1], 0, 0, 0);
            float ff0 = sigf(acc[1][0]);
            float ff1 = sigf(acc[1][1]);

            acc[2] = __builtin_amdgcn_mfma_f32_16x16x32_f16(ah0, bf[2][0], acc[2], 0, 0, 0);
            acc[2] = __builtin_amdgcn_mfma_f32_16x16x32_f16(ah1, bf[2][1], acc[2], 0, 0, 0);
            acc[2] = __builtin_amdgcn_mfma_f32_16x16x32_f16(ah2, bf[2][2], acc[2], 0, 0, 0);
            acc[2] = __builtin_amdgcn_mfma_f32_16x16x32_f16(ah3, bf[2][3], acc[2], 0, 0, 0);
            float gg0 = tnhf(acc[2][0]);
            float gg1 = tnhf(acc[2][1]);

            acc[3] = __builtin_amdgcn_mfma_f32_16x16x32_f16(ah0, bf[3][0], acc[3], 0, 0, 0);
            acc[3] = __builtin_amdgcn_mfma_f32_16x16x32_f16(ah1, bf[3][1], acc[3], 0, 0, 0);
            acc[3] = __builtin_amdgcn_mfma_f32_16x16x32_f16(ah2, bf[3][2], acc[3], 0, 0, 0);
            acc[3] = __builtin_amdgcn_mfma_f32_16x16x32_f16(ah3, bf[3][3], acc[3], 0, 0, 0);
            float oo0 = sigf(acc[3][0]);
            float oo1 = sigf(acc[3][1]);

            float cn0 = ff0 * c2[0] + ii0 * gg0;
            c2[0] = cn0;
            float hn0 = oo0 * tnhf(cn0);
            h2[0] = hn0;
            *reinterpret_cast<_Float16*>(wcH + wr0) = (_Float16)hn0;

            float cn1 = ff1 * c2[1] + ii1 * gg1;
            c2[1] = cn1;
            float hn1 = oo1 * tnhf(cn1);
            h2[1] = hn1;
            *reinterpret_cast<_Float16*>(wcH + wr1) = (_Float16)hn1;
        } else {
            // ---------- x-wave: produce partial(t+1), stage x(t+2) ----------
            const char* rcX = reinterpret_cast<const char*>(xbuf[(t + 1) & 1]);
            char*       wcX = reinterpret_cast<char*>(xbuf[t & 1]);

            float4 nxt = make_float4(0.f, 0.f, 0.f, 0.f);
            int t2 = t + 2 < TT ? t + 2 : TT - 1;
            if (st) nxt = *reinterpret_cast<const float4*>(xb + (size_t)t2 * DIN);

            f4v acc[4];
            #pragma unroll
            for (int nt = 0; nt < 4; ++nt)
                acc[nt] = (f4v){bs[nt], bs[nt], 0.f, 0.f};

            h8v ax0 = *reinterpret_cast<const h8v*>(rcX + arow + ((0 * 64 + g4 * 16) ^ aswz));
            h8v ax1 = *reinterpret_cast<const h8v*>(rcX + arow + ((1 * 64 + g4 * 16) ^ aswz));
            h8v ax2 = *reinterpret_cast<const h8v*>(rcX + arow + ((2 * 64 + g4 * 16) ^ aswz));
            h8v ax3 = *reinterpret_cast<const h8v*>(rcX + arow + ((3 * 64 + g4 * 16) ^ aswz));
            #pragma unroll
            for (int nt = 0; nt < 4; ++nt) {
                acc[nt] = __builtin_amdgcn_mfma_f32_16x16x32_f16(ax0, bf[nt][0], acc[nt], 0, 0, 0);
                acc[nt] = __builtin_amdgcn_mfma_f32_16x16x32_f16(ax1, bf[nt][1], acc[nt], 0, 0, 0);
                acc[nt] = __builtin_amdgcn_mfma_f32_16x16x32_f16(ax2, bf[nt][2], acc[nt], 0, 0, 0);
                acc[nt] = __builtin_amdgcn_mfma_f32_16x16x32_f16(ax3, bf[nt][3], acc[nt], 0, 0, 0);
            }
            f4v pA = (f4v){acc[0][0], acc[0][1], acc[1][0], acc[1][1]};
            f4v pB = (f4v){acc[2][0], acc[2][1], acc[3][0], acc[3][1]};
            *reinterpret_cast<f4v*>(&partA[(t + 1) & 1][hb][lane][0]) = pA;
            *reinterpret_cast<f4v*>(&partB[(t + 1) & 1][hb][lane][0]) = pB;

            if (st) {
                h4v pk = {(_Float16)nxt.x, (_Float16)nxt.y, (_Float16)nxt.z, (_Float16)nxt.w};
                *reinterpret_cast<h4v*>(wcX + wofs_x) = pk;
            }
        }
        lgkm_barrier();
    }

    if (role == 0) {
        #pragma unroll
        for (int q = 0; q < 2; ++q) {
            int b = bq * 16 + hi * 8 + (g4 & 1) * 4 + (g4 >> 1) * 2 + q;
            hf[((size_t)b * NN + n) * HID + j] = h2[q];
        }
    }
}

// Head: 64 blocks (one per batch row), 256 thr, split-K over 2 halves.
__global__ __launch_bounds__(256) void head2_kernel(
        const float* __restrict__ hf, const float* __restrict__ w1t,
        const float* __restrict__ b1, const float* __restrict__ W2,
        const float* __restrict__ b2, float* __restrict__ out) {
    __shared__ float comb[FEAT];
    __shared__ float par[2][HID];
    __shared__ float hid[HID];
    const int b = blockIdx.x;
    const int u  = threadIdx.x & 127;
    const int kk = threadIdx.x >> 7;
    const float* hfp = hf + (size_t)b * FEAT;
    for (int i = threadIdx.x; i < FEAT; i += 256) comb[i] = hfp[i];
    __syncthreads();

    const int k0 = kk * (FEAT / 2);
    float acc = 0.f;
    #pragma unroll 8
    for (int k = 0; k < FEAT / 2; ++k)
        acc = fmaf(comb[k0 + k], w1t[(size_t)(k0 + k) * HID + u], acc);
    par[kk][u] = acc;
    __syncthreads();
    if (kk == 0) hid[u] = fmaxf(par[0][u] + par[1][u] + b1[u], 0.f);
    __syncthreads();

    if (threadIdx.x < NC) {
        int cls = threadIdx.x;
        float a = b2[cls];
        #pragma unroll 4
        for (int k = 0; k < HID; ++k)
            a = fmaf(hid[k], W2[cls * HID + k], a);
        out[b * NC + cls] = a;
    }
}

// ======================= fallback (round-3) =======================
__global__ __launch_bounds__(256) void packfb_kernel(
        const float* __restrict__ W_ih, const float* __restrict__ W_hh,
        const float* __restrict__ W1,
        unsigned short* __restrict__ bfw, float* __restrict__ w1t) {
    int id = blockIdx.x * 256 + threadIdx.x;
    if (id < SZ_BF) {
        int e    = id & 7;
        int lane = (id >> 3) & 63;
        int kt   = (id >> 9) & 7;
        int nt   = (id >> 12) & 3;
        int hb   = (id >> 14) & 7;
        int n    = id >> 17;
        int k = kt * 32 + (lane >> 4) * 8 + e;
        int g = nt * 128 + hb * 16 + (lane & 15);
        float v = 0.f;
        if (k < DIN)       v = W_ih[((size_t)n * 512 + g) * DIN + k];
        else if (k < 228)  v = W_hh[((size_t)n * 512 + g) * HID + (k - DIN)];
        bfw[id] = f2bf(v);
        return;
    }
    int id3 = id - SZ_BF;
    if (id3 < SZ_W1T) {
        int j = id3 & 127, k = id3 >> 7;
        w1t[id3] = W1[(size_t)j * FEAT + k];
    }
}

__global__ __launch_bounds__(512, 2) void lstmfb_kernel(
        const float* __restrict__ inp,
        const float* __restrict__ b_ih, const float* __restrict__ b_hh,
        const unsigned short* __restrict__ bfw, float* __restrict__ hf) {
    __shared__ alignas(16) unsigned short xh[2][16 * 256];
    const int tid  = threadIdx.x;
    const int lane = tid & 63;
    const int w    = tid >> 6;
    const int l15  = lane & 15;
    const int g4   = lane >> 4;
    const int n    = blockIdx.x >> 2;
    const int bq   = blockIdx.x & 3;
    const int j    = w * 16 + l15;

    s8v bf[4][8];
    const unsigned short* wp = bfw + ((size_t)(n * 8 + w) * 32) * 512 + lane * 8;
    #pragma unroll
    for (int nt = 0; nt < 4; ++nt)
        #pragma unroll
        for (int kt = 0; kt < 8; ++kt)
            bf[nt][kt] = *reinterpret_cast<const s8v*>(wp + (nt * 8 + kt) * 512);

    float bs[4];
    #pragma unroll
    for (int nt = 0; nt < 4; ++nt)
        bs[nt] = b_ih[n * 512 + nt * 128 + j] + b_hh[n * 512 + nt * 128 + j];

    float c[4] = {0.f, 0.f, 0.f, 0.f};
    float h[4] = {0.f, 0.f, 0.f, 0.f};
    for (int i = tid; i < 2 * 16 * 256; i += 512) (&xh[0][0])[i] = 0;

    const bool st = tid < 400;
    const int row = st ? tid / 25 : 0;
    const int c4  = st ? tid - row * 25 : 0;
    const float* xb = inp + ((size_t)(bq * 16 + row) * NN + n) * (TT * DIN) + c4 * 4;
    const int wofs = row * 512 + ((c4 * 8) ^ ((row & 7) << 4));
    const int arow = l15 * 512;
    const int aswz = (l15 & 7) << 4;

    __syncthreads();
    if (st) {
        float4 v = *reinterpret_cast<const float4*>(xb);
        unsigned lo = f2bf(v.x) | ((unsigned)f2bf(v.y) << 16);
        unsigned hi = f2bf(v.z) | ((unsigned)f2bf(v.w) << 16);
        *reinterpret_cast<uint2*>(reinterpret_cast<char*>(xh[0]) + wofs) =
            make_uint2(lo, hi);
    }
    __syncthreads();

    for (int t = 0; t < TT; ++t) {
        char* rc = reinterpret_cast<char*>(xh[t & 1]);
        char* wc = reinterpret_cast<char*>(xh[(t + 1) & 1]);
        float4 nxt = make_float4(0.f, 0.f, 0.f, 0.f);
        if (t < TT - 1 && st)
            nxt = *reinterpret_cast<const float4*>(xb + (t + 1) * DIN);

        f4v acc[4];
        #pragma unroll
        for (int nt = 0; nt < 4; ++nt)
            acc[nt] = (f4v){bs[nt], bs[nt], bs[nt], bs[nt]};
        #pragma unroll
        for (int kt = 0; kt < 8; ++kt) {
            s8v a = *reinterpret_cast<const s8v*>(rc + arow + ((kt * 64 + g4 * 16) ^ aswz));
            #pragma unroll
            for (int nt = 0; nt < 4; ++nt)
                acc[nt] = __builtin_amdgcn_mfma_f32_16x16x32_bf16(a, bf[nt][kt], acc[nt], 0, 0, 0);
        }
        #pragma unroll
        for (int r = 0; r < 4; ++r) {
            float ii = sigf(acc[0][r]);
            float ff = sigf(acc[1][r]);
            float gg = tnhf(acc[2][r]);
            float oo = sigf(acc[3][r]);
            float cn = ff * c[r] + ii * gg;
            c[r] = cn;
            float hn = oo * tnhf(cn);
            h[r] = hn;
            int rr = g4 * 4 + r;
            *reinterpret_cast<unsigned short*>(
                wc + rr * 512 + (((DIN + j) * 2) ^ ((rr & 7) << 4))) = f2bf(hn);
        }
        if (t < TT - 1 && st) {
            unsigned lo = f2bf(nxt.x) | ((unsigned)f2bf(nxt.y) << 16);
            unsigned hi = f2bf(nxt.z) | ((unsigned)f2bf(nxt.w) << 16);
            *reinterpret_cast<uint2*>(wc + wofs) = make_uint2(lo, hi);
        }
        __syncthreads();
    }
    #pragma unroll
    for (int r = 0; r < 4; ++r) {
        int b = bq * 16 + g4 * 4 + r;
        hf[((size_t)b * NN + n) * HID + j] = h[r];
    }
}

// ============================ launch ==============================
extern "C" void kernel_launch(void* const* d_in, const int* in_sizes, int n_in,
                              void* d_out, int out_size, void* d_ws, size_t ws_size,
                              hipStream_t stream) {
    const float* inp  = (const float*)d_in[0];
    const float* W_ih = (const float*)d_in[2];
    const float* W_hh = (const float*)d_in[3];
    const float* b_ih = (const float*)d_in[4];
    const float* b_hh = (const float*)d_in[5];
    const float* W1   = (const float*)d_in[6];
    const float* b1   = (const float*)d_in[7];
    const float* W2   = (const float*)d_in[8];
    const float* b2   = (const float*)d_in[9];
    float* out = (float*)d_out;

    if (ws_size >= V2_NEED) {
        char* wsb = (char*)d_ws;
        float* hf  = (float*)(wsb + V2_OFF_HF);
        float* w1t = (float*)(wsb + V2_OFF_W1T);
        pack2_kernel<<<(PACK2_TOTAL + 255) / 256, 256, 0, stream>>>(
            W_ih, W_hh, b_ih, b_hh, W1, wsb);
        lstm10_kernel<<<NN * 8, 1024, 0, stream>>>(wsb, inp, hf);
        head2_kernel<<<BB, 256, 0, stream>>>(hf, w1t, b1, W2, b2, out);
    } else {
        float* ws = (float*)d_ws;
        unsigned short* bfw = (unsigned short*)d_ws;
        packfb_kernel<<<(PACK_TOTAL_O + 255) / 256, 256, 0, stream>>>(
            W_ih, W_hh, W1, bfw, ws + OFF_W1T_O);
        lstmfb_kernel<<<NN * 4, 512, 0, stream>>>(inp, b_ih, b_hh, bfw, ws + OFF_HF_O);
        head2_kernel<<<BB, 256, 0, stream>>>(ws + OFF_HF_O, ws + OFF_W1T_O,
                                             b1, W2, b2, out);
    }
}

// Round 14
// 407.556 us; speedup vs baseline: 1.0572x; 1.0572x over previous
//
#include <hip/hip_runtime.h>
#include <hip/hip_bf16.h>

#define NN   19
#define DIN  100
#define HID  128
#define TT   250
#define BB   64
#define NC   4
#define FEAT 2432          // NN*HID

typedef __attribute__((ext_vector_type(8))) short s8v;
typedef __attribute__((ext_vector_type(4))) float f4v;
typedef _Float16 h8v __attribute__((ext_vector_type(8)));
typedef _Float16 h4v __attribute__((ext_vector_type(4)));

// =============== V2 workspace layout (byte offsets) ===============
// BFI: W_ih MFMA B-frags f16    (19*8*4*4*512 halfs)
// BFH: W_hh MFMA B-frags f16    (same count)
// BIAS: combined b_ih+b_hh f32  (19*512)
// W1T: W1 transposed f32        (2432*128)
// HF : final hidden f32         (64*2432)
// XG : precomputed x-gates f16, slot-grouped fragment layout:
//      ((n*4+bq)*250+t)*8192 + (hb*64+lane)*16 + slotpair*8 + [nt | 4+nt]
#define BFI_USH   1245184
#define V2_OFF_BFI  0ull
#define V2_OFF_BFH  2490368ull
#define V2_OFF_BIAS 4980736ull
#define V2_OFF_W1T  5019648ull
#define V2_OFF_HF   6264832ull
#define V2_OFF_XG   6887424ull
#define V2_NEED     318183424ull
#define PACK2_TOTAL (2*BFI_USH + 19*512 + FEAT*HID)

// =============== fallback (round-3) layout, float offsets =========
#define SZ_BF   (NN*8*4*8*512)
#define OFF_W1T_O (SZ_BF/2)
#define SZ_W1T  (FEAT*HID)
#define OFF_HF_O  (OFF_W1T_O + SZ_W1T)
#define PACK_TOTAL_O (SZ_BF + SZ_W1T)

__device__ __forceinline__ unsigned short f2bf(float x) {
    union { float f; unsigned u; } v; v.f = x;
    unsigned r = v.u + 0x7FFF + ((v.u >> 16) & 1);   // RNE
    return (unsigned short)(r >> 16);
}
#define LOG2E 1.4426950408889634f
__device__ __forceinline__ float sigf(float x) {
    return __builtin_amdgcn_rcpf(1.f + __builtin_amdgcn_exp2f(-LOG2E * x));
}
__device__ __forceinline__ float tnhf(float x) {
    return 1.f - 2.f * __builtin_amdgcn_rcpf(__builtin_amdgcn_exp2f(2.f * LOG2E * x) + 1.f);
}

// lgkm-only barrier: LDS ordered; global loads/stores stay in flight.
__device__ __forceinline__ void lgkm_barrier() {
    asm volatile("s_waitcnt lgkmcnt(0)" ::: "memory");
    __builtin_amdgcn_s_barrier();
    asm volatile("" ::: "memory");
}

// ======================= V2 kernels ===============================

// Pack W_ih frags, W_hh frags (f16), combined bias, W1T.
// Frag element (n, hb, nt, kt, lane, e) = W[k][g]:
// k = kt*32+(lane>>4)*8+e, g = nt*128+hb*16+(lane&15).
__global__ __launch_bounds__(256) void pack2_kernel(
        const float* __restrict__ W_ih, const float* __restrict__ W_hh,
        const float* __restrict__ b_ih, const float* __restrict__ b_hh,
        const float* __restrict__ W1, char* __restrict__ wsb) {
    int id = blockIdx.x * 256 + threadIdx.x;
    if (id < 2 * BFI_USH) {
        int which = id >= BFI_USH;                 // 0 = W_ih, 1 = W_hh
        int i = which ? id - BFI_USH : id;
        int e    = i & 7;
        int lane = (i >> 3) & 63;
        int kt   = (i >> 9) & 3;
        int nt   = (i >> 11) & 3;
        int hb   = (i >> 13) & 7;
        int n    = i >> 16;
        int k = kt * 32 + (lane >> 4) * 8 + e;
        int g = nt * 128 + hb * 16 + (lane & 15);
        float v;
        if (which) v = W_hh[((size_t)n * 512 + g) * HID + k];
        else       v = (k < DIN) ? W_ih[((size_t)n * 512 + g) * DIN + k] : 0.f;
        reinterpret_cast<_Float16*>(wsb)[id] = (_Float16)v;
        return;
    }
    int id2 = id - 2 * BFI_USH;
    if (id2 < NN * 512) {
        reinterpret_cast<float*>(wsb + V2_OFF_BIAS)[id2] = b_ih[id2] + b_hh[id2];
        return;
    }
    int id3 = id2 - NN * 512;
    if (id3 < FEAT * HID) {
        int j = id3 & 127, k = id3 >> 7;
        reinterpret_cast<float*>(wsb + V2_OFF_W1T)[id3] = W1[(size_t)j * FEAT + k];
    }
}

// xg2: BARRIER-FREE x-projection. grid = (n, bq, tchunk of 25), 512 thr
// = 8 independent waves (wave w = gate-column block hb = w). No LDS, no
// __syncthreads: each wave loads its own A-fragments straight from
// global f32 x (per lane 7 float4; the k in [96,100) boundary is one
// predicated float4, windows with k0+8 <= 100 are unconditional), casts
// to f16 exactly as the old staged path, and runs the identical MFMA
// accumulation order -> bitwise-identical xg.
// Stores slot-grouped: s0[nt]=acc[nt][0], s0[4+nt]=acc[nt][1],
// s1[nt]=acc[nt][2], s1[4+nt]=acc[nt][3].
__global__ __launch_bounds__(512, 2) void xg2_kernel(
        const float* __restrict__ inp, const char* __restrict__ wsb,
        _Float16* __restrict__ xg) {
    const int tid  = threadIdx.x;
    const int lane = tid & 63;
    const int w    = tid >> 6;
    const int l15  = lane & 15;
    const int g4   = lane >> 4;
    const int blk  = blockIdx.x;
    const int tc   = blk % 10;
    const int bq   = (blk / 10) & 3;
    const int n    = blk / 40;
    const int t0   = tc * 25;
    const int j    = w * 16 + l15;

    // W_ih frags, register-resident (16 h8v)
    h8v bf[4][4];
    {
        const _Float16* wp = reinterpret_cast<const _Float16*>(wsb)
                             + ((size_t)(n * 8 + w) * 16) * 512 + lane * 8;
        #pragma unroll
        for (int nt = 0; nt < 4; ++nt)
            #pragma unroll
            for (int kt = 0; kt < 4; ++kt)
                bf[nt][kt] = *reinterpret_cast<const h8v*>(wp + (nt * 4 + kt) * 512);
    }
    float bs[4];
    #pragma unroll
    for (int nt = 0; nt < 4; ++nt)
        bs[nt] = reinterpret_cast<const float*>(wsb + V2_OFF_BIAS)[n * 512 + nt * 128 + j];

    // this lane's x row (batch row bq*16 + l15), k window base g4*8
    const float* xrow = inp + ((size_t)(bq * 16 + l15) * NN + n) * (TT * DIN)
                        + (size_t)t0 * DIN;

    _Float16* xout = xg + ((size_t)((n * 4 + bq) * 250 + t0)) * 8192
                     + (w * 64 + lane) * 16;

    for (int t = 0; t < 25; ++t) {
        const float* xt = xrow + (size_t)t * DIN;

        // A-fragments direct from global f32, cast to f16 (same RNE cast
        // as the old staged path -> identical values)
        h8v a[4];
        #pragma unroll
        for (int kt = 0; kt < 3; ++kt) {
            int k0 = kt * 32 + g4 * 8;           // k0+8 <= 96+? : kt<=2 -> k0<=88, +8<=96<=100 OK
            float4 v0 = *reinterpret_cast<const float4*>(xt + k0);
            float4 v1 = *reinterpret_cast<const float4*>(xt + k0 + 4);
            a[kt][0] = (_Float16)v0.x; a[kt][1] = (_Float16)v0.y;
            a[kt][2] = (_Float16)v0.z; a[kt][3] = (_Float16)v0.w;
            a[kt][4] = (_Float16)v1.x; a[kt][5] = (_Float16)v1.y;
            a[kt][6] = (_Float16)v1.z; a[kt][7] = (_Float16)v1.w;
        }
        {   // kt = 3: k = 96 + g4*8 .. +7; only g4==0 touches valid k (96..99)
            #pragma unroll
            for (int e = 0; e < 8; ++e) a[3][e] = (_Float16)0.f;
            if (g4 == 0) {
                float4 v0 = *reinterpret_cast<const float4*>(xt + 96);
                a[3][0] = (_Float16)v0.x; a[3][1] = (_Float16)v0.y;
                a[3][2] = (_Float16)v0.z; a[3][3] = (_Float16)v0.w;
            }
        }

        f4v acc[4];
        #pragma unroll
        for (int nt = 0; nt < 4; ++nt)
            acc[nt] = (f4v){bs[nt], bs[nt], bs[nt], bs[nt]};
        #pragma unroll
        for (int kt = 0; kt < 4; ++kt)
            #pragma unroll
            for (int nt = 0; nt < 4; ++nt)
                acc[nt] = __builtin_amdgcn_mfma_f32_16x16x32_f16(
                              a[kt], bf[nt][kt], acc[nt], 0, 0, 0);

        h8v s0, s1;
        #pragma unroll
        for (int nt = 0; nt < 4; ++nt) {
            s0[nt]     = (_Float16)acc[nt][0];
            s0[4 + nt] = (_Float16)acc[nt][1];
            s1[nt]     = (_Float16)acc[nt][2];
            s1[4 + nt] = (_Float16)acc[nt][3];
        }
        *reinterpret_cast<h8v*>(xout + (size_t)t * 8192)     = s0;
        *reinterpret_cast<h8v*>(xout + (size_t)t * 8192 + 8) = s1;
    }
}

// Recurrence v7 (round-10 exact, 176 us): 152 WGs, 8 waves, nt-major
// MFMA + early nonlin, lgkm-only barrier, 2-deep xg prefetch.
__global__ __launch_bounds__(512, 2) void lstm7_kernel(
        const char* __restrict__ wsb, const _Float16* __restrict__ xg,
        float* __restrict__ hf) {
    __shared__ alignas(16) _Float16 xh[2][16 * 128];

    const int tid  = threadIdx.x;
    const int lane = tid & 63;
    const int w8   = tid >> 6;          // 0..7
    const int l15  = lane & 15;
    const int g4   = lane >> 4;
    const int n    = blockIdx.x >> 3;
    const int oct  = blockIdx.x & 7;
    const int bq   = oct >> 1;
    const int hi   = oct & 1;
    const int hb   = w8;
    const int j    = hb * 16 + l15;

    h8v bf[4][4];
    {
        const _Float16* wp = reinterpret_cast<const _Float16*>(wsb + V2_OFF_BFH)
                             + (size_t)lane * 8;
        #pragma unroll
        for (int nt = 0; nt < 4; ++nt)
            #pragma unroll
            for (int kt = 0; kt < 4; ++kt)
                bf[nt][kt] = *reinterpret_cast<const h8v*>(
                    wp + ((size_t)((n * 8 + hb) * 16 + nt * 4 + kt)) * 512);
    }

    float c2[2] = {0.f, 0.f};
    float h2[2] = {0.f, 0.f};

    for (int i = tid; i < 2 * 16 * 128; i += 512) (&xh[0][0])[i] = (_Float16)0.f;

    const _Float16* xp = xg + ((size_t)((n * 4 + bq) * 250)) * 8192
        + (size_t)(hb * 64 + l15 + 16 * (hi * 2 + (g4 & 1))) * 16
        + (g4 >> 1) * 8;

    const int arow = l15 * 256;
    const int aswz = ((l15 & 1) << 4) | (((l15 >> 2) & 3) << 5);
    const int wr0 = (g4 * 4) * 256 + ((2 * j) ^ (g4 << 5));
    const int wr1 = (g4 * 4 + 1) * 256 + ((2 * j) ^ 16 ^ (g4 << 5));

    h8v p  = *reinterpret_cast<const h8v*>(xp);
    h8v qn = *reinterpret_cast<const h8v*>(xp + 8192);
    lgkm_barrier();

    #pragma unroll 2
    for (int t = 0; t < TT; ++t) {
        char* rc = reinterpret_cast<char*>(xh[t & 1]);
        char* wc = reinterpret_cast<char*>(xh[(t + 1) & 1]);

        f4v acc[4];
        #pragma unroll
        for (int nt = 0; nt < 4; ++nt)
            acc[nt] = (f4v){(float)p[nt], (float)p[4 + nt], 0.f, 0.f};

        int tn = t + 2 < TT ? t + 2 : TT - 1;
        h8v rn = *reinterpret_cast<const h8v*>(xp + (size_t)tn * 8192);

        h8v a0 = *reinterpret_cast<const h8v*>(rc + arow + ((0 * 64 + g4 * 16) ^ aswz));
        h8v a1 = *reinterpret_cast<const h8v*>(rc + arow + ((1 * 64 + g4 * 16) ^ aswz));
        h8v a2 = *reinterpret_cast<const h8v*>(rc + arow + ((2 * 64 + g4 * 16) ^ aswz));
        h8v a3 = *reinterpret_cast<const h8v*>(rc + arow + ((3 * 64 + g4 * 16) ^ aswz));

        acc[0] = __builtin_amdgcn_mfma_f32_16x16x32_f16(a0, bf[0][0], acc[0], 0, 0, 0);
        acc[0] = __builtin_amdgcn_mfma_f32_16x16x32_f16(a1, bf[0][1], acc[0], 0, 0, 0);
        acc[0] = __builtin_amdgcn_mfma_f32_16x16x32_f16(a2, bf[0][2], acc[0], 0, 0, 0);
        acc[0] = __builtin_amdgcn_mfma_f32_16x16x32_f16(a3, bf[0][3], acc[0], 0, 0, 0);
        float ii0 = sigf(acc[0][0]);
        float ii1 = sigf(acc[0][1]);

        acc[1] = __builtin_amdgcn_mfma_f32_16x16x32_f16(a0, bf[1][0], acc[1], 0, 0, 0);
        acc[1] = __builtin_amdgcn_mfma_f32_16x16x32_f16(a1, bf[1][1], acc[1], 0, 0, 0);
        acc[1] = __builtin_amdgcn_mfma_f32_16x16x32_f16(a2, bf[1][2], acc[1], 0, 0, 0);
        acc[1] = __builtin_amdgcn_mfma_f32_16x16x32_f16(a3, bf[1][3], acc[1], 0, 0, 0);
        float ff0 = sigf(acc[1][0]);
        float ff1 = sigf(acc[1][1]);

        acc[2] = __builtin_amdgcn_mfma_f32_16x16x32_f16(a0, bf[2][0], acc[2], 0, 0, 0);
        acc[2] = __builtin_amdgcn_mfma_f32_16x16x32_f16(a1, bf[2][1], acc[2], 0, 0, 0);
        acc[2] = __builtin_amdgcn_mfma_f32_16x16x32_f16(a2, bf[2][2], acc[2], 0, 0, 0);
        acc[2] = __builtin_amdgcn_mfma_f32_16x16x32_f16(a3, bf[2][3], acc[2], 0, 0, 0);
        float gg0 = tnhf(acc[2][0]);
        float gg1 = tnhf(acc[2][1]);

        acc[3] = __builtin_amdgcn_mfma_f32_16x16x32_f16(a0, bf[3][0], acc[3], 0, 0, 0);
        acc[3] = __builtin_amdgcn_mfma_f32_16x16x32_f16(a1, bf[3][1], acc[3], 0, 0, 0);
        acc[3] = __builtin_amdgcn_mfma_f32_16x16x32_f16(a2, bf[3][2], acc[3], 0, 0, 0);
        acc[3] = __builtin_amdgcn_mfma_f32_16x16x32_f16(a3, bf[3][3], acc[3], 0, 0, 0);
        float oo0 = sigf(acc[3][0]);
        float oo1 = sigf(acc[3][1]);

        float cn0 = ff0 * c2[0] + ii0 * gg0;
        c2[0] = cn0;
        float hn0 = oo0 * tnhf(cn0);
        h2[0] = hn0;
        *reinterpret_cast<_Float16*>(wc + wr0) = (_Float16)hn0;

        float cn1 = ff1 * c2[1] + ii1 * gg1;
        c2[1] = cn1;
        float hn1 = oo1 * tnhf(cn1);
        h2[1] = hn1;
        *reinterpret_cast<_Float16*>(wc + wr1) = (_Float16)hn1;

        p = qn; qn = rn;
        lgkm_barrier();
    }

    #pragma unroll
    for (int q = 0; q < 2; ++q) {
        int b = bq * 16 + hi * 8 + (g4 & 1) * 4 + (g4 >> 1) * 2 + q;
        hf[((size_t)b * NN + n) * HID + j] = h2[q];
    }
}

// Head: 64 blocks (one per batch row), 256 thr, split-K over 2 halves.
__global__ __launch_bounds__(256) void head2_kernel(
        const float* __restrict__ hf, const float* __restrict__ w1t,
        const float* __restrict__ b1, const float* __restrict__ W2,
        const float* __restrict__ b2, float* __restrict__ out) {
    __shared__ float comb[FEAT];
    __shared__ float par[2][HID];
    __shared__ float hid[HID];
    const int b = blockIdx.x;
    const int u  = threadIdx.x & 127;
    const int kk = threadIdx.x >> 7;
    const float* hfp = hf + (size_t)b * FEAT;
    for (int i = threadIdx.x; i < FEAT; i += 256) comb[i] = hfp[i];
    __syncthreads();

    const int k0 = kk * (FEAT / 2);
    float acc = 0.f;
    #pragma unroll 8
    for (int k = 0; k < FEAT / 2; ++k)
        acc = fmaf(comb[k0 + k], w1t[(size_t)(k0 + k) * HID + u], acc);
    par[kk][u] = acc;
    __syncthreads();
    if (kk == 0) hid[u] = fmaxf(par[0][u] + par[1][u] + b1[u], 0.f);
    __syncthreads();

    if (threadIdx.x < NC) {
        int cls = threadIdx.x;
        float a = b2[cls];
        #pragma unroll 4
        for (int k = 0; k < HID; ++k)
            a = fmaf(hid[k], W2[cls * HID + k], a);
        out[b * NC + cls] = a;
    }
}

// ======================= fallback (round-3) =======================
__global__ __launch_bounds__(256) void packfb_kernel(
        const float* __restrict__ W_ih, const float* __restrict__ W_hh,
        const float* __restrict__ W1,
        unsigned short* __restrict__ bfw, float* __restrict__ w1t) {
    int id = blockIdx.x * 256 + threadIdx.x;
    if (id < SZ_BF) {
        int e    = id & 7;
        int lane = (id >> 3) & 63;
        int kt   = (id >> 9) & 7;
        int nt   = (id >> 12) & 3;
        int hb   = (id >> 14) & 7;
        int n    = id >> 17;
        int k = kt * 32 + (lane >> 4) * 8 + e;
        int g = nt * 128 + hb * 16 + (lane & 15);
        float v = 0.f;
        if (k < DIN)       v = W_ih[((size_t)n * 512 + g) * DIN + k];
        else if (k < 228)  v = W_hh[((size_t)n * 512 + g) * HID + (k - DIN)];
        bfw[id] = f2bf(v);
        return;
    }
    int id3 = id - SZ_BF;
    if (id3 < SZ_W1T) {
        int j = id3 & 127, k = id3 >> 7;
        w1t[id3] = W1[(size_t)j * FEAT + k];
    }
}

__global__ __launch_bounds__(512, 2) void lstmfb_kernel(
        const float* __restrict__ inp,
        const float* __restrict__ b_ih, const float* __restrict__ b_hh,
        const unsigned short* __restrict__ bfw, float* __restrict__ hf) {
    __shared__ alignas(16) unsigned short xh[2][16 * 256];
    const int tid  = threadIdx.x;
    const int lane = tid & 63;
    const int w    = tid >> 6;
    const int l15  = lane & 15;
    const int g4   = lane >> 4;
    const int n    = blockIdx.x >> 2;
    const int bq   = blockIdx.x & 3;
    const int j    = w * 16 + l15;

    s8v bf[4][8];
    const unsigned short* wp = bfw + ((size_t)(n * 8 + w) * 32) * 512 + lane * 8;
    #pragma unroll
    for (int nt = 0; nt < 4; ++nt)
        #pragma unroll
        for (int kt = 0; kt < 8; ++kt)
            bf[nt][kt] = *reinterpret_cast<const s8v*>(wp + (nt * 8 + kt) * 512);

    float bs[4];
    #pragma unroll
    for (int nt = 0; nt < 4; ++nt)
        bs[nt] = b_ih[n * 512 + nt * 128 + j] + b_hh[n * 512 + nt * 128 + j];

    float c[4] = {0.f, 0.f, 0.f, 0.f};
    float h[4] = {0.f, 0.f, 0.f, 0.f};
    for (int i = tid; i < 2 * 16 * 256; i += 512) (&xh[0][0])[i] = 0;

    const bool st = tid < 400;
    const int row = st ? tid / 25 : 0;
    const int c4  = st ? tid - row * 25 : 0;
    const float* xb = inp + ((size_t)(bq * 16 + row) * NN + n) * (TT * DIN) + c4 * 4;
    const int wofs = row * 512 + ((c4 * 8) ^ ((row & 7) << 4));
    const int arow = l15 * 512;
    const int aswz = (l15 & 7) << 4;

    __syncthreads();
    if (st) {
        float4 v = *reinterpret_cast<const float4*>(xb);
        unsigned lo = f2bf(v.x) | ((unsigned)f2bf(v.y) << 16);
        unsigned hi = f2bf(v.z) | ((unsigned)f2bf(v.w) << 16);
        *reinterpret_cast<uint2*>(reinterpret_cast<char*>(xh[0]) + wofs) =
            make_uint2(lo, hi);
    }
    __syncthreads();

    for (int t = 0; t < TT; ++t) {
        char* rc = reinterpret_cast<char*>(xh[t & 1]);
        char* wc = reinterpret_cast<char*>(xh[(t + 1) & 1]);
        float4 nxt = make_float4(0.f, 0.f, 0.f, 0.f);
        if (t < TT - 1 && st)
            nxt = *reinterpret_cast<const float4*>(xb + (t + 1) * DIN);

        f4v acc[4];
        #pragma unroll
        for (int nt = 0; nt < 4; ++nt)
            acc[nt] = (f4v){bs[nt], bs[nt], bs[nt], bs[nt]};
        #pragma unroll
        for (int kt = 0; kt < 8; ++kt) {
            s8v a = *reinterpret_cast<const s8v*>(rc + arow + ((kt * 64 + g4 * 16) ^ aswz));
            #pragma unroll
            for (int nt = 0; nt < 4; ++nt)
                acc[nt] = __builtin_amdgcn_mfma_f32_16x16x32_bf16(a, bf[nt][kt], acc[nt], 0, 0, 0);
        }
        #pragma unroll
        for (int r = 0; r < 4; ++r) {
            float ii = sigf(acc[0][r]);
            float ff = sigf(acc[1][r]);
            float gg = tnhf(acc[2][r]);
            float oo = sigf(acc[3][r]);
            float cn = ff * c[r] + ii * gg;
            c[r] = cn;
            float hn = oo * tnhf(cn);
            h[r] = hn;
            int rr = g4 * 4 + r;
            *reinterpret_cast<unsigned short*>(
                wc + rr * 512 + (((DIN + j) * 2) ^ ((rr & 7) << 4))) = f2bf(hn);
        }
        if (t < TT - 1 && st) {
            unsigned lo = f2bf(nxt.x) | ((unsigned)f2bf(nxt.y) << 16);
            unsigned hi = f2bf(nxt.z) | ((unsigned)f2bf(nxt.w) << 16);
            *reinterpret_cast<uint2*>(wc + wofs) = make_uint2(lo, hi);
        }
        __syncthreads();
    }
    #pragma unroll
    for (int r = 0; r < 4; ++r) {
        int b = bq * 16 + g4 * 4 + r;
        hf[((size_t)b * NN + n) * HID + j] = h[r];
    }
}

// ============================ launch ==============================
extern "C" void kernel_launch(void* const* d_in, const int* in_sizes, int n_in,
                              void* d_out, int out_size, void* d_ws, size_t ws_size,
                              hipStream_t stream) {
    const float* inp  = (const float*)d_in[0];
    const float* W_ih = (const float*)d_in[2];
    const float* W_hh = (const float*)d_in[3];
    const float* b_ih = (const float*)d_in[4];
    const float* b_hh = (const float*)d_in[5];
    const float* W1   = (const float*)d_in[6];
    const float* b1   = (const float*)d_in[7];
    const float* W2   = (const float*)d_in[8];
    const float* b2   = (const float*)d_in[9];
    float* out = (float*)d_out;

    if (ws_size >= V2_NEED) {
        char* wsb = (char*)d_ws;
        _Float16* xg = (_Float16*)(wsb + V2_OFF_XG);
        float* hf    = (float*)(wsb + V2_OFF_HF);
        float* w1t   = (float*)(wsb + V2_OFF_W1T);
        pack2_kernel<<<(PACK2_TOTAL + 255) / 256, 256, 0, stream>>>(
            W_ih, W_hh, b_ih, b_hh, W1, wsb);
        xg2_kernel<<<NN * 4 * 10, 512, 0, stream>>>(inp, wsb, xg);
        lstm7_kernel<<<NN * 8, 512, 0, stream>>>(wsb, xg, hf);
        head2_kernel<<<BB, 256, 0, stream>>>(hf, w1t, b1, W2, b2, out);
    } else {
        float* ws = (float*)d_ws;
        unsigned short* bfw = (unsigned short*)d_ws;
        packfb_kernel<<<(PACK_TOTAL_O + 255) / 256, 256, 0, stream>>>(
            W_ih, W_hh, W1, bfw, ws + OFF_W1T_O);
        lstmfb_kernel<<<NN * 4, 512, 0, stream>>>(inp, b_ih, b_hh, bfw, ws + OFF_HF_O);
        head2_kernel<<<BB, 256, 0, stream>>>(ws + OFF_HF_O, ws + OFF_W1T_O,
                                             b1, W2, b2, out);
    }
}

// Round 15
// 361.626 us; speedup vs baseline: 1.1915x; 1.1270x over previous
//
#include <hip/hip_runtime.h>
#include <hip/hip_bf16.h>

#define NN   19
#define DIN  100
#define HID  128
#define TT   250
#define BB   64
#define NC   4
#define FEAT 2432          // NN*HID

typedef __attribute__((ext_vector_type(8))) short s8v;
typedef __attribute__((ext_vector_type(4))) float f4v;
typedef _Float16 h8v __attribute__((ext_vector_type(8)));
typedef _Float16 h4v __attribute__((ext_vector_type(4)));

// =============== V2 workspace layout (byte offsets) ===============
#define BFI_USH   1245184
#define V2_OFF_BFI  0ull
#define V2_OFF_BFH  2490368ull
#define V2_OFF_BIAS 4980736ull
#define V2_OFF_W1T  5019648ull
#define V2_OFF_HF   6264832ull
#define V2_OFF_XG   6887424ull
#define V2_NEED     318183424ull
#define PACK2_TOTAL (2*BFI_USH + 19*512 + FEAT*HID)

// =============== fallback (round-3) layout, float offsets =========
#define SZ_BF   (NN*8*4*8*512)
#define OFF_W1T_O (SZ_BF/2)
#define SZ_W1T  (FEAT*HID)
#define OFF_HF_O  (OFF_W1T_O + SZ_W1T)
#define PACK_TOTAL_O (SZ_BF + SZ_W1T)

__device__ __forceinline__ unsigned short f2bf(float x) {
    union { float f; unsigned u; } v; v.f = x;
    unsigned r = v.u + 0x7FFF + ((v.u >> 16) & 1);   // RNE
    return (unsigned short)(r >> 16);
}
#define LOG2E 1.4426950408889634f
__device__ __forceinline__ float sigf(float x) {
    return __builtin_amdgcn_rcpf(1.f + __builtin_amdgcn_exp2f(-LOG2E * x));
}
__device__ __forceinline__ float tnhf(float x) {
    return 1.f - 2.f * __builtin_amdgcn_rcpf(__builtin_amdgcn_exp2f(2.f * LOG2E * x) + 1.f);
}

// lgkm-only barrier: LDS ordered; global loads/stores stay in flight.
__device__ __forceinline__ void lgkm_barrier() {
    asm volatile("s_waitcnt lgkmcnt(0)" ::: "memory");
    __builtin_amdgcn_s_barrier();
    asm volatile("" ::: "memory");
}

// ======================= V2 kernels ===============================

// Pack W_ih frags, W_hh frags (f16), combined bias, W1T.
__global__ __launch_bounds__(256) void pack2_kernel(
        const float* __restrict__ W_ih, const float* __restrict__ W_hh,
        const float* __restrict__ b_ih, const float* __restrict__ b_hh,
        const float* __restrict__ W1, char* __restrict__ wsb) {
    int id = blockIdx.x * 256 + threadIdx.x;
    if (id < 2 * BFI_USH) {
        int which = id >= BFI_USH;                 // 0 = W_ih, 1 = W_hh
        int i = which ? id - BFI_USH : id;
        int e    = i & 7;
        int lane = (i >> 3) & 63;
        int kt   = (i >> 9) & 3;
        int nt   = (i >> 11) & 3;
        int hb   = (i >> 13) & 7;
        int n    = i >> 16;
        int k = kt * 32 + (lane >> 4) * 8 + e;
        int g = nt * 128 + hb * 16 + (lane & 15);
        float v;
        if (which) v = W_hh[((size_t)n * 512 + g) * HID + k];
        else       v = (k < DIN) ? W_ih[((size_t)n * 512 + g) * DIN + k] : 0.f;
        reinterpret_cast<_Float16*>(wsb)[id] = (_Float16)v;
        return;
    }
    int id2 = id - 2 * BFI_USH;
    if (id2 < NN * 512) {
        reinterpret_cast<float*>(wsb + V2_OFF_BIAS)[id2] = b_ih[id2] + b_hh[id2];
        return;
    }
    int id3 = id2 - NN * 512;
    if (id3 < FEAT * HID) {
        int j = id3 & 127, k = id3 >> 7;
        reinterpret_cast<float*>(wsb + V2_OFF_W1T)[id3] = W1[(size_t)j * FEAT + k];
    }
}

// xg3: chunk-staged x-projection. grid = (n, bq, tchunk of 10), 512 thr.
// Stage 16 rows x 10 t x 100 d fp32 -> f16 LDS [16][10*104] with
// COALESCED float4 loads (one __syncthreads), then 8 waves compute
// 10 t each barrier-free: 4 ds_read_b128 + 16 MFMA + 2 stores per t.
// Identical cast + MFMA order as before -> bitwise-identical xg.
#define XC 10                          // timesteps per chunk
#define XROWB 2080                     // row stride bytes: 10*104*2
#define ZPAD  33280                    // 16*2080; 16B zero region follows
__global__ __launch_bounds__(512, 2) void xg3_kernel(
        const float* __restrict__ inp, const char* __restrict__ wsb,
        _Float16* __restrict__ xg) {
    __shared__ alignas(16) char xa[ZPAD + 16];

    const int tid  = threadIdx.x;
    const int lane = tid & 63;
    const int w    = tid >> 6;
    const int l15  = lane & 15;
    const int g4   = lane >> 4;
    const int blk  = blockIdx.x;
    const int tc   = blk % 25;
    const int bq   = (blk / 25) & 3;
    const int n    = blk / 100;
    const int t0   = tc * XC;
    const int j    = w * 16 + l15;

    // W_ih frags, register-resident (16 h8v)
    h8v bf[4][4];
    {
        const _Float16* wp = reinterpret_cast<const _Float16*>(wsb)
                             + ((size_t)(n * 8 + w) * 16) * 512 + lane * 8;
        #pragma unroll
        for (int nt = 0; nt < 4; ++nt)
            #pragma unroll
            for (int kt = 0; kt < 4; ++kt)
                bf[nt][kt] = *reinterpret_cast<const h8v*>(wp + (nt * 4 + kt) * 512);
    }
    float bs[4];
    #pragma unroll
    for (int nt = 0; nt < 4; ++nt)
        bs[nt] = reinterpret_cast<const float*>(wsb + V2_OFF_BIAS)[n * 512 + nt * 128 + j];

    // ---- zero pads: k in [100,104) per (r,t), plus the 16B zpad ----
    if (tid < 160) {
        int r = tid / XC, t = tid - r * XC;
        *reinterpret_cast<h4v*>(xa + r * XROWB + t * 208 + 200) =
            (h4v){(_Float16)0.f, (_Float16)0.f, (_Float16)0.f, (_Float16)0.f};
    } else if (tid < 162) {
        *reinterpret_cast<h4v*>(xa + ZPAD + (tid - 160) * 8) =
            (h4v){(_Float16)0.f, (_Float16)0.f, (_Float16)0.f, (_Float16)0.f};
    }

    // ---- stage: 4000 float4, coalesced per row ----
    // i -> row r = i/250, rem = i%250, t = rem/25, d4 = rem%25 (d = d4*4)
    for (int i = tid; i < 16 * 250; i += 512) {
        int r   = i / 250;
        int rem = i - r * 250;
        int t   = rem / 25;
        int d4  = rem - t * 25;
        const float* src = inp + ((size_t)(bq * 16 + r) * NN + n) * (TT * DIN)
                           + (size_t)(t0 + t) * DIN + d4 * 4;
        float4 v = *reinterpret_cast<const float4*>(src);
        *reinterpret_cast<h4v*>(xa + r * XROWB + t * 208 + d4 * 8) =
            (h4v){(_Float16)v.x, (_Float16)v.y, (_Float16)v.z, (_Float16)v.w};
    }
    __syncthreads();

    // ---- compute: barrier-free ----
    const int arow = l15 * XROWB;
    _Float16* xout = xg + ((size_t)((n * 4 + bq) * 250 + t0)) * 8192
                     + (w * 64 + lane) * 16;

    for (int t = 0; t < XC; ++t) {
        const char* base = xa + arow + t * 208;
        h8v a0 = *reinterpret_cast<const h8v*>(base + g4 * 16);
        h8v a1 = *reinterpret_cast<const h8v*>(base + 64 + g4 * 16);
        h8v a2 = *reinterpret_cast<const h8v*>(base + 128 + g4 * 16);
        h8v a3 = (g4 == 0)
            ? *reinterpret_cast<const h8v*>(base + 192)
            : *reinterpret_cast<const h8v*>(xa + ZPAD);

        f4v acc[4];
        #pragma unroll
        for (int nt = 0; nt < 4; ++nt)
            acc[nt] = (f4v){bs[nt], bs[nt], bs[nt], bs[nt]};
        #pragma unroll
        for (int nt = 0; nt < 4; ++nt)
            acc[nt] = __builtin_amdgcn_mfma_f32_16x16x32_f16(a0, bf[nt][0], acc[nt], 0, 0, 0);
        #pragma unroll
        for (int nt = 0; nt < 4; ++nt)
            acc[nt] = __builtin_amdgcn_mfma_f32_16x16x32_f16(a1, bf[nt][1], acc[nt], 0, 0, 0);
        #pragma unroll
        for (int nt = 0; nt < 4; ++nt)
            acc[nt] = __builtin_amdgcn_mfma_f32_16x16x32_f16(a2, bf[nt][2], acc[nt], 0, 0, 0);
        #pragma unroll
        for (int nt = 0; nt < 4; ++nt)
            acc[nt] = __builtin_amdgcn_mfma_f32_16x16x32_f16(a3, bf[nt][3], acc[nt], 0, 0, 0);

        h8v s0, s1;
        #pragma unroll
        for (int nt = 0; nt < 4; ++nt) {
            s0[nt]     = (_Float16)acc[nt][0];
            s0[4 + nt] = (_Float16)acc[nt][1];
            s1[nt]     = (_Float16)acc[nt][2];
            s1[4 + nt] = (_Float16)acc[nt][3];
        }
        *reinterpret_cast<h8v*>(xout + (size_t)t * 8192)     = s0;
        *reinterpret_cast<h8v*>(xout + (size_t)t * 8192 + 8) = s1;
    }
}

// Recurrence v7 (round-10 exact, 176 us): 152 WGs, 8 waves, nt-major
// MFMA + early nonlin, lgkm-only barrier, 2-deep xg prefetch.
__global__ __launch_bounds__(512, 2) void lstm7_kernel(
        const char* __restrict__ wsb, const _Float16* __restrict__ xg,
        float* __restrict__ hf) {
    __shared__ alignas(16) _Float16 xh[2][16 * 128];

    const int tid  = threadIdx.x;
    const int lane = tid & 63;
    const int w8   = tid >> 6;          // 0..7
    const int l15  = lane & 15;
    const int g4   = lane >> 4;
    const int n    = blockIdx.x >> 3;
    const int oct  = blockIdx.x & 7;
    const int bq   = oct >> 1;
    const int hi   = oct & 1;
    const int hb   = w8;
    const int j    = hb * 16 + l15;

    h8v bf[4][4];
    {
        const _Float16* wp = reinterpret_cast<const _Float16*>(wsb + V2_OFF_BFH)
                             + (size_t)lane * 8;
        #pragma unroll
        for (int nt = 0; nt < 4; ++nt)
            #pragma unroll
            for (int kt = 0; kt < 4; ++kt)
                bf[nt][kt] = *reinterpret_cast<const h8v*>(
                    wp + ((size_t)((n * 8 + hb) * 16 + nt * 4 + kt)) * 512);
    }

    float c2[2] = {0.f, 0.f};
    float h2[2] = {0.f, 0.f};

    for (int i = tid; i < 2 * 16 * 128; i += 512) (&xh[0][0])[i] = (_Float16)0.f;

    const _Float16* xp = xg + ((size_t)((n * 4 + bq) * 250)) * 8192
        + (size_t)(hb * 64 + l15 + 16 * (hi * 2 + (g4 & 1))) * 16
        + (g4 >> 1) * 8;

    const int arow = l15 * 256;
    const int aswz = ((l15 & 1) << 4) | (((l15 >> 2) & 3) << 5);
    const int wr0 = (g4 * 4) * 256 + ((2 * j) ^ (g4 << 5));
    const int wr1 = (g4 * 4 + 1) * 256 + ((2 * j) ^ 16 ^ (g4 << 5));

    h8v p  = *reinterpret_cast<const h8v*>(xp);
    h8v qn = *reinterpret_cast<const h8v*>(xp + 8192);
    lgkm_barrier();

    #pragma unroll 2
    for (int t = 0; t < TT; ++t) {
        char* rc = reinterpret_cast<char*>(xh[t & 1]);
        char* wc = reinterpret_cast<char*>(xh[(t + 1) & 1]);

        f4v acc[4];
        #pragma unroll
        for (int nt = 0; nt < 4; ++nt)
            acc[nt] = (f4v){(float)p[nt], (float)p[4 + nt], 0.f, 0.f};

        int tn = t + 2 < TT ? t + 2 : TT - 1;
        h8v rn = *reinterpret_cast<const h8v*>(xp + (size_t)tn * 8192);

        h8v a0 = *reinterpret_cast<const h8v*>(rc + arow + ((0 * 64 + g4 * 16) ^ aswz));
        h8v a1 = *reinterpret_cast<const h8v*>(rc + arow + ((1 * 64 + g4 * 16) ^ aswz));
        h8v a2 = *reinterpret_cast<const h8v*>(rc + arow + ((2 * 64 + g4 * 16) ^ aswz));
        h8v a3 = *reinterpret_cast<const h8v*>(rc + arow + ((3 * 64 + g4 * 16) ^ aswz));

        acc[0] = __builtin_amdgcn_mfma_f32_16x16x32_f16(a0, bf[0][0], acc[0], 0, 0, 0);
        acc[0] = __builtin_amdgcn_mfma_f32_16x16x32_f16(a1, bf[0][1], acc[0], 0, 0, 0);
        acc[0] = __builtin_amdgcn_mfma_f32_16x16x32_f16(a2, bf[0][2], acc[0], 0, 0, 0);
        acc[0] = __builtin_amdgcn_mfma_f32_16x16x32_f16(a3, bf[0][3], acc[0], 0, 0, 0);
        float ii0 = sigf(acc[0][0]);
        float ii1 = sigf(acc[0][1]);

        acc[1] = __builtin_amdgcn_mfma_f32_16x16x32_f16(a0, bf[1][0], acc[1], 0, 0, 0);
        acc[1] = __builtin_amdgcn_mfma_f32_16x16x32_f16(a1, bf[1][1], acc[1], 0, 0, 0);
        acc[1] = __builtin_amdgcn_mfma_f32_16x16x32_f16(a2, bf[1][2], acc[1], 0, 0, 0);
        acc[1] = __builtin_amdgcn_mfma_f32_16x16x32_f16(a3, bf[1][3], acc[1], 0, 0, 0);
        float ff0 = sigf(acc[1][0]);
        float ff1 = sigf(acc[1][1]);

        acc[2] = __builtin_amdgcn_mfma_f32_16x16x32_f16(a0, bf[2][0], acc[2], 0, 0, 0);
        acc[2] = __builtin_amdgcn_mfma_f32_16x16x32_f16(a1, bf[2][1], acc[2], 0, 0, 0);
        acc[2] = __builtin_amdgcn_mfma_f32_16x16x32_f16(a2, bf[2][2], acc[2], 0, 0, 0);
        acc[2] = __builtin_amdgcn_mfma_f32_16x16x32_f16(a3, bf[2][3], acc[2], 0, 0, 0);
        float gg0 = tnhf(acc[2][0]);
        float gg1 = tnhf(acc[2][1]);

        acc[3] = __builtin_amdgcn_mfma_f32_16x16x32_f16(a0, bf[3][0], acc[3], 0, 0, 0);
        acc[3] = __builtin_amdgcn_mfma_f32_16x16x32_f16(a1, bf[3][1], acc[3], 0, 0, 0);
        acc[3] = __builtin_amdgcn_mfma_f32_16x16x32_f16(a2, bf[3][2], acc[3], 0, 0, 0);
        acc[3] = __builtin_amdgcn_mfma_f32_16x16x32_f16(a3, bf[3][3], acc[3], 0, 0, 0);
        float oo0 = sigf(acc[3][0]);
        float oo1 = sigf(acc[3][1]);

        float cn0 = ff0 * c2[0] + ii0 * gg0;
        c2[0] = cn0;
        float hn0 = oo0 * tnhf(cn0);
        h2[0] = hn0;
        *reinterpret_cast<_Float16*>(wc + wr0) = (_Float16)hn0;

        float cn1 = ff1 * c2[1] + ii1 * gg1;
        c2[1] = cn1;
        float hn1 = oo1 * tnhf(cn1);
        h2[1] = hn1;
        *reinterpret_cast<_Float16*>(wc + wr1) = (_Float16)hn1;

        p = qn; qn = rn;
        lgkm_barrier();
    }

    #pragma unroll
    for (int q = 0; q < 2; ++q) {
        int b = bq * 16 + hi * 8 + (g4 & 1) * 4 + (g4 >> 1) * 2 + q;
        hf[((size_t)b * NN + n) * HID + j] = h2[q];
    }
}

// Head: 64 blocks (one per batch row), 256 thr, split-K over 2 halves.
__global__ __launch_bounds__(256) void head2_kernel(
        const float* __restrict__ hf, const float* __restrict__ w1t,
        const float* __restrict__ b1, const float* __restrict__ W2,
        const float* __restrict__ b2, float* __restrict__ out) {
    __shared__ float comb[FEAT];
    __shared__ float par[2][HID];
    __shared__ float hid[HID];
    const int b = blockIdx.x;
    const int u  = threadIdx.x & 127;
    const int kk = threadIdx.x >> 7;
    const float* hfp = hf + (size_t)b * FEAT;
    for (int i = threadIdx.x; i < FEAT; i += 256) comb[i] = hfp[i];
    __syncthreads();

    const int k0 = kk * (FEAT / 2);
    float acc = 0.f;
    #pragma unroll 8
    for (int k = 0; k < FEAT / 2; ++k)
        acc = fmaf(comb[k0 + k], w1t[(size_t)(k0 + k) * HID + u], acc);
    par[kk][u] = acc;
    __syncthreads();
    if (kk == 0) hid[u] = fmaxf(par[0][u] + par[1][u] + b1[u], 0.f);
    __syncthreads();

    if (threadIdx.x < NC) {
        int cls = threadIdx.x;
        float a = b2[cls];
        #pragma unroll 4
        for (int k = 0; k < HID; ++k)
            a = fmaf(hid[k], W2[cls * HID + k], a);
        out[b * NC + cls] = a;
    }
}

// ======================= fallback (round-3) =======================
__global__ __launch_bounds__(256) void packfb_kernel(
        const float* __restrict__ W_ih, const float* __restrict__ W_hh,
        const float* __restrict__ W1,
        unsigned short* __restrict__ bfw, float* __restrict__ w1t) {
    int id = blockIdx.x * 256 + threadIdx.x;
    if (id < SZ_BF) {
        int e    = id & 7;
        int lane = (id >> 3) & 63;
        int kt   = (id >> 9) & 7;
        int nt   = (id >> 12) & 3;
        int hb   = (id >> 14) & 7;
        int n    = id >> 17;
        int k = kt * 32 + (lane >> 4) * 8 + e;
        int g = nt * 128 + hb * 16 + (lane & 15);
        float v = 0.f;
        if (k < DIN)       v = W_ih[((size_t)n * 512 + g) * DIN + k];
        else if (k < 228)  v = W_hh[((size_t)n * 512 + g) * HID + (k - DIN)];
        bfw[id] = f2bf(v);
        return;
    }
    int id3 = id - SZ_BF;
    if (id3 < SZ_W1T) {
        int j = id3 & 127, k = id3 >> 7;
        w1t[id3] = W1[(size_t)j * FEAT + k];
    }
}

__global__ __launch_bounds__(512, 2) void lstmfb_kernel(
        const float* __restrict__ inp,
        const float* __restrict__ b_ih, const float* __restrict__ b_hh,
        const unsigned short* __restrict__ bfw, float* __restrict__ hf) {
    __shared__ alignas(16) unsigned short xh[2][16 * 256];
    const int tid  = threadIdx.x;
    const int lane = tid & 63;
    const int w    = tid >> 6;
    const int l15  = lane & 15;
    const int g4   = lane >> 4;
    const int n    = blockIdx.x >> 2;
    const int bq   = blockIdx.x & 3;
    const int j    = w * 16 + l15;

    s8v bf[4][8];
    const unsigned short* wp = bfw + ((size_t)(n * 8 + w) * 32) * 512 + lane * 8;
    #pragma unroll
    for (int nt = 0; nt < 4; ++nt)
        #pragma unroll
        for (int kt = 0; kt < 8; ++kt)
            bf[nt][kt] = *reinterpret_cast<const s8v*>(wp + (nt * 8 + kt) * 512);

    float bs[4];
    #pragma unroll
    for (int nt = 0; nt < 4; ++nt)
        bs[nt] = b_ih[n * 512 + nt * 128 + j] + b_hh[n * 512 + nt * 128 + j];

    float c[4] = {0.f, 0.f, 0.f, 0.f};
    float h[4] = {0.f, 0.f, 0.f, 0.f};
    for (int i = tid; i < 2 * 16 * 256; i += 512) (&xh[0][0])[i] = 0;

    const bool st = tid < 400;
    const int row = st ? tid / 25 : 0;
    const int c4  = st ? tid - row * 25 : 0;
    const float* xb = inp + ((size_t)(bq * 16 + row) * NN + n) * (TT * DIN) + c4 * 4;
    const int wofs = row * 512 + ((c4 * 8) ^ ((row & 7) << 4));
    const int arow = l15 * 512;
    const int aswz = (l15 & 7) << 4;

    __syncthreads();
    if (st) {
        float4 v = *reinterpret_cast<const float4*>(xb);
        unsigned lo = f2bf(v.x) | ((unsigned)f2bf(v.y) << 16);
        unsigned hi = f2bf(v.z) | ((unsigned)f2bf(v.w) << 16);
        *reinterpret_cast<uint2*>(reinterpret_cast<char*>(xh[0]) + wofs) =
            make_uint2(lo, hi);
    }
    __syncthreads();

    for (int t = 0; t < TT; ++t) {
        char* rc = reinterpret_cast<char*>(xh[t & 1]);
        char* wc = reinterpret_cast<char*>(xh[(t + 1) & 1]);
        float4 nxt = make_float4(0.f, 0.f, 0.f, 0.f);
        if (t < TT - 1 && st)
            nxt = *reinterpret_cast<const float4*>(xb + (t + 1) * DIN);

        f4v acc[4];
        #pragma unroll
        for (int nt = 0; nt < 4; ++nt)
            acc[nt] = (f4v){bs[nt], bs[nt], bs[nt], bs[nt]};
        #pragma unroll
        for (int kt = 0; kt < 8; ++kt) {
            s8v a = *reinterpret_cast<const s8v*>(rc + arow + ((kt * 64 + g4 * 16) ^ aswz));
            #pragma unroll
            for (int nt = 0; nt < 4; ++nt)
                acc[nt] = __builtin_amdgcn_mfma_f32_16x16x32_bf16(a, bf[nt][kt], acc[nt], 0, 0, 0);
        }
        #pragma unroll
        for (int r = 0; r < 4; ++r) {
            float ii = sigf(acc[0][r]);
            float ff = sigf(acc[1][r]);
            float gg = tnhf(acc[2][r]);
            float oo = sigf(acc[3][r]);
            float cn = ff * c[r] + ii * gg;
            c[r] = cn;
            float hn = oo * tnhf(cn);
            h[r] = hn;
            int rr = g4 * 4 + r;
            *reinterpret_cast<unsigned short*>(
                wc + rr * 512 + (((DIN + j) * 2) ^ ((rr & 7) << 4))) = f2bf(hn);
        }
        if (t < TT - 1 && st) {
            unsigned lo = f2bf(nxt.x) | ((unsigned)f2bf(nxt.y) << 16);
            unsigned hi = f2bf(nxt.z) | ((unsigned)f2bf(nxt.w) << 16);
            *reinterpret_cast<uint2*>(wc + wofs) = make_uint2(lo, hi);
        }
        __syncthreads();
    }
    #pragma unroll
    for (int r = 0; r < 4; ++r) {
        int b = bq * 16 + g4 * 4 + r;
        hf[((size_t)b * NN + n) * HID + j] = h[r];
    }
}

// ============================ launch ==============================
extern "C" void kernel_launch(void* const* d_in, const int* in_sizes, int n_in,
                              void* d_out, int out_size, void* d_ws, size_t ws_size,
                              hipStream_t stream) {
    const float* inp  = (const float*)d_in[0];
    const float* W_ih = (const float*)d_in[2];
    const float* W_hh = (const float*)d_in[3];
    const float* b_ih = (const float*)d_in[4];
    const float* b_hh = (const float*)d_in[5];
    const float* W1   = (const float*)d_in[6];
    const float* b1   = (const float*)d_in[7];
    const float* W2   = (const float*)d_in[8];
    const float* b2   = (const float*)d_in[9];
    float* out = (float*)d_out;

    if (ws_size >= V2_NEED) {
        char* wsb = (char*)d_ws;
        _Float16* xg = (_Float16*)(wsb + V2_OFF_XG);
        float* hf    = (float*)(wsb + V2_OFF_HF);
        float* w1t   = (float*)(wsb + V2_OFF_W1T);
        pack2_kernel<<<(PACK2_TOTAL + 255) / 256, 256, 0, stream>>>(
            W_ih, W_hh, b_ih, b_hh, W1, wsb);
        xg3_kernel<<<NN * 4 * 25, 512, 0, stream>>>(inp, wsb, xg);
        lstm7_kernel<<<NN * 8, 512, 0, stream>>>(wsb, xg, hf);
        head2_kernel<<<BB, 256, 0, stream>>>(hf, w1t, b1, W2, b2, out);
    } else {
        float* ws = (float*)d_ws;
        unsigned short* bfw = (unsigned short*)d_ws;
        packfb_kernel<<<(PACK_TOTAL_O + 255) / 256, 256, 0, stream>>>(
            W_ih, W_hh, W1, bfw, ws + OFF_W1T_O);
        lstmfb_kernel<<<NN * 4, 512, 0, stream>>>(inp, b_ih, b_hh, bfw, ws + OFF_HF_O);
        head2_kernel<<<BB, 256, 0, stream>>>(ws + OFF_HF_O, ws + OFF_W1T_O,
                                             b1, W2, b2, out);
    }
}

// Round 16
// 333.063 us; speedup vs baseline: 1.2937x; 1.0858x over previous
//
#include <hip/hip_runtime.h>
#include <hip/hip_bf16.h>

#define NN   19
#define DIN  100
#define HID  128
#define TT   250
#define BB   64
#define NC   4
#define FEAT 2432          // NN*HID

typedef __attribute__((ext_vector_type(8))) short s8v;
typedef __attribute__((ext_vector_type(4))) float f4v;
typedef _Float16 h8v __attribute__((ext_vector_type(8)));
typedef _Float16 h4v __attribute__((ext_vector_type(4)));

// =============== V2 workspace layout (byte offsets) ===============
// BFI: W_ih MFMA B-frags f16  (19*8*4*4*512 halfs; per node 65536 halfs)
// BFH: W_hh MFMA B-frags f16  (same count)
// BIAS: combined b_ih+b_hh f32 (19*512)
// W1T: W1 transposed f32 (2432*128) ; HF: final hidden f32 (64*2432)
#define BFI_USH   1245184
#define V2_OFF_BFI  0ull
#define V2_OFF_BFH  2490368ull
#define V2_OFF_BIAS 4980736ull
#define V2_OFF_W1T  5019648ull
#define V2_OFF_HF   6264832ull
#define V2_NEED     6887424ull
#define PACK2_TOTAL (2*BFI_USH + 19*512 + FEAT*HID)

// =============== fallback (round-3) layout, float offsets =========
#define SZ_BF   (NN*8*4*8*512)
#define OFF_W1T_O (SZ_BF/2)
#define SZ_W1T  (FEAT*HID)
#define OFF_HF_O  (OFF_W1T_O + SZ_W1T)
#define PACK_TOTAL_O (SZ_BF + SZ_W1T)

// A-tile row stride: 264 f16 = 528 B = 132 words == 4 (mod 32 banks).
// Successive rows shift 4 banks -> any fixed col-slot read across 16 rows
// is at worst 2-way (rows r, r+8 alias) = free. No XOR swizzle needed.
#define RSTR 528

__device__ __forceinline__ unsigned short f2bf(float x) {
    union { float f; unsigned u; } v; v.f = x;
    unsigned r = v.u + 0x7FFF + ((v.u >> 16) & 1);   // RNE
    return (unsigned short)(r >> 16);
}
#define LOG2E 1.4426950408889634f
__device__ __forceinline__ float sigf(float x) {
    return __builtin_amdgcn_rcpf(1.f + __builtin_amdgcn_exp2f(-LOG2E * x));
}
__device__ __forceinline__ float tnhf(float x) {
    return 1.f - 2.f * __builtin_amdgcn_rcpf(__builtin_amdgcn_exp2f(2.f * LOG2E * x) + 1.f);
}

// lgkm-only barrier: LDS ordered; global loads/stores stay in flight.
__device__ __forceinline__ void lgkm_barrier() {
    asm volatile("s_waitcnt lgkmcnt(0)" ::: "memory");
    __builtin_amdgcn_s_barrier();
    asm volatile("" ::: "memory");
}

// ======================= V2 kernels ===============================

// Pack W_ih frags, W_hh frags (f16), combined bias, W1T.
// Frag element (n, hb, nt, kt, lane, e) = W[k][g]:
// k = kt*32+(lane>>4)*8+e, g = nt*128+hb*16+(lane&15).
__global__ __launch_bounds__(256) void pack2_kernel(
        const float* __restrict__ W_ih, const float* __restrict__ W_hh,
        const float* __restrict__ b_ih, const float* __restrict__ b_hh,
        const float* __restrict__ W1, char* __restrict__ wsb) {
    int id = blockIdx.x * 256 + threadIdx.x;
    if (id < 2 * BFI_USH) {
        int which = id >= BFI_USH;                 // 0 = W_ih, 1 = W_hh
        int i = which ? id - BFI_USH : id;
        int e    = i & 7;
        int lane = (i >> 3) & 63;
        int kt   = (i >> 9) & 3;
        int nt   = (i >> 11) & 3;
        int hb   = (i >> 13) & 7;
        int n    = i >> 16;
        int k = kt * 32 + (lane >> 4) * 8 + e;
        int g = nt * 128 + hb * 16 + (lane & 15);
        float v;
        if (which) v = W_hh[((size_t)n * 512 + g) * HID + k];
        else       v = (k < DIN) ? W_ih[((size_t)n * 512 + g) * DIN + k] : 0.f;
        reinterpret_cast<_Float16*>(wsb)[id] = (_Float16)v;
        return;
    }
    int id2 = id - 2 * BFI_USH;
    if (id2 < NN * 512) {
        reinterpret_cast<float*>(wsb + V2_OFF_BIAS)[id2] = b_ih[id2] + b_hh[id2];
        return;
    }
    int id3 = id2 - NN * 512;
    if (id3 < FEAT * HID) {
        int j = id3 & 127, k = id3 >> 7;
        reinterpret_cast<float*>(wsb + V2_OFF_W1T)[id3] = W1[(size_t)j * FEAT + k];
    }
}

// Fused recurrence v11 = round-11 lstm8 + padded-stride A-tile (no XOR).
// grid 152 = (n, batch-octet). 512 thr = 8 waves, wave hb owns 16 hidden j.
// Gate GEMM fused over K=256 ([x|h]): W_hh frags in regs, W_ih frags in
// LDS (128 KB, loaded once), x(t) staged by 200 threads (1-step prefetch).
// A-tile [16][264] f16 (row stride 528 B, bank-shift 4/row -> conflicts
// <=2-way everywhere). Tile map: tile row g4*4+q (q=0,1) holds real octet
// row R=(g4&1)*4+(g4>>1)*2+q; other rows stay zero. nt-major h-MFMA with
// early per-gate nonlinearity; lgkm-only barrier (1/step).
__global__ __launch_bounds__(512, 2) void lstm8b_kernel(
        const char* __restrict__ wsb, const float* __restrict__ inp,
        float* __restrict__ hf) {
    __shared__ alignas(16) _Float16 wih[8 * 16 * 512];   // 128 KB
    __shared__ alignas(16) _Float16 xh[2][16 * 264];     // 2 x 8.25 KB

    const int tid  = threadIdx.x;
    const int lane = tid & 63;
    const int w8   = tid >> 6;          // 0..7
    const int l15  = lane & 15;
    const int g4   = lane >> 4;
    const int n    = blockIdx.x >> 3;
    const int oct  = blockIdx.x & 7;
    const int bq   = oct >> 1;
    const int hi   = oct & 1;
    const int hb   = w8;
    const int j    = hb * 16 + l15;

    // W_hh frags in regs (16 h8v)
    h8v bf[4][4];
    {
        const _Float16* wp = reinterpret_cast<const _Float16*>(wsb + V2_OFF_BFH)
                             + (size_t)lane * 8;
        #pragma unroll
        for (int nt = 0; nt < 4; ++nt)
            #pragma unroll
            for (int kt = 0; kt < 4; ++kt)
                bf[nt][kt] = *reinterpret_cast<const h8v*>(
                    wp + ((size_t)((n * 8 + hb) * 16 + nt * 4 + kt)) * 512);
    }
    float bs[4];
    #pragma unroll
    for (int nt = 0; nt < 4; ++nt)
        bs[nt] = reinterpret_cast<const float*>(wsb + V2_OFF_BIAS)[n * 512 + nt * 128 + j];

    // W_ih frags -> LDS (128 KB, coalesced; reads later are lane-contiguous
    // 1024 B per wave = conflict-free)
    {
        const h8v* src = reinterpret_cast<const h8v*>(
            reinterpret_cast<const _Float16*>(wsb + V2_OFF_BFI) + (size_t)n * 65536);
        h8v* dst = reinterpret_cast<h8v*>(wih);
        for (int i = tid; i < 8192; i += 512) dst[i] = src[i];
    }
    // zero xh (both buffers; dead rows + pads must stay 0)
    for (int i = tid; i < 2 * 16 * 264; i += 512) (&xh[0][0])[i] = (_Float16)0.f;

    // x staging: 200 threads, 8 live tile rows x 25 float4
    const bool st = tid < 200;
    const int sr  = st ? tid / 25 : 0;
    const int c4  = st ? tid - sr * 25 : 0;
    const int g4s = sr >> 1, qs = sr & 1;
    const int tr  = g4s * 4 + qs;                         // live tile row
    const int Rr  = (g4s & 1) * 4 + (g4s >> 1) * 2 + qs;  // real octet row
    const float* xb = inp + (size_t)((bq * 16 + hi * 8 + Rr) * NN + n) * (TT * DIN)
                      + c4 * 4;
    const int wofs_x = tr * RSTR + c4 * 8;

    const int arow = l15 * RSTR;
    const int wr0 = (g4 * 4) * RSTR + 256 + 2 * j;
    const int wr1 = (g4 * 4 + 1) * RSTR + 256 + 2 * j;
    const char* wfb = reinterpret_cast<const char*>(wih) + hb * 16384 + lane * 16;

    float c2[2] = {0.f, 0.f};
    float h2[2] = {0.f, 0.f};

    __syncthreads();
    if (st) {   // stage x(0) into buffer 0
        float4 v = *reinterpret_cast<const float4*>(xb);
        h4v pk = {(_Float16)v.x, (_Float16)v.y, (_Float16)v.z, (_Float16)v.w};
        *reinterpret_cast<h4v*>(reinterpret_cast<char*>(xh[0]) + wofs_x) = pk;
    }
    __syncthreads();

    #pragma unroll 2
    for (int t = 0; t < TT; ++t) {
        char* rc = reinterpret_cast<char*>(xh[t & 1]);
        char* wc = reinterpret_cast<char*>(xh[(t + 1) & 1]);

        // issue x(t+1) load early; lgkm barriers never drain vmcnt
        float4 nxt = make_float4(0.f, 0.f, 0.f, 0.f);
        if (t < TT - 1 && st)
            nxt = *reinterpret_cast<const float4*>(xb + (t + 1) * DIN);

        f4v acc[4];
        #pragma unroll
        for (int nt = 0; nt < 4; ++nt)
            acc[nt] = (f4v){bs[nt], bs[nt], 0.f, 0.f};

        // ---- phase X: x-part A frags + W_ih (LDS) MFMAs ----
        h8v ax0 = *reinterpret_cast<const h8v*>(rc + arow + (0 * 64 + g4 * 16));
        h8v ax1 = *reinterpret_cast<const h8v*>(rc + arow + (1 * 64 + g4 * 16));
        h8v ax2 = *reinterpret_cast<const h8v*>(rc + arow + (2 * 64 + g4 * 16));
        h8v ax3 = *reinterpret_cast<const h8v*>(rc + arow + (3 * 64 + g4 * 16));
        #pragma unroll
        for (int nt = 0; nt < 4; ++nt) {
            h8v w0 = *reinterpret_cast<const h8v*>(wfb + (nt * 4 + 0) * 1024);
            h8v w1 = *reinterpret_cast<const h8v*>(wfb + (nt * 4 + 1) * 1024);
            h8v w2 = *reinterpret_cast<const h8v*>(wfb + (nt * 4 + 2) * 1024);
            h8v w3 = *reinterpret_cast<const h8v*>(wfb + (nt * 4 + 3) * 1024);
            acc[nt] = __builtin_amdgcn_mfma_f32_16x16x32_f16(ax0, w0, acc[nt], 0, 0, 0);
            acc[nt] = __builtin_amdgcn_mfma_f32_16x16x32_f16(ax1, w1, acc[nt], 0, 0, 0);
            acc[nt] = __builtin_amdgcn_mfma_f32_16x16x32_f16(ax2, w2, acc[nt], 0, 0, 0);
            acc[nt] = __builtin_amdgcn_mfma_f32_16x16x32_f16(ax3, w3, acc[nt], 0, 0, 0);
        }

        // ---- phase H: h-part A frags + W_hh (reg) MFMAs, early nonlin ----
        h8v ah0 = *reinterpret_cast<const h8v*>(rc + arow + (256 + 0 * 64 + g4 * 16));
        h8v ah1 = *reinterpret_cast<const h8v*>(rc + arow + (256 + 1 * 64 + g4 * 16));
        h8v ah2 = *reinterpret_cast<const h8v*>(rc + arow + (256 + 2 * 64 + g4 * 16));
        h8v ah3 = *reinterpret_cast<const h8v*>(rc + arow + (256 + 3 * 64 + g4 * 16));

        acc[0] = __builtin_amdgcn_mfma_f32_16x16x32_f16(ah0, bf[0][0], acc[0], 0, 0, 0);
        acc[0] = __builtin_amdgcn_mfma_f32_16x16x32_f16(ah1, bf[0][1], acc[0], 0, 0, 0);
        acc[0] = __builtin_amdgcn_mfma_f32_16x16x32_f16(ah2, bf[0][2], acc[0], 0, 0, 0);
        acc[0] = __builtin_amdgcn_mfma_f32_16x16x32_f16(ah3, bf[0][3], acc[0], 0, 0, 0);
        float ii0 = sigf(acc[0][0]);
        float ii1 = sigf(acc[0][1]);

        acc[1] = __builtin_amdgcn_mfma_f32_16x16x32_f16(ah0, bf[1][0], acc[1], 0, 0, 0);
        acc[1] = __builtin_amdgcn_mfma_f32_16x16x32_f16(ah1, bf[1][1], acc[1], 0, 0, 0);
        acc[1] = __builtin_amdgcn_mfma_f32_16x16x32_f16(ah2, bf[1][2], acc[1], 0, 0, 0);
        acc[1] = __builtin_amdgcn_mfma_f32_16x16x32_f16(ah3, bf[1][3], acc[1], 0, 0, 0);
        float ff0 = sigf(acc[1][0]);
        float ff1 = sigf(acc[1][1]);

        acc[2] = __builtin_amdgcn_mfma_f32_16x16x32_f16(ah0, bf[2][0], acc[2], 0, 0, 0);
        acc[2] = __builtin_amdgcn_mfma_f32_16x16x32_f16(ah1, bf[2][1], acc[2], 0, 0, 0);
        acc[2] = __builtin_amdgcn_mfma_f32_16x16x32_f16(ah2, bf[2][2], acc[2], 0, 0, 0);
        acc[2] = __builtin_amdgcn_mfma_f32_16x16x32_f16(ah3, bf[2][3], acc[2], 0, 0, 0);
        float gg0 = tnhf(acc[2][0]);
        float gg1 = tnhf(acc[2][1]);

        acc[3] = __builtin_amdgcn_mfma_f32_16x16x32_f16(ah0, bf[3][0], acc[3], 0, 0, 0);
        acc[3] = __builtin_amdgcn_mfma_f32_16x16x32_f16(ah1, bf[3][1], acc[3], 0, 0, 0);
        acc[3] = __builtin_amdgcn_mfma_f32_16x16x32_f16(ah2, bf[3][2], acc[3], 0, 0, 0);
        acc[3] = __builtin_amdgcn_mfma_f32_16x16x32_f16(ah3, bf[3][3], acc[3], 0, 0, 0);
        float oo0 = sigf(acc[3][0]);
        float oo1 = sigf(acc[3][1]);

        // state update + h(t+1) writes
        float cn0 = ff0 * c2[0] + ii0 * gg0;
        c2[0] = cn0;
        float hn0 = oo0 * tnhf(cn0);
        h2[0] = hn0;
        *reinterpret_cast<_Float16*>(wc + wr0) = (_Float16)hn0;

        float cn1 = ff1 * c2[1] + ii1 * gg1;
        c2[1] = cn1;
        float hn1 = oo1 * tnhf(cn1);
        h2[1] = hn1;
        *reinterpret_cast<_Float16*>(wc + wr1) = (_Float16)hn1;

        // x(t+1) write into next buffer
        if (t < TT - 1 && st) {
            h4v pk = {(_Float16)nxt.x, (_Float16)nxt.y, (_Float16)nxt.z, (_Float16)nxt.w};
            *reinterpret_cast<h4v*>(wc + wofs_x) = pk;
        }
        lgkm_barrier();
    }

    #pragma unroll
    for (int q = 0; q < 2; ++q) {
        int b = bq * 16 + hi * 8 + (g4 & 1) * 4 + (g4 >> 1) * 2 + q;
        hf[((size_t)b * NN + n) * HID + j] = h2[q];
    }
}

// Head: 64 blocks (one per batch row), 256 thr, split-K over 2 halves.
__global__ __launch_bounds__(256) void head2_kernel(
        const float* __restrict__ hf, const float* __restrict__ w1t,
        const float* __restrict__ b1, const float* __restrict__ W2,
        const float* __restrict__ b2, float* __restrict__ out) {
    __shared__ float comb[FEAT];
    __shared__ float par[2][HID];
    __shared__ float hid[HID];
    const int b = blockIdx.x;
    const int u  = threadIdx.x & 127;
    const int kk = threadIdx.x >> 7;
    const float* hfp = hf + (size_t)b * FEAT;
    for (int i = threadIdx.x; i < FEAT; i += 256) comb[i] = hfp[i];
    __syncthreads();

    const int k0 = kk * (FEAT / 2);
    float acc = 0.f;
    #pragma unroll 8
    for (int k = 0; k < FEAT / 2; ++k)
        acc = fmaf(comb[k0 + k], w1t[(size_t)(k0 + k) * HID + u], acc);
    par[kk][u] = acc;
    __syncthreads();
    if (kk == 0) hid[u] = fmaxf(par[0][u] + par[1][u] + b1[u], 0.f);
    __syncthreads();

    if (threadIdx.x < NC) {
        int cls = threadIdx.x;
        float a = b2[cls];
        #pragma unroll 4
        for (int k = 0; k < HID; ++k)
            a = fmaf(hid[k], W2[cls * HID + k], a);
        out[b * NC + cls] = a;
    }
}

// ======================= fallback (round-3) =======================
__global__ __launch_bounds__(256) void packfb_kernel(
        const float* __restrict__ W_ih, const float* __restrict__ W_hh,
        const float* __restrict__ W1,
        unsigned short* __restrict__ bfw, float* __restrict__ w1t) {
    int id = blockIdx.x * 256 + threadIdx.x;
    if (id < SZ_BF) {
        int e    = id & 7;
        int lane = (id >> 3) & 63;
        int kt   = (id >> 9) & 7;
        int nt   = (id >> 12) & 3;
        int hb   = (id >> 14) & 7;
        int n    = id >> 17;
        int k = kt * 32 + (lane >> 4) * 8 + e;
        int g = nt * 128 + hb * 16 + (lane & 15);
        float v = 0.f;
        if (k < DIN)       v = W_ih[((size_t)n * 512 + g) * DIN + k];
        else if (k < 228)  v = W_hh[((size_t)n * 512 + g) * HID + (k - DIN)];
        bfw[id] = f2bf(v);
        return;
    }
    int id3 = id - SZ_BF;
    if (id3 < SZ_W1T) {
        int j = id3 & 127, k = id3 >> 7;
        w1t[id3] = W1[(size_t)j * FEAT + k];
    }
}

__global__ __launch_bounds__(512, 2) void lstmfb_kernel(
        const float* __restrict__ inp,
        const float* __restrict__ b_ih, const float* __restrict__ b_hh,
        const unsigned short* __restrict__ bfw, float* __restrict__ hf) {
    __shared__ alignas(16) unsigned short xh[2][16 * 256];
    const int tid  = threadIdx.x;
    const int lane = tid & 63;
    const int w    = tid >> 6;
    const int l15  = lane & 15;
    const int g4   = lane >> 4;
    const int n    = blockIdx.x >> 2;
    const int bq   = blockIdx.x & 3;
    const int j    = w * 16 + l15;

    s8v bf[4][8];
    const unsigned short* wp = bfw + ((size_t)(n * 8 + w) * 32) * 512 + lane * 8;
    #pragma unroll
    for (int nt = 0; nt < 4; ++nt)
        #pragma unroll
        for (int kt = 0; kt < 8; ++kt)
            bf[nt][kt] = *reinterpret_cast<const s8v*>(wp + (nt * 8 + kt) * 512);

    float bs[4];
    #pragma unroll
    for (int nt = 0; nt < 4; ++nt)
        bs[nt] = b_ih[n * 512 + nt * 128 + j] + b_hh[n * 512 + nt * 128 + j];

    float c[4] = {0.f, 0.f, 0.f, 0.f};
    float h[4] = {0.f, 0.f, 0.f, 0.f};
    for (int i = tid; i < 2 * 16 * 256; i += 512) (&xh[0][0])[i] = 0;

    const bool st = tid < 400;
    const int row = st ? tid / 25 : 0;
    const int c4  = st ? tid - row * 25 : 0;
    const float* xb = inp + ((size_t)(bq * 16 + row) * NN + n) * (TT * DIN) + c4 * 4;
    const int wofs = row * 512 + ((c4 * 8) ^ ((row & 7) << 4));
    const int arow = l15 * 512;
    const int aswz = (l15 & 7) << 4;

    __syncthreads();
    if (st) {
        float4 v = *reinterpret_cast<const float4*>(xb);
        unsigned lo = f2bf(v.x) | ((unsigned)f2bf(v.y) << 16);
        unsigned hi = f2bf(v.z) | ((unsigned)f2bf(v.w) << 16);
        *reinterpret_cast<uint2*>(reinterpret_cast<char*>(xh[0]) + wofs) =
            make_uint2(lo, hi);
    }
    __syncthreads();

    for (int t = 0; t < TT; ++t) {
        char* rc = reinterpret_cast<char*>(xh[t & 1]);
        char* wc = reinterpret_cast<char*>(xh[(t + 1) & 1]);
        float4 nxt = make_float4(0.f, 0.f, 0.f, 0.f);
        if (t < TT - 1 && st)
            nxt = *reinterpret_cast<const float4*>(xb + (t + 1) * DIN);

        f4v acc[4];
        #pragma unroll
        for (int nt = 0; nt < 4; ++nt)
            acc[nt] = (f4v){bs[nt], bs[nt], bs[nt], bs[nt]};
        #pragma unroll
        for (int kt = 0; kt < 8; ++kt) {
            s8v a = *reinterpret_cast<const s8v*>(rc + arow + ((kt * 64 + g4 * 16) ^ aswz));
            #pragma unroll
            for (int nt = 0; nt < 4; ++nt)
                acc[nt] = __builtin_amdgcn_mfma_f32_16x16x32_bf16(a, bf[nt][kt], acc[nt], 0, 0, 0);
        }
        #pragma unroll
        for (int r = 0; r < 4; ++r) {
            float ii = sigf(acc[0][r]);
            float ff = sigf(acc[1][r]);
            float gg = tnhf(acc[2][r]);
            float oo = sigf(acc[3][r]);
            float cn = ff * c[r] + ii * gg;
            c[r] = cn;
            float hn = oo * tnhf(cn);
            h[r] = hn;
            int rr = g4 * 4 + r;
            *reinterpret_cast<unsigned short*>(
                wc + rr * 512 + (((DIN + j) * 2) ^ ((rr & 7) << 4))) = f2bf(hn);
        }
        if (t < TT - 1 && st) {
            unsigned lo = f2bf(nxt.x) | ((unsigned)f2bf(nxt.y) << 16);
            unsigned hi = f2bf(nxt.z) | ((unsigned)f2bf(nxt.w) << 16);
            *reinterpret_cast<uint2*>(wc + wofs) = make_uint2(lo, hi);
        }
        __syncthreads();
    }
    #pragma unroll
    for (int r = 0; r < 4; ++r) {
        int b = bq * 16 + g4 * 4 + r;
        hf[((size_t)b * NN + n) * HID + j] = h[r];
    }
}

// ============================ launch ==============================
extern "C" void kernel_launch(void* const* d_in, const int* in_sizes, int n_in,
                              void* d_out, int out_size, void* d_ws, size_t ws_size,
                              hipStream_t stream) {
    const float* inp  = (const float*)d_in[0];
    const float* W_ih = (const float*)d_in[2];
    const float* W_hh = (const float*)d_in[3];
    const float* b_ih = (const float*)d_in[4];
    const float* b_hh = (const float*)d_in[5];
    const float* W1   = (const float*)d_in[6];
    const float* b1   = (const float*)d_in[7];
    const float* W2   = (const float*)d_in[8];
    const float* b2   = (const float*)d_in[9];
    float* out = (float*)d_out;

    if (ws_size >= V2_NEED) {
        char* wsb = (char*)d_ws;
        float* hf  = (float*)(wsb + V2_OFF_HF);
        float* w1t = (float*)(wsb + V2_OFF_W1T);
        pack2_kernel<<<(PACK2_TOTAL + 255) / 256, 256, 0, stream>>>(
            W_ih, W_hh, b_ih, b_hh, W1, wsb);
        lstm8b_kernel<<<NN * 8, 512, 0, stream>>>(wsb, inp, hf);
        head2_kernel<<<BB, 256, 0, stream>>>(hf, w1t, b1, W2, b2, out);
    } else {
        float* ws = (float*)d_ws;
        unsigned short* bfw = (unsigned short*)d_ws;
        packfb_kernel<<<(PACK_TOTAL_O + 255) / 256, 256, 0, stream>>>(
            W_ih, W_hh, W1, bfw, ws + OFF_W1T_O);
        lstmfb_kernel<<<NN * 4, 512, 0, stream>>>(inp, b_ih, b_hh, bfw, ws + OFF_HF_O);
        head2_kernel<<<BB, 256, 0, stream>>>(ws + OFF_HF_O, ws + OFF_W1T_O,
                                             b1, W2, b2, out);
    }
}

// Round 17
// 283.464 us; speedup vs baseline: 1.5200x; 1.1750x over previous
//
#include <hip/hip_runtime.h>
#include <hip/hip_bf16.h>

#define NN   19
#define DIN  100
#define HID  128
#define TT   250
#define BB   64
#define NC   4
#define FEAT 2432          // NN*HID

typedef __attribute__((ext_vector_type(8))) short s8v;
typedef __attribute__((ext_vector_type(4))) float f4v;
typedef _Float16 h8v __attribute__((ext_vector_type(8)));
typedef _Float16 h4v __attribute__((ext_vector_type(4)));
typedef unsigned int u4v __attribute__((ext_vector_type(4)));

// =============== V2 workspace layout (byte offsets) ===============
#define BFI_USH   1245184
#define V2_OFF_BFI  0ull
#define V2_OFF_BFH  2490368ull
#define V2_OFF_BIAS 4980736ull
#define V2_OFF_W1T  5019648ull
#define V2_OFF_HF   6264832ull
#define V2_NEED     6887424ull
#define PACK2_TOTAL (2*BFI_USH + 19*512 + FEAT*HID)

// =============== fallback (round-3) layout, float offsets =========
#define SZ_BF   (NN*8*4*8*512)
#define OFF_W1T_O (SZ_BF/2)
#define SZ_W1T  (FEAT*HID)
#define OFF_HF_O  (OFF_W1T_O + SZ_W1T)
#define PACK_TOTAL_O (SZ_BF + SZ_W1T)

// A-tile row stride: 264 f16 = 528 B (4-bank shift per row).
#define RSTR 528

__device__ __forceinline__ unsigned short f2bf(float x) {
    union { float f; unsigned u; } v; v.f = x;
    unsigned r = v.u + 0x7FFF + ((v.u >> 16) & 1);   // RNE
    return (unsigned short)(r >> 16);
}
#define LOG2E 1.4426950408889634f
__device__ __forceinline__ float sigf(float x) {
    return __builtin_amdgcn_rcpf(1.f + __builtin_amdgcn_exp2f(-LOG2E * x));
}
__device__ __forceinline__ float tnhf(float x) {
    return 1.f - 2.f * __builtin_amdgcn_rcpf(__builtin_amdgcn_exp2f(2.f * LOG2E * x) + 1.f);
}

// Pin a fragment in VGPRs: value becomes asm-defined, so the compiler
// cannot rematerialize it by re-loading from memory (round-3 failure mode).
__device__ __forceinline__ void pin8(h8v& v) {
    u4v u = __builtin_bit_cast(u4v, v);
    asm volatile("" : "+v"(u));
    v = __builtin_bit_cast(h8v, u);
}

// lgkm-only barrier: LDS ordered; global loads/stores stay in flight.
__device__ __forceinline__ void lgkm_barrier() {
    asm volatile("s_waitcnt lgkmcnt(0)" ::: "memory");
    __builtin_amdgcn_s_barrier();
    asm volatile("" ::: "memory");
}

// ======================= V2 kernels ===============================

// Pack W_ih frags, W_hh frags (f16), combined bias, W1T.
// Frag element (n, hb, nt, kt, lane, e) = W[k][g]:
// k = kt*32+(lane>>4)*8+e, g = nt*128+hb*16+(lane&15).
__global__ __launch_bounds__(256) void pack2_kernel(
        const float* __restrict__ W_ih, const float* __restrict__ W_hh,
        const float* __restrict__ b_ih, const float* __restrict__ b_hh,
        const float* __restrict__ W1, char* __restrict__ wsb) {
    int id = blockIdx.x * 256 + threadIdx.x;
    if (id < 2 * BFI_USH) {
        int which = id >= BFI_USH;                 // 0 = W_ih, 1 = W_hh
        int i = which ? id - BFI_USH : id;
        int e    = i & 7;
        int lane = (i >> 3) & 63;
        int kt   = (i >> 9) & 3;
        int nt   = (i >> 11) & 3;
        int hb   = (i >> 13) & 7;
        int n    = i >> 16;
        int k = kt * 32 + (lane >> 4) * 8 + e;
        int g = nt * 128 + hb * 16 + (lane & 15);
        float v;
        if (which) v = W_hh[((size_t)n * 512 + g) * HID + k];
        else       v = (k < DIN) ? W_ih[((size_t)n * 512 + g) * DIN + k] : 0.f;
        reinterpret_cast<_Float16*>(wsb)[id] = (_Float16)v;
        return;
    }
    int id2 = id - 2 * BFI_USH;
    if (id2 < NN * 512) {
        reinterpret_cast<float*>(wsb + V2_OFF_BIAS)[id2] = b_ih[id2] + b_hh[id2];
        return;
    }
    int id3 = id2 - NN * 512;
    if (id3 < FEAT * HID) {
        int j = id3 & 127, k = id3 >> 7;
        reinterpret_cast<float*>(wsb + V2_OFF_W1T)[id3] = W1[(size_t)j * FEAT + k];
    }
}

// Fused recurrence v12: BOTH weight sets register-resident (pinned).
// grid 152 = (n, batch-octet). 512 thr = 8 waves, wave hb owns 16 hidden j.
// Per step per wave: 8 ds_read_b128 (A-frags) + 32 MFMA (16 x-part on
// pinned W_ih, 16 h-part on pinned W_hh, nt-major with early nonlin) +
// 2 h-writes + x-stage; one lgkm-only barrier. LDS = A-tile only (16.5KB).
// Tile map: tile row g4*4+q (q=0,1) holds real octet row
// R=(g4&1)*4+(g4>>1)*2+q; other rows stay zero.
__global__ __launch_bounds__(512, 2) void lstm8c_kernel(
        const char* __restrict__ wsb, const float* __restrict__ inp,
        float* __restrict__ hf) {
    __shared__ alignas(16) _Float16 xh[2][16 * 264];     // 2 x 8.25 KB

    const int tid  = threadIdx.x;
    const int lane = tid & 63;
    const int w8   = tid >> 6;          // 0..7
    const int l15  = lane & 15;
    const int g4   = lane >> 4;
    const int n    = blockIdx.x >> 3;
    const int oct  = blockIdx.x & 7;
    const int bq   = oct >> 1;
    const int hi   = oct & 1;
    const int hb   = w8;
    const int j    = hb * 16 + l15;

    // W_hh frags (16 h8v) + W_ih frags (16 h8v), both pinned in VGPRs
    h8v bf[4][4], bfx[4][4];
    {
        const _Float16* wph = reinterpret_cast<const _Float16*>(wsb + V2_OFF_BFH)
                              + (size_t)lane * 8;
        const _Float16* wpx = reinterpret_cast<const _Float16*>(wsb + V2_OFF_BFI)
                              + (size_t)lane * 8;
        #pragma unroll
        for (int nt = 0; nt < 4; ++nt)
            #pragma unroll
            for (int kt = 0; kt < 4; ++kt) {
                size_t off = ((size_t)((n * 8 + hb) * 16 + nt * 4 + kt)) * 512;
                bf[nt][kt]  = *reinterpret_cast<const h8v*>(wph + off);
                bfx[nt][kt] = *reinterpret_cast<const h8v*>(wpx + off);
            }
        #pragma unroll
        for (int nt = 0; nt < 4; ++nt)
            #pragma unroll
            for (int kt = 0; kt < 4; ++kt) {
                pin8(bf[nt][kt]);
                pin8(bfx[nt][kt]);
            }
    }
    float bs[4];
    #pragma unroll
    for (int nt = 0; nt < 4; ++nt)
        bs[nt] = reinterpret_cast<const float*>(wsb + V2_OFF_BIAS)[n * 512 + nt * 128 + j];

    // zero xh (both buffers; dead rows + pads must stay 0)
    for (int i = tid; i < 2 * 16 * 264; i += 512) (&xh[0][0])[i] = (_Float16)0.f;

    // x staging: 200 threads, 8 live tile rows x 25 float4
    const bool st = tid < 200;
    const int sr  = st ? tid / 25 : 0;
    const int c4  = st ? tid - sr * 25 : 0;
    const int g4s = sr >> 1, qs = sr & 1;
    const int tr  = g4s * 4 + qs;                         // live tile row
    const int Rr  = (g4s & 1) * 4 + (g4s >> 1) * 2 + qs;  // real octet row
    const float* xb = inp + (size_t)((bq * 16 + hi * 8 + Rr) * NN + n) * (TT * DIN)
                      + c4 * 4;
    const int wofs_x = tr * RSTR + c4 * 8;

    const int arow = l15 * RSTR;
    const int wr0 = (g4 * 4) * RSTR + 256 + 2 * j;
    const int wr1 = (g4 * 4 + 1) * RSTR + 256 + 2 * j;

    float c2[2] = {0.f, 0.f};
    float h2[2] = {0.f, 0.f};

    __syncthreads();
    if (st) {   // stage x(0) into buffer 0
        float4 v = *reinterpret_cast<const float4*>(xb);
        h4v pk = {(_Float16)v.x, (_Float16)v.y, (_Float16)v.z, (_Float16)v.w};
        *reinterpret_cast<h4v*>(reinterpret_cast<char*>(xh[0]) + wofs_x) = pk;
    }
    __syncthreads();

    #pragma unroll 2
    for (int t = 0; t < TT; ++t) {
        char* rc = reinterpret_cast<char*>(xh[t & 1]);
        char* wc = reinterpret_cast<char*>(xh[(t + 1) & 1]);

        // issue x(t+1) load early; lgkm barriers never drain vmcnt
        float4 nxt = make_float4(0.f, 0.f, 0.f, 0.f);
        if (t < TT - 1 && st)
            nxt = *reinterpret_cast<const float4*>(xb + (t + 1) * DIN);

        f4v acc[4];
        #pragma unroll
        for (int nt = 0; nt < 4; ++nt)
            acc[nt] = (f4v){bs[nt], bs[nt], 0.f, 0.f};

        // ---- phase X: x-part A frags + pinned W_ih MFMAs ----
        h8v ax0 = *reinterpret_cast<const h8v*>(rc + arow + (0 * 64 + g4 * 16));
        h8v ax1 = *reinterpret_cast<const h8v*>(rc + arow + (1 * 64 + g4 * 16));
        h8v ax2 = *reinterpret_cast<const h8v*>(rc + arow + (2 * 64 + g4 * 16));
        h8v ax3 = *reinterpret_cast<const h8v*>(rc + arow + (3 * 64 + g4 * 16));
        #pragma unroll
        for (int nt = 0; nt < 4; ++nt) {
            acc[nt] = __builtin_amdgcn_mfma_f32_16x16x32_f16(ax0, bfx[nt][0], acc[nt], 0, 0, 0);
            acc[nt] = __builtin_amdgcn_mfma_f32_16x16x32_f16(ax1, bfx[nt][1], acc[nt], 0, 0, 0);
            acc[nt] = __builtin_amdgcn_mfma_f32_16x16x32_f16(ax2, bfx[nt][2], acc[nt], 0, 0, 0);
            acc[nt] = __builtin_amdgcn_mfma_f32_16x16x32_f16(ax3, bfx[nt][3], acc[nt], 0, 0, 0);
        }

        // ---- phase H: h-part A frags + pinned W_hh MFMAs, early nonlin ----
        h8v ah0 = *reinterpret_cast<const h8v*>(rc + arow + (256 + 0 * 64 + g4 * 16));
        h8v ah1 = *reinterpret_cast<const h8v*>(rc + arow + (256 + 1 * 64 + g4 * 16));
        h8v ah2 = *reinterpret_cast<const h8v*>(rc + arow + (256 + 2 * 64 + g4 * 16));
        h8v ah3 = *reinterpret_cast<const h8v*>(rc + arow + (256 + 3 * 64 + g4 * 16));

        acc[0] = __builtin_amdgcn_mfma_f32_16x16x32_f16(ah0, bf[0][0], acc[0], 0, 0, 0);
        acc[0] = __builtin_amdgcn_mfma_f32_16x16x32_f16(ah1, bf[0][1], acc[0], 0, 0, 0);
        acc[0] = __builtin_amdgcn_mfma_f32_16x16x32_f16(ah2, bf[0][2], acc[0], 0, 0, 0);
        acc[0] = __builtin_amdgcn_mfma_f32_16x16x32_f16(ah3, bf[0][3], acc[0], 0, 0, 0);
        float ii0 = sigf(acc[0][0]);
        float ii1 = sigf(acc[0][1]);

        acc[1] = __builtin_amdgcn_mfma_f32_16x16x32_f16(ah0, bf[1][0], acc[1], 0, 0, 0);
        acc[1] = __builtin_amdgcn_mfma_f32_16x16x32_f16(ah1, bf[1][1], acc[1], 0, 0, 0);
        acc[1] = __builtin_amdgcn_mfma_f32_16x16x32_f16(ah2, bf[1][2], acc[1], 0, 0, 0);
        acc[1] = __builtin_amdgcn_mfma_f32_16x16x32_f16(ah3, bf[1][3], acc[1], 0, 0, 0);
        float ff0 = sigf(acc[1][0]);
        float ff1 = sigf(acc[1][1]);

        acc[2] = __builtin_amdgcn_mfma_f32_16x16x32_f16(ah0, bf[2][0], acc[2], 0, 0, 0);
        acc[2] = __builtin_amdgcn_mfma_f32_16x16x32_f16(ah1, bf[2][1], acc[2], 0, 0, 0);
        acc[2] = __builtin_amdgcn_mfma_f32_16x16x32_f16(ah2, bf[2][2], acc[2], 0, 0, 0);
        acc[2] = __builtin_amdgcn_mfma_f32_16x16x32_f16(ah3, bf[2][3], acc[2], 0, 0, 0);
        float gg0 = tnhf(acc[2][0]);
        float gg1 = tnhf(acc[2][1]);

        acc[3] = __builtin_amdgcn_mfma_f32_16x16x32_f16(ah0, bf[3][0], acc[3], 0, 0, 0);
        acc[3] = __builtin_amdgcn_mfma_f32_16x16x32_f16(ah1, bf[3][1], acc[3], 0, 0, 0);
        acc[3] = __builtin_amdgcn_mfma_f32_16x16x32_f16(ah2, bf[3][2], acc[3], 0, 0, 0);
        acc[3] = __builtin_amdgcn_mfma_f32_16x16x32_f16(ah3, bf[3][3], acc[3], 0, 0, 0);
        float oo0 = sigf(acc[3][0]);
        float oo1 = sigf(acc[3][1]);

        // state update + h(t+1) writes
        float cn0 = ff0 * c2[0] + ii0 * gg0;
        c2[0] = cn0;
        float hn0 = oo0 * tnhf(cn0);
        h2[0] = hn0;
        *reinterpret_cast<_Float16*>(wc + wr0) = (_Float16)hn0;

        float cn1 = ff1 * c2[1] + ii1 * gg1;
        c2[1] = cn1;
        float hn1 = oo1 * tnhf(cn1);
        h2[1] = hn1;
        *reinterpret_cast<_Float16*>(wc + wr1) = (_Float16)hn1;

        // x(t+1) write into next buffer
        if (t < TT - 1 && st) {
            h4v pk = {(_Float16)nxt.x, (_Float16)nxt.y, (_Float16)nxt.z, (_Float16)nxt.w};
            *reinterpret_cast<h4v*>(wc + wofs_x) = pk;
        }
        lgkm_barrier();
    }

    #pragma unroll
    for (int q = 0; q < 2; ++q) {
        int b = bq * 16 + hi * 8 + (g4 & 1) * 4 + (g4 >> 1) * 2 + q;
        hf[((size_t)b * NN + n) * HID + j] = h2[q];
    }
}

// Head: 64 blocks (one per batch row), 256 thr, split-K over 2 halves.
__global__ __launch_bounds__(256) void head2_kernel(
        const float* __restrict__ hf, const float* __restrict__ w1t,
        const float* __restrict__ b1, const float* __restrict__ W2,
        const float* __restrict__ b2, float* __restrict__ out) {
    __shared__ float comb[FEAT];
    __shared__ float par[2][HID];
    __shared__ float hid[HID];
    const int b = blockIdx.x;
    const int u  = threadIdx.x & 127;
    const int kk = threadIdx.x >> 7;
    const float* hfp = hf + (size_t)b * FEAT;
    for (int i = threadIdx.x; i < FEAT; i += 256) comb[i] = hfp[i];
    __syncthreads();

    const int k0 = kk * (FEAT / 2);
    float acc = 0.f;
    #pragma unroll 8
    for (int k = 0; k < FEAT / 2; ++k)
        acc = fmaf(comb[k0 + k], w1t[(size_t)(k0 + k) * HID + u], acc);
    par[kk][u] = acc;
    __syncthreads();
    if (kk == 0) hid[u] = fmaxf(par[0][u] + par[1][u] + b1[u], 0.f);
    __syncthreads();

    if (threadIdx.x < NC) {
        int cls = threadIdx.x;
        float a = b2[cls];
        #pragma unroll 4
        for (int k = 0; k < HID; ++k)
            a = fmaf(hid[k], W2[cls * HID + k], a);
        out[b * NC + cls] = a;
    }
}

// ======================= fallback (round-3) =======================
__global__ __launch_bounds__(256) void packfb_kernel(
        const float* __restrict__ W_ih, const float* __restrict__ W_hh,
        const float* __restrict__ W1,
        unsigned short* __restrict__ bfw, float* __restrict__ w1t) {
    int id = blockIdx.x * 256 + threadIdx.x;
    if (id < SZ_BF) {
        int e    = id & 7;
        int lane = (id >> 3) & 63;
        int kt   = (id >> 9) & 7;
        int nt   = (id >> 12) & 3;
        int hb   = (id >> 14) & 7;
        int n    = id >> 17;
        int k = kt * 32 + (lane >> 4) * 8 + e;
        int g = nt * 128 + hb * 16 + (lane & 15);
        float v = 0.f;
        if (k < DIN)       v = W_ih[((size_t)n * 512 + g) * DIN + k];
        else if (k < 228)  v = W_hh[((size_t)n * 512 + g) * HID + (k - DIN)];
        bfw[id] = f2bf(v);
        return;
    }
    int id3 = id - SZ_BF;
    if (id3 < SZ_W1T) {
        int j = id3 & 127, k = id3 >> 7;
        w1t[id3] = W1[(size_t)j * FEAT + k];
    }
}

__global__ __launch_bounds__(512, 2) void lstmfb_kernel(
        const float* __restrict__ inp,
        const float* __restrict__ b_ih, const float* __restrict__ b_hh,
        const unsigned short* __restrict__ bfw, float* __restrict__ hf) {
    __shared__ alignas(16) unsigned short xh[2][16 * 256];
    const int tid  = threadIdx.x;
    const int lane = tid & 63;
    const int w    = tid >> 6;
    const int l15  = lane & 15;
    const int g4   = lane >> 4;
    const int n    = blockIdx.x >> 2;
    const int bq   = blockIdx.x & 3;
    const int j    = w * 16 + l15;

    s8v bf[4][8];
    const unsigned short* wp = bfw + ((size_t)(n * 8 + w) * 32) * 512 + lane * 8;
    #pragma unroll
    for (int nt = 0; nt < 4; ++nt)
        #pragma unroll
        for (int kt = 0; kt < 8; ++kt)
            bf[nt][kt] = *reinterpret_cast<const s8v*>(wp + (nt * 8 + kt) * 512);

    float bs[4];
    #pragma unroll
    for (int nt = 0; nt < 4; ++nt)
        bs[nt] = b_ih[n * 512 + nt * 128 + j] + b_hh[n * 512 + nt * 128 + j];

    float c[4] = {0.f, 0.f, 0.f, 0.f};
    float h[4] = {0.f, 0.f, 0.f, 0.f};
    for (int i = tid; i < 2 * 16 * 256; i += 512) (&xh[0][0])[i] = 0;

    const bool st = tid < 400;
    const int row = st ? tid / 25 : 0;
    const int c4  = st ? tid - row * 25 : 0;
    const float* xb = inp + ((size_t)(bq * 16 + row) * NN + n) * (TT * DIN) + c4 * 4;
    const int wofs = row * 512 + ((c4 * 8) ^ ((row & 7) << 4));
    const int arow = l15 * 512;
    const int aswz = (l15 & 7) << 4;

    __syncthreads();
    if (st) {
        float4 v = *reinterpret_cast<const float4*>(xb);
        unsigned lo = f2bf(v.x) | ((unsigned)f2bf(v.y) << 16);
        unsigned hi = f2bf(v.z) | ((unsigned)f2bf(v.w) << 16);
        *reinterpret_cast<uint2*>(reinterpret_cast<char*>(xh[0]) + wofs) =
            make_uint2(lo, hi);
    }
    __syncthreads();

    for (int t = 0; t < TT; ++t) {
        char* rc = reinterpret_cast<char*>(xh[t & 1]);
        char* wc = reinterpret_cast<char*>(xh[(t + 1) & 1]);
        float4 nxt = make_float4(0.f, 0.f, 0.f, 0.f);
        if (t < TT - 1 && st)
            nxt = *reinterpret_cast<const float4*>(xb + (t + 1) * DIN);

        f4v acc[4];
        #pragma unroll
        for (int nt = 0; nt < 4; ++nt)
            acc[nt] = (f4v){bs[nt], bs[nt], bs[nt], bs[nt]};
        #pragma unroll
        for (int kt = 0; kt < 8; ++kt) {
            s8v a = *reinterpret_cast<const s8v*>(rc + arow + ((kt * 64 + g4 * 16) ^ aswz));
            #pragma unroll
            for (int nt = 0; nt < 4; ++nt)
                acc[nt] = __builtin_amdgcn_mfma_f32_16x16x32_bf16(a, bf[nt][kt], acc[nt], 0, 0, 0);
        }
        #pragma unroll
        for (int r = 0; r < 4; ++r) {
            float ii = sigf(acc[0][r]);
            float ff = sigf(acc[1][r]);
            float gg = tnhf(acc[2][r]);
            float oo = sigf(acc[3][r]);
            float cn = ff * c[r] + ii * gg;
            c[r] = cn;
            float hn = oo * tnhf(cn);
            h[r] = hn;
            int rr = g4 * 4 + r;
            *reinterpret_cast<unsigned short*>(
                wc + rr * 512 + (((DIN + j) * 2) ^ ((rr & 7) << 4))) = f2bf(hn);
        }
        if (t < TT - 1 && st) {
            unsigned lo = f2bf(nxt.x) | ((unsigned)f2bf(nxt.y) << 16);
            unsigned hi = f2bf(nxt.z) | ((unsigned)f2bf(nxt.w) << 16);
            *reinterpret_cast<uint2*>(wc + wofs) = make_uint2(lo, hi);
        }
        __syncthreads();
    }
    #pragma unroll
    for (int r = 0; r < 4; ++r) {
        int b = bq * 16 + g4 * 4 + r;
        hf[((size_t)b * NN + n) * HID + j] = h[r];
    }
}

// ============================ launch ==============================
extern "C" void kernel_launch(void* const* d_in, const int* in_sizes, int n_in,
                              void* d_out, int out_size, void* d_ws, size_t ws_size,
                              hipStream_t stream) {
    const float* inp  = (const float*)d_in[0];
    const float* W_ih = (const float*)d_in[2];
    const float* W_hh = (const float*)d_in[3];
    const float* b_ih = (const float*)d_in[4];
    const float* b_hh = (const float*)d_in[5];
    const float* W1   = (const float*)d_in[6];
    const float* b1   = (const float*)d_in[7];
    const float* W2   = (const float*)d_in[8];
    const float* b2   = (const float*)d_in[9];
    float* out = (float*)d_out;

    if (ws_size >= V2_NEED) {
        char* wsb = (char*)d_ws;
        float* hf  = (float*)(wsb + V2_OFF_HF);
        float* w1t = (float*)(wsb + V2_OFF_W1T);
        pack2_kernel<<<(PACK2_TOTAL + 255) / 256, 256, 0, stream>>>(
            W_ih, W_hh, b_ih, b_hh, W1, wsb);
        lstm8c_kernel<<<NN * 8, 512, 0, stream>>>(wsb, inp, hf);
        head2_kernel<<<BB, 256, 0, stream>>>(hf, w1t, b1, W2, b2, out);
    } else {
        float* ws = (float*)d_ws;
        unsigned short* bfw = (unsigned short*)d_ws;
        packfb_kernel<<<(PACK_TOTAL_O + 255) / 256, 256, 0, stream>>>(
            W_ih, W_hh, W1, bfw, ws + OFF_W1T_O);
        lstmfb_kernel<<<NN * 4, 512, 0, stream>>>(inp, b_ih, b_hh, bfw, ws + OFF_HF_O);
        head2_kernel<<<BB, 256, 0, stream>>>(ws + OFF_HF_O, ws + OFF_W1T_O,
                                             b1, W2, b2, out);
    }
}

// Round 18
// 277.790 us; speedup vs baseline: 1.5511x; 1.0204x over previous
//
#include <hip/hip_runtime.h>
#include <hip/hip_bf16.h>

#define NN   19
#define DIN  100
#define HID  128
#define TT   250
#define BB   64
#define NC   4
#define FEAT 2432          // NN*HID

typedef __attribute__((ext_vector_type(8))) short s8v;
typedef __attribute__((ext_vector_type(4))) float f4v;
typedef _Float16 h8v __attribute__((ext_vector_type(8)));
typedef _Float16 h4v __attribute__((ext_vector_type(4)));
typedef unsigned int u4v __attribute__((ext_vector_type(4)));

// =============== V2 workspace layout (byte offsets) ===============
#define BFI_USH   1245184
#define V2_OFF_BFI  0ull
#define V2_OFF_BFH  2490368ull
#define V2_OFF_BIAS 4980736ull
#define V2_OFF_W1T  5019648ull
#define V2_OFF_HF   6264832ull
#define V2_NEED     6887424ull
#define PACK2_TOTAL (2*BFI_USH + 19*512 + FEAT*HID)

// =============== fallback (round-3) layout, float offsets =========
#define SZ_BF   (NN*8*4*8*512)
#define OFF_W1T_O (SZ_BF/2)
#define SZ_W1T  (FEAT*HID)
#define OFF_HF_O  (OFF_W1T_O + SZ_W1T)
#define PACK_TOTAL_O (SZ_BF + SZ_W1T)

// tile row stride: 136 f16 = 272 B = 68 words == 4 (mod 32 banks)
#define XSTR 272

__device__ __forceinline__ unsigned short f2bf(float x) {
    union { float f; unsigned u; } v; v.f = x;
    unsigned r = v.u + 0x7FFF + ((v.u >> 16) & 1);   // RNE
    return (unsigned short)(r >> 16);
}
#define LOG2E 1.4426950408889634f
__device__ __forceinline__ float sigf(float x) {
    return __builtin_amdgcn_rcpf(1.f + __builtin_amdgcn_exp2f(-LOG2E * x));
}
__device__ __forceinline__ float tnhf(float x) {
    return 1.f - 2.f * __builtin_amdgcn_rcpf(__builtin_amdgcn_exp2f(2.f * LOG2E * x) + 1.f);
}

// Pin a fragment in VGPRs (prevents rematerialize-by-reload).
__device__ __forceinline__ void pin8(h8v& v) {
    u4v u = __builtin_bit_cast(u4v, v);
    asm volatile("" : "+v"(u));
    v = __builtin_bit_cast(h8v, u);
}

// lgkm-only barrier: LDS ordered; global loads/stores stay in flight.
__device__ __forceinline__ void lgkm_barrier() {
    asm volatile("s_waitcnt lgkmcnt(0)" ::: "memory");
    __builtin_amdgcn_s_barrier();
    asm volatile("" ::: "memory");
}

// ======================= V2 kernels ===============================

// Pack W_ih frags, W_hh frags (f16), combined bias, W1T.
__global__ __launch_bounds__(256) void pack2_kernel(
        const float* __restrict__ W_ih, const float* __restrict__ W_hh,
        const float* __restrict__ b_ih, const float* __restrict__ b_hh,
        const float* __restrict__ W1, char* __restrict__ wsb) {
    int id = blockIdx.x * 256 + threadIdx.x;
    if (id < 2 * BFI_USH) {
        int which = id >= BFI_USH;                 // 0 = W_ih, 1 = W_hh
        int i = which ? id - BFI_USH : id;
        int e    = i & 7;
        int lane = (i >> 3) & 63;
        int kt   = (i >> 9) & 3;
        int nt   = (i >> 11) & 3;
        int hb   = (i >> 13) & 7;
        int n    = i >> 16;
        int k = kt * 32 + (lane >> 4) * 8 + e;
        int g = nt * 128 + hb * 16 + (lane & 15);
        float v;
        if (which) v = W_hh[((size_t)n * 512 + g) * HID + k];
        else       v = (k < DIN) ? W_ih[((size_t)n * 512 + g) * DIN + k] : 0.f;
        reinterpret_cast<_Float16*>(wsb)[id] = (_Float16)v;
        return;
    }
    int id2 = id - 2 * BFI_USH;
    if (id2 < NN * 512) {
        reinterpret_cast<float*>(wsb + V2_OFF_BIAS)[id2] = b_ih[id2] + b_hh[id2];
        return;
    }
    int id3 = id2 - NN * 512;
    if (id3 < FEAT * HID) {
        int j = id3 & 127, k = id3 >> 7;
        reinterpret_cast<float*>(wsb + V2_OFF_W1T)[id3] = W1[(size_t)j * FEAT + k];
    }
}

// Fused recurrence v13: PAIR-STEP — dead C-slots 2,3 carry step t+1's
// x-projection. grid 152 = (n, batch-octet), 512 thr = 8 waves; weights
// (W_ih + W_hh frags) pinned in VGPRs. Loop over 125 step-pairs:
//  EVEN step: 16 x-MFMA over x-tile holding x(t) at rows g4*4+{0,1} and
//    x(t+1) at rows g4*4+{2,3} (slots 0,1 <- xpart(t); 2,3 <- xpart(t+1))
//    + 16 h-MFMA (h rows {0,1}; rows {2,3} zero -> slots 2,3 get exact +0)
//    + nonlin(slots 0,1) -> h(t+1); pend = slots 2,3.
//  ODD step: acc = {pend,0,0} + 16 h-MFMA + nonlin. NO phase-X.
// MFMA/wave: 32/16 alternating = 24 avg (-25%). Bitwise-identical output
// (per-gate op sequence unchanged; h-MFMA on zero rows adds exact 0).
__global__ __launch_bounds__(512, 2) void lstm9p_kernel(
        const char* __restrict__ wsb, const float* __restrict__ inp,
        float* __restrict__ hf) {
    __shared__ alignas(16) _Float16 xt[2][16 * 136];   // 2 x 4.25 KB
    __shared__ alignas(16) _Float16 ht[2][16 * 136];   // 2 x 4.25 KB

    const int tid  = threadIdx.x;
    const int lane = tid & 63;
    const int w8   = tid >> 6;
    const int l15  = lane & 15;
    const int g4   = lane >> 4;
    const int n    = blockIdx.x >> 3;
    const int oct  = blockIdx.x & 7;
    const int bq   = oct >> 1;
    const int hi   = oct & 1;
    const int hb   = w8;
    const int j    = hb * 16 + l15;

    // W_hh + W_ih frags, pinned (32 h8v = 128 regs)
    h8v bf[4][4], bfx[4][4];
    {
        const _Float16* wph = reinterpret_cast<const _Float16*>(wsb + V2_OFF_BFH)
                              + (size_t)lane * 8;
        const _Float16* wpx = reinterpret_cast<const _Float16*>(wsb + V2_OFF_BFI)
                              + (size_t)lane * 8;
        #pragma unroll
        for (int nt = 0; nt < 4; ++nt)
            #pragma unroll
            for (int kt = 0; kt < 4; ++kt) {
                size_t off = ((size_t)((n * 8 + hb) * 16 + nt * 4 + kt)) * 512;
                bf[nt][kt]  = *reinterpret_cast<const h8v*>(wph + off);
                bfx[nt][kt] = *reinterpret_cast<const h8v*>(wpx + off);
            }
        #pragma unroll
        for (int nt = 0; nt < 4; ++nt)
            #pragma unroll
            for (int kt = 0; kt < 4; ++kt) {
                pin8(bf[nt][kt]);
                pin8(bfx[nt][kt]);
            }
    }
    float bs[4];
    #pragma unroll
    for (int nt = 0; nt < 4; ++nt)
        bs[nt] = reinterpret_cast<const float*>(wsb + V2_OFF_BIAS)[n * 512 + nt * 128 + j];

    // zero all tiles (x cols >=100 and h rows g4*4+{2,3} must stay 0)
    for (int i = tid; i < 16 * 136; i += 512) {
        xt[0][i] = (_Float16)0.f; xt[1][i] = (_Float16)0.f;
        ht[0][i] = (_Float16)0.f; ht[1][i] = (_Float16)0.f;
    }

    // x staging: 400 threads cover 16 tile rows x 25 float4 per PAIR.
    // tile row sr = g4s*4+qs: qs<2 -> even-of-pair x of real row R(g4s,qs);
    // qs>=2 -> odd-of-pair x of real row R(g4s,qs-2).
    const bool st = tid < 400;
    const int sr  = st ? tid / 25 : 0;
    const int d4  = st ? tid - sr * 25 : 0;
    const int g4s = sr >> 2, qs = sr & 3;
    const int tpo = qs >> 1;                               // 0 even, 1 odd
    const int Rr  = (g4s & 1) * 4 + (g4s >> 1) * 2 + (qs & 1);
    const float* xbp = inp + (size_t)((bq * 16 + hi * 8 + Rr) * NN + n) * (TT * DIN)
                       + d4 * 4;
    const int wofs_x = sr * XSTR + d4 * 8;

    const int arow = l15 * XSTR;
    const int wr0 = (g4 * 4) * XSTR + 2 * j;
    const int wr1 = (g4 * 4 + 1) * XSTR + 2 * j;

    float c2[2] = {0.f, 0.f};
    float h2[2] = {0.f, 0.f};

    __syncthreads();
    if (st) {   // prologue: stage x(0),x(1) into xt[0]
        float4 v = *reinterpret_cast<const float4*>(xbp + (size_t)tpo * DIN);
        h4v pk = {(_Float16)v.x, (_Float16)v.y, (_Float16)v.z, (_Float16)v.w};
        *reinterpret_cast<h4v*>(reinterpret_cast<char*>(xt[0]) + wofs_x) = pk;
    }
    __syncthreads();

    float pend[8];

    for (int tp = 0; tp < 125; ++tp) {
        const char* rx = reinterpret_cast<const char*>(xt[tp & 1]);
        char*       wx = reinterpret_cast<char*>(xt[(tp + 1) & 1]);
        const char* rh0 = reinterpret_cast<const char*>(ht[0]);
        char*       wh1 = reinterpret_cast<char*>(ht[1]);

        // prefetch next pair's x slice (lgkm barriers never drain vmcnt)
        float4 nxt = make_float4(0.f, 0.f, 0.f, 0.f);
        if (st) {
            int tl = 2 * tp + 2 + tpo;
            if (tl > 249) tl = 249;
            nxt = *reinterpret_cast<const float4*>(xbp + (size_t)tl * DIN);
        }

        // ================= EVEN step t = 2tp =================
        f4v acc[4];
        #pragma unroll
        for (int nt = 0; nt < 4; ++nt)
            acc[nt] = (f4v){bs[nt], bs[nt], bs[nt], bs[nt]};

        h8v ax0 = *reinterpret_cast<const h8v*>(rx + arow + (0 * 64 + g4 * 16));
        h8v ax1 = *reinterpret_cast<const h8v*>(rx + arow + (1 * 64 + g4 * 16));
        h8v ax2 = *reinterpret_cast<const h8v*>(rx + arow + (2 * 64 + g4 * 16));
        h8v ax3 = *reinterpret_cast<const h8v*>(rx + arow + (3 * 64 + g4 * 16));
        #pragma unroll
        for (int nt = 0; nt < 4; ++nt) {
            acc[nt] = __builtin_amdgcn_mfma_f32_16x16x32_f16(ax0, bfx[nt][0], acc[nt], 0, 0, 0);
            acc[nt] = __builtin_amdgcn_mfma_f32_16x16x32_f16(ax1, bfx[nt][1], acc[nt], 0, 0, 0);
            acc[nt] = __builtin_amdgcn_mfma_f32_16x16x32_f16(ax2, bfx[nt][2], acc[nt], 0, 0, 0);
            acc[nt] = __builtin_amdgcn_mfma_f32_16x16x32_f16(ax3, bfx[nt][3], acc[nt], 0, 0, 0);
        }

        h8v ah0 = *reinterpret_cast<const h8v*>(rh0 + arow + (0 * 64 + g4 * 16));
        h8v ah1 = *reinterpret_cast<const h8v*>(rh0 + arow + (1 * 64 + g4 * 16));
        h8v ah2 = *reinterpret_cast<const h8v*>(rh0 + arow + (2 * 64 + g4 * 16));
        h8v ah3 = *reinterpret_cast<const h8v*>(rh0 + arow + (3 * 64 + g4 * 16));

        acc[0] = __builtin_amdgcn_mfma_f32_16x16x32_f16(ah0, bf[0][0], acc[0], 0, 0, 0);
        acc[0] = __builtin_amdgcn_mfma_f32_16x16x32_f16(ah1, bf[0][1], acc[0], 0, 0, 0);
        acc[0] = __builtin_amdgcn_mfma_f32_16x16x32_f16(ah2, bf[0][2], acc[0], 0, 0, 0);
        acc[0] = __builtin_amdgcn_mfma_f32_16x16x32_f16(ah3, bf[0][3], acc[0], 0, 0, 0);
        float ii0 = sigf(acc[0][0]);
        float ii1 = sigf(acc[0][1]);

        acc[1] = __builtin_amdgcn_mfma_f32_16x16x32_f16(ah0, bf[1][0], acc[1], 0, 0, 0);
        acc[1] = __builtin_amdgcn_mfma_f32_16x16x32_f16(ah1, bf[1][1], acc[1], 0, 0, 0);
        acc[1] = __builtin_amdgcn_mfma_f32_16x16x32_f16(ah2, bf[1][2], acc[1], 0, 0, 0);
        acc[1] = __builtin_amdgcn_mfma_f32_16x16x32_f16(ah3, bf[1][3], acc[1], 0, 0, 0);
        float ff0 = sigf(acc[1][0]);
        float ff1 = sigf(acc[1][1]);

        acc[2] = __builtin_amdgcn_mfma_f32_16x16x32_f16(ah0, bf[2][0], acc[2], 0, 0, 0);
        acc[2] = __builtin_amdgcn_mfma_f32_16x16x32_f16(ah1, bf[2][1], acc[2], 0, 0, 0);
        acc[2] = __builtin_amdgcn_mfma_f32_16x16x32_f16(ah2, bf[2][2], acc[2], 0, 0, 0);
        acc[2] = __builtin_amdgcn_mfma_f32_16x16x32_f16(ah3, bf[2][3], acc[2], 0, 0, 0);
        float gg0 = tnhf(acc[2][0]);
        float gg1 = tnhf(acc[2][1]);

        acc[3] = __builtin_amdgcn_mfma_f32_16x16x32_f16(ah0, bf[3][0], acc[3], 0, 0, 0);
        acc[3] = __builtin_amdgcn_mfma_f32_16x16x32_f16(ah1, bf[3][1], acc[3], 0, 0, 0);
        acc[3] = __builtin_amdgcn_mfma_f32_16x16x32_f16(ah2, bf[3][2], acc[3], 0, 0, 0);
        acc[3] = __builtin_amdgcn_mfma_f32_16x16x32_f16(ah3, bf[3][3], acc[3], 0, 0, 0);
        float oo0 = sigf(acc[3][0]);
        float oo1 = sigf(acc[3][1]);

        // pending = slots 2,3 (bias + xpart(t+1); h-rows 2,3 were zero)
        #pragma unroll
        for (int nt = 0; nt < 4; ++nt) {
            pend[nt * 2]     = acc[nt][2];
            pend[nt * 2 + 1] = acc[nt][3];
        }

        float cn0 = ff0 * c2[0] + ii0 * gg0;
        c2[0] = cn0;
        float hn0 = oo0 * tnhf(cn0);
        h2[0] = hn0;
        *reinterpret_cast<_Float16*>(wh1 + wr0) = (_Float16)hn0;

        float cn1 = ff1 * c2[1] + ii1 * gg1;
        c2[1] = cn1;
        float hn1 = oo1 * tnhf(cn1);
        h2[1] = hn1;
        *reinterpret_cast<_Float16*>(wh1 + wr1) = (_Float16)hn1;

        // stage next pair's x into the other x-buffer
        if (st) {
            h4v pk = {(_Float16)nxt.x, (_Float16)nxt.y, (_Float16)nxt.z, (_Float16)nxt.w};
            *reinterpret_cast<h4v*>(wx + wofs_x) = pk;
        }
        lgkm_barrier();

        // ================= ODD step t = 2tp+1 =================
        #pragma unroll
        for (int nt = 0; nt < 4; ++nt)
            acc[nt] = (f4v){pend[nt * 2], pend[nt * 2 + 1], 0.f, 0.f};

        const char* rh1 = reinterpret_cast<const char*>(ht[1]);
        char*       wh0 = reinterpret_cast<char*>(ht[0]);
        h8v bh0 = *reinterpret_cast<const h8v*>(rh1 + arow + (0 * 64 + g4 * 16));
        h8v bh1 = *reinterpret_cast<const h8v*>(rh1 + arow + (1 * 64 + g4 * 16));
        h8v bh2 = *reinterpret_cast<const h8v*>(rh1 + arow + (2 * 64 + g4 * 16));
        h8v bh3 = *reinterpret_cast<const h8v*>(rh1 + arow + (3 * 64 + g4 * 16));

        acc[0] = __builtin_amdgcn_mfma_f32_16x16x32_f16(bh0, bf[0][0], acc[0], 0, 0, 0);
        acc[0] = __builtin_amdgcn_mfma_f32_16x16x32_f16(bh1, bf[0][1], acc[0], 0, 0, 0);
        acc[0] = __builtin_amdgcn_mfma_f32_16x16x32_f16(bh2, bf[0][2], acc[0], 0, 0, 0);
        acc[0] = __builtin_amdgcn_mfma_f32_16x16x32_f16(bh3, bf[0][3], acc[0], 0, 0, 0);
        float jj0 = sigf(acc[0][0]);
        float jj1 = sigf(acc[0][1]);

        acc[1] = __builtin_amdgcn_mfma_f32_16x16x32_f16(bh0, bf[1][0], acc[1], 0, 0, 0);
        acc[1] = __builtin_amdgcn_mfma_f32_16x16x32_f16(bh1, bf[1][1], acc[1], 0, 0, 0);
        acc[1] = __builtin_amdgcn_mfma_f32_16x16x32_f16(bh2, bf[1][2], acc[1], 0, 0, 0);
        acc[1] = __builtin_amdgcn_mfma_f32_16x16x32_f16(bh3, bf[1][3], acc[1], 0, 0, 0);
        float kk0 = sigf(acc[1][0]);
        float kk1 = sigf(acc[1][1]);

        acc[2] = __builtin_amdgcn_mfma_f32_16x16x32_f16(bh0, bf[2][0], acc[2], 0, 0, 0);
        acc[2] = __builtin_amdgcn_mfma_f32_16x16x32_f16(bh1, bf[2][1], acc[2], 0, 0, 0);
        acc[2] = __builtin_amdgcn_mfma_f32_16x16x32_f16(bh2, bf[2][2], acc[2], 0, 0, 0);
        acc[2] = __builtin_amdgcn_mfma_f32_16x16x32_f16(bh3, bf[2][3], acc[2], 0, 0, 0);
        float ll0 = tnhf(acc[2][0]);
        float ll1 = tnhf(acc[2][1]);

        acc[3] = __builtin_amdgcn_mfma_f32_16x16x32_f16(bh0, bf[3][0], acc[3], 0, 0, 0);
        acc[3] = __builtin_amdgcn_mfma_f32_16x16x32_f16(bh1, bf[3][1], acc[3], 0, 0, 0);
        acc[3] = __builtin_amdgcn_mfma_f32_16x16x32_f16(bh2, bf[3][2], acc[3], 0, 0, 0);
        acc[3] = __builtin_amdgcn_mfma_f32_16x16x32_f16(bh3, bf[3][3], acc[3], 0, 0, 0);
        float mm0 = sigf(acc[3][0]);
        float mm1 = sigf(acc[3][1]);

        float dn0 = kk0 * c2[0] + jj0 * ll0;
        c2[0] = dn0;
        float gn0 = mm0 * tnhf(dn0);
        h2[0] = gn0;
        *reinterpret_cast<_Float16*>(wh0 + wr0) = (_Float16)gn0;

        float dn1 = kk1 * c2[1] + jj1 * ll1;
        c2[1] = dn1;
        float gn1 = mm1 * tnhf(dn1);
        h2[1] = gn1;
        *reinterpret_cast<_Float16*>(wh0 + wr1) = (_Float16)gn1;

        lgkm_barrier();
    }

    #pragma unroll
    for (int q = 0; q < 2; ++q) {
        int b = bq * 16 + hi * 8 + (g4 & 1) * 4 + (g4 >> 1) * 2 + q;
        hf[((size_t)b * NN + n) * HID + j] = h2[q];
    }
}

// Head: 64 blocks (one per batch row), 256 thr, split-K over 2 halves.
__global__ __launch_bounds__(256) void head2_kernel(
        const float* __restrict__ hf, const float* __restrict__ w1t,
        const float* __restrict__ b1, const float* __restrict__ W2,
        const float* __restrict__ b2, float* __restrict__ out) {
    __shared__ float comb[FEAT];
    __shared__ float par[2][HID];
    __shared__ float hid[HID];
    const int b = blockIdx.x;
    const int u  = threadIdx.x & 127;
    const int kk = threadIdx.x >> 7;
    const float* hfp = hf + (size_t)b * FEAT;
    for (int i = threadIdx.x; i < FEAT; i += 256) comb[i] = hfp[i];
    __syncthreads();

    const int k0 = kk * (FEAT / 2);
    float acc = 0.f;
    #pragma unroll 8
    for (int k = 0; k < FEAT / 2; ++k)
        acc = fmaf(comb[k0 + k], w1t[(size_t)(k0 + k) * HID + u], acc);
    par[kk][u] = acc;
    __syncthreads();
    if (kk == 0) hid[u] = fmaxf(par[0][u] + par[1][u] + b1[u], 0.f);
    __syncthreads();

    if (threadIdx.x < NC) {
        int cls = threadIdx.x;
        float a = b2[cls];
        #pragma unroll 4
        for (int k = 0; k < HID; ++k)
            a = fmaf(hid[k], W2[cls * HID + k], a);
        out[b * NC + cls] = a;
    }
}

// ======================= fallback (round-3) =======================
__global__ __launch_bounds__(256) void packfb_kernel(
        const float* __restrict__ W_ih, const float* __restrict__ W_hh,
        const float* __restrict__ W1,
        unsigned short* __restrict__ bfw, float* __restrict__ w1t) {
    int id = blockIdx.x * 256 + threadIdx.x;
    if (id < SZ_BF) {
        int e    = id & 7;
        int lane = (id >> 3) & 63;
        int kt   = (id >> 9) & 7;
        int nt   = (id >> 12) & 3;
        int hb   = (id >> 14) & 7;
        int n    = id >> 17;
        int k = kt * 32 + (lane >> 4) * 8 + e;
        int g = nt * 128 + hb * 16 + (lane & 15);
        float v = 0.f;
        if (k < DIN)       v = W_ih[((size_t)n * 512 + g) * DIN + k];
        else if (k < 228)  v = W_hh[((size_t)n * 512 + g) * HID + (k - DIN)];
        bfw[id] = f2bf(v);
        return;
    }
    int id3 = id - SZ_BF;
    if (id3 < SZ_W1T) {
        int j = id3 & 127, k = id3 >> 7;
        w1t[id3] = W1[(size_t)j * FEAT + k];
    }
}

__global__ __launch_bounds__(512, 2) void lstmfb_kernel(
        const float* __restrict__ inp,
        const float* __restrict__ b_ih, const float* __restrict__ b_hh,
        const unsigned short* __restrict__ bfw, float* __restrict__ hf) {
    __shared__ alignas(16) unsigned short xh[2][16 * 256];
    const int tid  = threadIdx.x;
    const int lane = tid & 63;
    const int w    = tid >> 6;
    const int l15  = lane & 15;
    const int g4   = lane >> 4;
    const int n    = blockIdx.x >> 2;
    const int bq   = blockIdx.x & 3;
    const int j    = w * 16 + l15;

    s8v bf[4][8];
    const unsigned short* wp = bfw + ((size_t)(n * 8 + w) * 32) * 512 + lane * 8;
    #pragma unroll
    for (int nt = 0; nt < 4; ++nt)
        #pragma unroll
        for (int kt = 0; kt < 8; ++kt)
            bf[nt][kt] = *reinterpret_cast<const s8v*>(wp + (nt * 8 + kt) * 512);

    float bs[4];
    #pragma unroll
    for (int nt = 0; nt < 4; ++nt)
        bs[nt] = b_ih[n * 512 + nt * 128 + j] + b_hh[n * 512 + nt * 128 + j];

    float c[4] = {0.f, 0.f, 0.f, 0.f};
    float h[4] = {0.f, 0.f, 0.f, 0.f};
    for (int i = tid; i < 2 * 16 * 256; i += 512) (&xh[0][0])[i] = 0;

    const bool st = tid < 400;
    const int row = st ? tid / 25 : 0;
    const int c4  = st ? tid - row * 25 : 0;
    const float* xb = inp + ((size_t)(bq * 16 + row) * NN + n) * (TT * DIN) + c4 * 4;
    const int wofs = row * 512 + ((c4 * 8) ^ ((row & 7) << 4));
    const int arow = l15 * 512;
    const int aswz = (l15 & 7) << 4;

    __syncthreads();
    if (st) {
        float4 v = *reinterpret_cast<const float4*>(xb);
        unsigned lo = f2bf(v.x) | ((unsigned)f2bf(v.y) << 16);
        unsigned hi = f2bf(v.z) | ((unsigned)f2bf(v.w) << 16);
        *reinterpret_cast<uint2*>(reinterpret_cast<char*>(xh[0]) + wofs) =
            make_uint2(lo, hi);
    }
    __syncthreads();

    for (int t = 0; t < TT; ++t) {
        char* rc = reinterpret_cast<char*>(xh[t & 1]);
        char* wc = reinterpret_cast<char*>(xh[(t + 1) & 1]);
        float4 nxt = make_float4(0.f, 0.f, 0.f, 0.f);
        if (t < TT - 1 && st)
            nxt = *reinterpret_cast<const float4*>(xb + (t + 1) * DIN);

        f4v acc[4];
        #pragma unroll
        for (int nt = 0; nt < 4; ++nt)
            acc[nt] = (f4v){bs[nt], bs[nt], bs[nt], bs[nt]};
        #pragma unroll
        for (int kt = 0; kt < 8; ++kt) {
            s8v a = *reinterpret_cast<const s8v*>(rc + arow + ((kt * 64 + g4 * 16) ^ aswz));
            #pragma unroll
            for (int nt = 0; nt < 4; ++nt)
                acc[nt] = __builtin_amdgcn_mfma_f32_16x16x32_bf16(a, bf[nt][kt], acc[nt], 0, 0, 0);
        }
        #pragma unroll
        for (int r = 0; r < 4; ++r) {
            float ii = sigf(acc[0][r]);
            float ff = sigf(acc[1][r]);
            float gg = tnhf(acc[2][r]);
            float oo = sigf(acc[3][r]);
            float cn = ff * c[r] + ii * gg;
            c[r] = cn;
            float hn = oo * tnhf(cn);
            h[r] = hn;
            int rr = g4 * 4 + r;
            *reinterpret_cast<unsigned short*>(
                wc + rr * 512 + (((DIN + j) * 2) ^ ((rr & 7) << 4))) = f2bf(hn);
        }
        if (t < TT - 1 && st) {
            unsigned lo = f2bf(nxt.x) | ((unsigned)f2bf(nxt.y) << 16);
            unsigned hi = f2bf(nxt.z) | ((unsigned)f2bf(nxt.w) << 16);
            *reinterpret_cast<uint2*>(wc + wofs) = make_uint2(lo, hi);
        }
        __syncthreads();
    }
    #pragma unroll
    for (int r = 0; r < 4; ++r) {
        int b = bq * 16 + g4 * 4 + r;
        hf[((size_t)b * NN + n) * HID + j] = h[r];
    }
}

// ============================ launch ==============================
extern "C" void kernel_launch(void* const* d_in, const int* in_sizes, int n_in,
                              void* d_out, int out_size, void* d_ws, size_t ws_size,
                              hipStream_t stream) {
    const float* inp  = (const float*)d_in[0];
    const float* W_ih = (const float*)d_in[2];
    const float* W_hh = (const float*)d_in[3];
    const float* b_ih = (const float*)d_in[4];
    const float* b_hh = (const float*)d_in[5];
    const float* W1   = (const float*)d_in[6];
    const float* b1   = (const float*)d_in[7];
    const float* W2   = (const float*)d_in[8];
    const float* b2   = (const float*)d_in[9];
    float* out = (float*)d_out;

    if (ws_size >= V2_NEED) {
        char* wsb = (char*)d_ws;
        float* hf  = (float*)(wsb + V2_OFF_HF);
        float* w1t = (float*)(wsb + V2_OFF_W1T);
        pack2_kernel<<<(PACK2_TOTAL + 255) / 256, 256, 0, stream>>>(
            W_ih, W_hh, b_ih, b_hh, W1, wsb);
        lstm9p_kernel<<<NN * 8, 512, 0, stream>>>(wsb, inp, hf);
        head2_kernel<<<BB, 256, 0, stream>>>(hf, w1t, b1, W2, b2, out);
    } else {
        float* ws = (float*)d_ws;
        unsigned short* bfw = (unsigned short*)d_ws;
        packfb_kernel<<<(PACK_TOTAL_O + 255) / 256, 256, 0, stream>>>(
            W_ih, W_hh, W1, bfw, ws + OFF_W1T_O);
        lstmfb_kernel<<<NN * 4, 512, 0, stream>>>(inp, b_ih, b_hh, bfw, ws + OFF_HF_O);
        head2_kernel<<<BB, 256, 0, stream>>>(ws + OFF_HF_O, ws + OFF_W1T_O,
                                             b1, W2, b2, out);
    }
}

// Round 19
// 268.892 us; speedup vs baseline: 1.6024x; 1.0331x over previous
//
#include <hip/hip_runtime.h>
#include <hip/hip_bf16.h>

#define NN   19
#define DIN  100
#define HID  128
#define TT   250
#define BB   64
#define NC   4
#define FEAT 2432          // NN*HID

typedef __attribute__((ext_vector_type(8))) short s8v;
typedef __attribute__((ext_vector_type(4))) float f4v;
typedef _Float16 h8v __attribute__((ext_vector_type(8)));
typedef _Float16 h4v __attribute__((ext_vector_type(4)));
typedef unsigned int u4v __attribute__((ext_vector_type(4)));

// =============== V2 workspace layout (byte offsets) ===============
#define BFI_USH   1245184
#define V2_OFF_BFI  0ull
#define V2_OFF_BFH  2490368ull
#define V2_OFF_BIAS 4980736ull
#define V2_OFF_W1T  5019648ull
#define V2_OFF_HF   6264832ull
#define V2_NEED     6887424ull
#define PACK2_TOTAL (2*BFI_USH + 19*512 + FEAT*HID)

// =============== fallback (round-3) layout, float offsets =========
#define SZ_BF   (NN*8*4*8*512)
#define OFF_W1T_O (SZ_BF/2)
#define SZ_W1T  (FEAT*HID)
#define OFF_HF_O  (OFF_W1T_O + SZ_W1T)
#define PACK_TOTAL_O (SZ_BF + SZ_W1T)

// tile row stride: 136 f16 = 272 B = 68 words == 4 (mod 32 banks)
#define XSTR 272

__device__ __forceinline__ unsigned short f2bf(float x) {
    union { float f; unsigned u; } v; v.f = x;
    unsigned r = v.u + 0x7FFF + ((v.u >> 16) & 1);   // RNE
    return (unsigned short)(r >> 16);
}
#define LOG2E 1.4426950408889634f
__device__ __forceinline__ float sigf(float x) {
    return __builtin_amdgcn_rcpf(1.f + __builtin_amdgcn_exp2f(-LOG2E * x));
}
__device__ __forceinline__ float tnhf(float x) {
    return 1.f - 2.f * __builtin_amdgcn_rcpf(__builtin_amdgcn_exp2f(2.f * LOG2E * x) + 1.f);
}

// Pin a fragment in VGPRs (prevents rematerialize-by-reload).
__device__ __forceinline__ void pin8(h8v& v) {
    u4v u = __builtin_bit_cast(u4v, v);
    asm volatile("" : "+v"(u));
    v = __builtin_bit_cast(h8v, u);
}

// lgkm-only barrier: LDS ordered; global loads/stores stay in flight.
__device__ __forceinline__ void lgkm_barrier() {
    asm volatile("s_waitcnt lgkmcnt(0)" ::: "memory");
    __builtin_amdgcn_s_barrier();
    asm volatile("" ::: "memory");
}

// ======================= V2 kernels ===============================

// Pack W_ih frags, W_hh frags (f16), combined bias, W1T.
__global__ __launch_bounds__(256) void pack2_kernel(
        const float* __restrict__ W_ih, const float* __restrict__ W_hh,
        const float* __restrict__ b_ih, const float* __restrict__ b_hh,
        const float* __restrict__ W1, char* __restrict__ wsb) {
    int id = blockIdx.x * 256 + threadIdx.x;
    if (id < 2 * BFI_USH) {
        int which = id >= BFI_USH;                 // 0 = W_ih, 1 = W_hh
        int i = which ? id - BFI_USH : id;
        int e    = i & 7;
        int lane = (i >> 3) & 63;
        int kt   = (i >> 9) & 3;
        int nt   = (i >> 11) & 3;
        int hb   = (i >> 13) & 7;
        int n    = i >> 16;
        int k = kt * 32 + (lane >> 4) * 8 + e;
        int g = nt * 128 + hb * 16 + (lane & 15);
        float v;
        if (which) v = W_hh[((size_t)n * 512 + g) * HID + k];
        else       v = (k < DIN) ? W_ih[((size_t)n * 512 + g) * DIN + k] : 0.f;
        reinterpret_cast<_Float16*>(wsb)[id] = (_Float16)v;
        return;
    }
    int id2 = id - 2 * BFI_USH;
    if (id2 < NN * 512) {
        reinterpret_cast<float*>(wsb + V2_OFF_BIAS)[id2] = b_ih[id2] + b_hh[id2];
        return;
    }
    int id3 = id2 - NN * 512;
    if (id3 < FEAT * HID) {
        int j = id3 & 127, k = id3 >> 7;
        reinterpret_cast<float*>(wsb + V2_OFF_W1T)[id3] = W1[(size_t)j * FEAT + k];
    }
}

// Fused recurrence v14: pair-step with IN-PLACE odd accumulation and
// cross-barrier x-frag prefetch.
//  - ht[0]: h for EVEN reads at rows g4*4+{0,1} (written by odd steps);
//    rows {2,3} stay zero.  ht[1]: h for ODD reads at rows g4*4+{2,3}
//    (written by even steps); rows {0,1} stay zero.
//  - EVEN step t=2tp: acc=bias(all slots); 16 x-MFMA on REGISTER x-frags
//    (slots 0,1 <- xpart(t), slots 2,3 <- xpart(t+1)); 16 h-MFMA on ht[0]
//    (slots 2,3 += 0); nonlin slots {0,1}; h(t+1) -> ht[1] rows {2,3}.
//  - ODD step: 4 ds_read of NEXT pair's x-frags (xt buffer completed
//    before the even->odd barrier) + 16 h-MFMA continuing the SAME acc
//    (slots 2,3 live; slots 0,1 stale-dead); nonlin slots {2,3};
//    h(t+2) -> ht[0] rows {0,1}.
// Bitwise-identical: per-gate op sequence (bias + 4 x-MFMA + 4 h-MFMA)
// unchanged; zero rows add exact 0; stale slots never read.
__global__ __launch_bounds__(512, 2) void lstm10p_kernel(
        const char* __restrict__ wsb, const float* __restrict__ inp,
        float* __restrict__ hf) {
    __shared__ alignas(16) _Float16 xt[2][16 * 136];   // 2 x 4.25 KB
    __shared__ alignas(16) _Float16 ht[2][16 * 136];   // 2 x 4.25 KB

    const int tid  = threadIdx.x;
    const int lane = tid & 63;
    const int w8   = tid >> 6;
    const int l15  = lane & 15;
    const int g4   = lane >> 4;
    const int n    = blockIdx.x >> 3;
    const int oct  = blockIdx.x & 7;
    const int bq   = oct >> 1;
    const int hi   = oct & 1;
    const int hb   = w8;
    const int j    = hb * 16 + l15;

    // W_hh + W_ih frags, pinned (32 h8v = 128 regs)
    h8v bf[4][4], bfx[4][4];
    {
        const _Float16* wph = reinterpret_cast<const _Float16*>(wsb + V2_OFF_BFH)
                              + (size_t)lane * 8;
        const _Float16* wpx = reinterpret_cast<const _Float16*>(wsb + V2_OFF_BFI)
                              + (size_t)lane * 8;
        #pragma unroll
        for (int nt = 0; nt < 4; ++nt)
            #pragma unroll
            for (int kt = 0; kt < 4; ++kt) {
                size_t off = ((size_t)((n * 8 + hb) * 16 + nt * 4 + kt)) * 512;
                bf[nt][kt]  = *reinterpret_cast<const h8v*>(wph + off);
                bfx[nt][kt] = *reinterpret_cast<const h8v*>(wpx + off);
            }
        #pragma unroll
        for (int nt = 0; nt < 4; ++nt)
            #pragma unroll
            for (int kt = 0; kt < 4; ++kt) {
                pin8(bf[nt][kt]);
                pin8(bfx[nt][kt]);
            }
    }
    float bs[4];
    #pragma unroll
    for (int nt = 0; nt < 4; ++nt)
        bs[nt] = reinterpret_cast<const float*>(wsb + V2_OFF_BIAS)[n * 512 + nt * 128 + j];

    // zero all tiles (x cols >=100, ht[0] rows {2,3}, ht[1] rows {0,1})
    for (int i = tid; i < 16 * 136; i += 512) {
        xt[0][i] = (_Float16)0.f; xt[1][i] = (_Float16)0.f;
        ht[0][i] = (_Float16)0.f; ht[1][i] = (_Float16)0.f;
    }

    // x staging: 400 threads cover 16 tile rows x 25 float4 per PAIR.
    const bool st = tid < 400;
    const int sr  = st ? tid / 25 : 0;
    const int d4  = st ? tid - sr * 25 : 0;
    const int g4s = sr >> 2, qs = sr & 3;
    const int tpo = qs >> 1;                               // 0 even, 1 odd
    const int Rr  = (g4s & 1) * 4 + (g4s >> 1) * 2 + (qs & 1);
    const float* xbp = inp + (size_t)((bq * 16 + hi * 8 + Rr) * NN + n) * (TT * DIN)
                       + d4 * 4;
    const int wofs_x = sr * XSTR + d4 * 8;

    const int arow = l15 * XSTR;
    // even writes h(t+1) -> ht[1] rows g4*4+{2,3}; odd writes -> ht[0] {0,1}
    const int wrE0 = (g4 * 4 + 2) * XSTR + 2 * j;
    const int wrE1 = (g4 * 4 + 3) * XSTR + 2 * j;
    const int wrO0 = (g4 * 4) * XSTR + 2 * j;
    const int wrO1 = (g4 * 4 + 1) * XSTR + 2 * j;

    float c2[2] = {0.f, 0.f};
    float h2[2] = {0.f, 0.f};

    __syncthreads();
    if (st) {   // prologue: stage x(0),x(1) into xt[0]
        float4 v = *reinterpret_cast<const float4*>(xbp + (size_t)tpo * DIN);
        h4v pk = {(_Float16)v.x, (_Float16)v.y, (_Float16)v.z, (_Float16)v.w};
        *reinterpret_cast<h4v*>(reinterpret_cast<char*>(xt[0]) + wofs_x) = pk;
    }
    __syncthreads();

    // preload pair-0 x-frags into registers
    h8v xf0, xf1, xf2, xf3;
    {
        const char* rx = reinterpret_cast<const char*>(xt[0]);
        xf0 = *reinterpret_cast<const h8v*>(rx + arow + (0 * 64 + g4 * 16));
        xf1 = *reinterpret_cast<const h8v*>(rx + arow + (1 * 64 + g4 * 16));
        xf2 = *reinterpret_cast<const h8v*>(rx + arow + (2 * 64 + g4 * 16));
        xf3 = *reinterpret_cast<const h8v*>(rx + arow + (3 * 64 + g4 * 16));
    }
    lgkm_barrier();

    for (int tp = 0; tp < 125; ++tp) {
        char* wx = reinterpret_cast<char*>(xt[(tp + 1) & 1]);

        // prefetch next pair's x slice from global (in flight across barriers)
        float4 nxt = make_float4(0.f, 0.f, 0.f, 0.f);
        if (st) {
            int tl = 2 * tp + 2 + tpo;
            if (tl > 249) tl = 249;
            nxt = *reinterpret_cast<const float4*>(xbp + (size_t)tl * DIN);
        }

        // ================= EVEN step t = 2tp =================
        f4v acc[4];
        #pragma unroll
        for (int nt = 0; nt < 4; ++nt)
            acc[nt] = (f4v){bs[nt], bs[nt], bs[nt], bs[nt]};

        // x-MFMA on register frags (no LDS on this path)
        #pragma unroll
        for (int nt = 0; nt < 4; ++nt) {
            acc[nt] = __builtin_amdgcn_mfma_f32_16x16x32_f16(xf0, bfx[nt][0], acc[nt], 0, 0, 0);
            acc[nt] = __builtin_amdgcn_mfma_f32_16x16x32_f16(xf1, bfx[nt][1], acc[nt], 0, 0, 0);
            acc[nt] = __builtin_amdgcn_mfma_f32_16x16x32_f16(xf2, bfx[nt][2], acc[nt], 0, 0, 0);
            acc[nt] = __builtin_amdgcn_mfma_f32_16x16x32_f16(xf3, bfx[nt][3], acc[nt], 0, 0, 0);
        }

        const char* rh0 = reinterpret_cast<const char*>(ht[0]);
        h8v ah0 = *reinterpret_cast<const h8v*>(rh0 + arow + (0 * 64 + g4 * 16));
        h8v ah1 = *reinterpret_cast<const h8v*>(rh0 + arow + (1 * 64 + g4 * 16));
        h8v ah2 = *reinterpret_cast<const h8v*>(rh0 + arow + (2 * 64 + g4 * 16));
        h8v ah3 = *reinterpret_cast<const h8v*>(rh0 + arow + (3 * 64 + g4 * 16));

        acc[0] = __builtin_amdgcn_mfma_f32_16x16x32_f16(ah0, bf[0][0], acc[0], 0, 0, 0);
        acc[0] = __builtin_amdgcn_mfma_f32_16x16x32_f16(ah1, bf[0][1], acc[0], 0, 0, 0);
        acc[0] = __builtin_amdgcn_mfma_f32_16x16x32_f16(ah2, bf[0][2], acc[0], 0, 0, 0);
        acc[0] = __builtin_amdgcn_mfma_f32_16x16x32_f16(ah3, bf[0][3], acc[0], 0, 0, 0);
        float ii0 = sigf(acc[0][0]);
        float ii1 = sigf(acc[0][1]);

        acc[1] = __builtin_amdgcn_mfma_f32_16x16x32_f16(ah0, bf[1][0], acc[1], 0, 0, 0);
        acc[1] = __builtin_amdgcn_mfma_f32_16x16x32_f16(ah1, bf[1][1], acc[1], 0, 0, 0);
        acc[1] = __builtin_amdgcn_mfma_f32_16x16x32_f16(ah2, bf[1][2], acc[1], 0, 0, 0);
        acc[1] = __builtin_amdgcn_mfma_f32_16x16x32_f16(ah3, bf[1][3], acc[1], 0, 0, 0);
        float ff0 = sigf(acc[1][0]);
        float ff1 = sigf(acc[1][1]);

        acc[2] = __builtin_amdgcn_mfma_f32_16x16x32_f16(ah0, bf[2][0], acc[2], 0, 0, 0);
        acc[2] = __builtin_amdgcn_mfma_f32_16x16x32_f16(ah1, bf[2][1], acc[2], 0, 0, 0);
        acc[2] = __builtin_amdgcn_mfma_f32_16x16x32_f16(ah2, bf[2][2], acc[2], 0, 0, 0);
        acc[2] = __builtin_amdgcn_mfma_f32_16x16x32_f16(ah3, bf[2][3], acc[2], 0, 0, 0);
        float gg0 = tnhf(acc[2][0]);
        float gg1 = tnhf(acc[2][1]);

        acc[3] = __builtin_amdgcn_mfma_f32_16x16x32_f16(ah0, bf[3][0], acc[3], 0, 0, 0);
        acc[3] = __builtin_amdgcn_mfma_f32_16x16x32_f16(ah1, bf[3][1], acc[3], 0, 0, 0);
        acc[3] = __builtin_amdgcn_mfma_f32_16x16x32_f16(ah2, bf[3][2], acc[3], 0, 0, 0);
        acc[3] = __builtin_amdgcn_mfma_f32_16x16x32_f16(ah3, bf[3][3], acc[3], 0, 0, 0);
        float oo0 = sigf(acc[3][0]);
        float oo1 = sigf(acc[3][1]);

        char* wh1 = reinterpret_cast<char*>(ht[1]);
        float cn0 = ff0 * c2[0] + ii0 * gg0;
        c2[0] = cn0;
        float hn0 = oo0 * tnhf(cn0);
        h2[0] = hn0;
        *reinterpret_cast<_Float16*>(wh1 + wrE0) = (_Float16)hn0;

        float cn1 = ff1 * c2[1] + ii1 * gg1;
        c2[1] = cn1;
        float hn1 = oo1 * tnhf(cn1);
        h2[1] = hn1;
        *reinterpret_cast<_Float16*>(wh1 + wrE1) = (_Float16)hn1;

        // stage next pair's x into the other x-buffer
        if (st) {
            h4v pk = {(_Float16)nxt.x, (_Float16)nxt.y, (_Float16)nxt.z, (_Float16)nxt.w};
            *reinterpret_cast<h4v*>(wx + wofs_x) = pk;
        }
        lgkm_barrier();

        // ================= ODD step t = 2tp+1 =================
        // prefetch NEXT pair's x-frags (buffer complete since the barrier)
        {
            const char* rxn = reinterpret_cast<const char*>(xt[(tp + 1) & 1]);
            xf0 = *reinterpret_cast<const h8v*>(rxn + arow + (0 * 64 + g4 * 16));
            xf1 = *reinterpret_cast<const h8v*>(rxn + arow + (1 * 64 + g4 * 16));
            xf2 = *reinterpret_cast<const h8v*>(rxn + arow + (2 * 64 + g4 * 16));
            xf3 = *reinterpret_cast<const h8v*>(rxn + arow + (3 * 64 + g4 * 16));
        }

        const char* rh1 = reinterpret_cast<const char*>(ht[1]);
        h8v bh0 = *reinterpret_cast<const h8v*>(rh1 + arow + (0 * 64 + g4 * 16));
        h8v bh1 = *reinterpret_cast<const h8v*>(rh1 + arow + (1 * 64 + g4 * 16));
        h8v bh2 = *reinterpret_cast<const h8v*>(rh1 + arow + (2 * 64 + g4 * 16));
        h8v bh3 = *reinterpret_cast<const h8v*>(rh1 + arow + (3 * 64 + g4 * 16));

        // acc continues in place: slots {2,3} = bias + xpart(t+1);
        // slots {0,1} stale-dead (ht[1] rows {0,1} are zero -> +0)
        acc[0] = __builtin_amdgcn_mfma_f32_16x16x32_f16(bh0, bf[0][0], acc[0], 0, 0, 0);
        acc[0] = __builtin_amdgcn_mfma_f32_16x16x32_f16(bh1, bf[0][1], acc[0], 0, 0, 0);
        acc[0] = __builtin_amdgcn_mfma_f32_16x16x32_f16(bh2, bf[0][2], acc[0], 0, 0, 0);
        acc[0] = __builtin_amdgcn_mfma_f32_16x16x32_f16(bh3, bf[0][3], acc[0], 0, 0, 0);
        float jj0 = sigf(acc[0][2]);
        float jj1 = sigf(acc[0][3]);

        acc[1] = __builtin_amdgcn_mfma_f32_16x16x32_f16(bh0, bf[1][0], acc[1], 0, 0, 0);
        acc[1] = __builtin_amdgcn_mfma_f32_16x16x32_f16(bh1, bf[1][1], acc[1], 0, 0, 0);
        acc[1] = __builtin_amdgcn_mfma_f32_16x16x32_f16(bh2, bf[1][2], acc[1], 0, 0, 0);
        acc[1] = __builtin_amdgcn_mfma_f32_16x16x32_f16(bh3, bf[1][3], acc[1], 0, 0, 0);
        float kk0 = sigf(acc[1][2]);
        float kk1 = sigf(acc[1][3]);

        acc[2] = __builtin_amdgcn_mfma_f32_16x16x32_f16(bh0, bf[2][0], acc[2], 0, 0, 0);
        acc[2] = __builtin_amdgcn_mfma_f32_16x16x32_f16(bh1, bf[2][1], acc[2], 0, 0, 0);
        acc[2] = __builtin_amdgcn_mfma_f32_16x16x32_f16(bh2, bf[2][2], acc[2], 0, 0, 0);
        acc[2] = __builtin_amdgcn_mfma_f32_16x16x32_f16(bh3, bf[2][3], acc[2], 0, 0, 0);
        float ll0 = tnhf(acc[2][2]);
        float ll1 = tnhf(acc[2][3]);

        acc[3] = __builtin_amdgcn_mfma_f32_16x16x32_f16(bh0, bf[3][0], acc[3], 0, 0, 0);
        acc[3] = __builtin_amdgcn_mfma_f32_16x16x32_f16(bh1, bf[3][1], acc[3], 0, 0, 0);
        acc[3] = __builtin_amdgcn_mfma_f32_16x16x32_f16(bh2, bf[3][2], acc[3], 0, 0, 0);
        acc[3] = __builtin_amdgcn_mfma_f32_16x16x32_f16(bh3, bf[3][3], acc[3], 0, 0, 0);
        float mm0 = sigf(acc[3][2]);
        float mm1 = sigf(acc[3][3]);

        char* wh0 = reinterpret_cast<char*>(ht[0]);
        float dn0 = kk0 * c2[0] + jj0 * ll0;
        c2[0] = dn0;
        float gn0 = mm0 * tnhf(dn0);
        h2[0] = gn0;
        *reinterpret_cast<_Float16*>(wh0 + wrO0) = (_Float16)gn0;

        float dn1 = kk1 * c2[1] + jj1 * ll1;
        c2[1] = dn1;
        float gn1 = mm1 * tnhf(dn1);
        h2[1] = gn1;
        *reinterpret_cast<_Float16*>(wh0 + wrO1) = (_Float16)gn1;

        lgkm_barrier();
    }

    #pragma unroll
    for (int q = 0; q < 2; ++q) {
        int b = bq * 16 + hi * 8 + (g4 & 1) * 4 + (g4 >> 1) * 2 + q;
        hf[((size_t)b * NN + n) * HID + j] = h2[q];
    }
}

// Head: 64 blocks (one per batch row), 256 thr, split-K over 2 halves.
__global__ __launch_bounds__(256) void head2_kernel(
        const float* __restrict__ hf, const float* __restrict__ w1t,
        const float* __restrict__ b1, const float* __restrict__ W2,
        const float* __restrict__ b2, float* __restrict__ out) {
    __shared__ float comb[FEAT];
    __shared__ float par[2][HID];
    __shared__ float hid[HID];
    const int b = blockIdx.x;
    const int u  = threadIdx.x & 127;
    const int kk = threadIdx.x >> 7;
    const float* hfp = hf + (size_t)b * FEAT;
    for (int i = threadIdx.x; i < FEAT; i += 256) comb[i] = hfp[i];
    __syncthreads();

    const int k0 = kk * (FEAT / 2);
    float acc = 0.f;
    #pragma unroll 8
    for (int k = 0; k < FEAT / 2; ++k)
        acc = fmaf(comb[k0 + k], w1t[(size_t)(k0 + k) * HID + u], acc);
    par[kk][u] = acc;
    __syncthreads();
    if (kk == 0) hid[u] = fmaxf(par[0][u] + par[1][u] + b1[u], 0.f);
    __syncthreads();

    if (threadIdx.x < NC) {
        int cls = threadIdx.x;
        float a = b2[cls];
        #pragma unroll 4
        for (int k = 0; k < HID; ++k)
            a = fmaf(hid[k], W2[cls * HID + k], a);
        out[b * NC + cls] = a;
    }
}

// ======================= fallback (round-3) =======================
__global__ __launch_bounds__(256) void packfb_kernel(
        const float* __restrict__ W_ih, const float* __restrict__ W_hh,
        const float* __restrict__ W1,
        unsigned short* __restrict__ bfw, float* __restrict__ w1t) {
    int id = blockIdx.x * 256 + threadIdx.x;
    if (id < SZ_BF) {
        int e    = id & 7;
        int lane = (id >> 3) & 63;
        int kt   = (id >> 9) & 7;
        int nt   = (id >> 12) & 3;
        int hb   = (id >> 14) & 7;
        int n    = id >> 17;
        int k = kt * 32 + (lane >> 4) * 8 + e;
        int g = nt * 128 + hb * 16 + (lane & 15);
        float v = 0.f;
        if (k < DIN)       v = W_ih[((size_t)n * 512 + g) * DIN + k];
        else if (k < 228)  v = W_hh[((size_t)n * 512 + g) * HID + (k - DIN)];
        bfw[id] = f2bf(v);
        return;
    }
    int id3 = id - SZ_BF;
    if (id3 < SZ_W1T) {
        int j = id3 & 127, k = id3 >> 7;
        w1t[id3] = W1[(size_t)j * FEAT + k];
    }
}

__global__ __launch_bounds__(512, 2) void lstmfb_kernel(
        const float* __restrict__ inp,
        const float* __restrict__ b_ih, const float* __restrict__ b_hh,
        const unsigned short* __restrict__ bfw, float* __restrict__ hf) {
    __shared__ alignas(16) unsigned short xh[2][16 * 256];
    const int tid  = threadIdx.x;
    const int lane = tid & 63;
    const int w    = tid >> 6;
    const int l15  = lane & 15;
    const int g4   = lane >> 4;
    const int n    = blockIdx.x >> 2;
    const int bq   = blockIdx.x & 3;
    const int j    = w * 16 + l15;

    s8v bf[4][8];
    const unsigned short* wp = bfw + ((size_t)(n * 8 + w) * 32) * 512 + lane * 8;
    #pragma unroll
    for (int nt = 0; nt < 4; ++nt)
        #pragma unroll
        for (int kt = 0; kt < 8; ++kt)
            bf[nt][kt] = *reinterpret_cast<const s8v*>(wp + (nt * 8 + kt) * 512);

    float bs[4];
    #pragma unroll
    for (int nt = 0; nt < 4; ++nt)
        bs[nt] = b_ih[n * 512 + nt * 128 + j] + b_hh[n * 512 + nt * 128 + j];

    float c[4] = {0.f, 0.f, 0.f, 0.f};
    float h[4] = {0.f, 0.f, 0.f, 0.f};
    for (int i = tid; i < 2 * 16 * 256; i += 512) (&xh[0][0])[i] = 0;

    const bool st = tid < 400;
    const int row = st ? tid / 25 : 0;
    const int c4  = st ? tid - row * 25 : 0;
    const float* xb = inp + ((size_t)(bq * 16 + row) * NN + n) * (TT * DIN) + c4 * 4;
    const int wofs = row * 512 + ((c4 * 8) ^ ((row & 7) << 4));
    const int arow = l15 * 512;
    const int aswz = (l15 & 7) << 4;

    __syncthreads();
    if (st) {
        float4 v = *reinterpret_cast<const float4*>(xb);
        unsigned lo = f2bf(v.x) | ((unsigned)f2bf(v.y) << 16);
        unsigned hi = f2bf(v.z) | ((unsigned)f2bf(v.w) << 16);
        *reinterpret_cast<uint2*>(reinterpret_cast<char*>(xh[0]) + wofs) =
            make_uint2(lo, hi);
    }
    __syncthreads();

    for (int t = 0; t < TT; ++t) {
        char* rc = reinterpret_cast<char*>(xh[t & 1]);
        char* wc = reinterpret_cast<char*>(xh[(t + 1) & 1]);
        float4 nxt = make_float4(0.f, 0.f, 0.f, 0.f);
        if (t < TT - 1 && st)
            nxt = *reinterpret_cast<const float4*>(xb + (t + 1) * DIN);

        f4v acc[4];
        #pragma unroll
        for (int nt = 0; nt < 4; ++nt)
            acc[nt] = (f4v){bs[nt], bs[nt], bs[nt], bs[nt]};
        #pragma unroll
        for (int kt = 0; kt < 8; ++kt) {
            s8v a = *reinterpret_cast<const s8v*>(rc + arow + ((kt * 64 + g4 * 16) ^ aswz));
            #pragma unroll
            for (int nt = 0; nt < 4; ++nt)
                acc[nt] = __builtin_amdgcn_mfma_f32_16x16x32_bf16(a, bf[nt][kt], acc[nt], 0, 0, 0);
        }
        #pragma unroll
        for (int r = 0; r < 4; ++r) {
            float ii = sigf(acc[0][r]);
            float ff = sigf(acc[1][r]);
            float gg = tnhf(acc[2][r]);
            float oo = sigf(acc[3][r]);
            float cn = ff * c[r] + ii * gg;
            c[r] = cn;
            float hn = oo * tnhf(cn);
            h[r] = hn;
            int rr = g4 * 4 + r;
            *reinterpret_cast<unsigned short*>(
                wc + rr * 512 + (((DIN + j) * 2) ^ ((rr & 7) << 4))) = f2bf(hn);
        }
        if (t < TT - 1 && st) {
            unsigned lo = f2bf(nxt.x) | ((unsigned)f2bf(nxt.y) << 16);
            unsigned hi = f2bf(nxt.z) | ((unsigned)f2bf(nxt.w) << 16);
            *reinterpret_cast<uint2*>(wc + wofs) = make_uint2(lo, hi);
        }
        __syncthreads();
    }
    #pragma unroll
    for (int r = 0; r < 4; ++r) {
        int b = bq * 16 + g4 * 4 + r;
        hf[((size_t)b * NN + n) * HID + j] = h[r];
    }
}

// ============================ launch ==============================
extern "C" void kernel_launch(void* const* d_in, const int* in_sizes, int n_in,
                              void* d_out, int out_size, void* d_ws, size_t ws_size,
                              hipStream_t stream) {
    const float* inp  = (const float*)d_in[0];
    const float* W_ih = (const float*)d_in[2];
    const float* W_hh = (const float*)d_in[3];
    const float* b_ih = (const float*)d_in[4];
    const float* b_hh = (const float*)d_in[5];
    const float* W1   = (const float*)d_in[6];
    const float* b1   = (const float*)d_in[7];
    const float* W2   = (const float*)d_in[8];
    const float* b2   = (const float*)d_in[9];
    float* out = (float*)d_out;

    if (ws_size >= V2_NEED) {
        char* wsb = (char*)d_ws;
        float* hf  = (float*)(wsb + V2_OFF_HF);
        float* w1t = (float*)(wsb + V2_OFF_W1T);
        pack2_kernel<<<(PACK2_TOTAL + 255) / 256, 256, 0, stream>>>(
            W_ih, W_hh, b_ih, b_hh, W1, wsb);
        lstm10p_kernel<<<NN * 8, 512, 0, stream>>>(wsb, inp, hf);
        head2_kernel<<<BB, 256, 0, stream>>>(hf, w1t, b1, W2, b2, out);
    } else {
        float* ws = (float*)d_ws;
        unsigned short* bfw = (unsigned short*)d_ws;
        packfb_kernel<<<(PACK_TOTAL_O + 255) / 256, 256, 0, stream>>>(
            W_ih, W_hh, W1, bfw, ws + OFF_W1T_O);
        lstmfb_kernel<<<NN * 4, 512, 0, stream>>>(inp, b_ih, b_hh, bfw, ws + OFF_HF_O);
        head2_kernel<<<BB, 256, 0, stream>>>(ws + OFF_HF_O, ws + OFF_W1T_O,
                                             b1, W2, b2, out);
    }
}

// Round 20
// 267.508 us; speedup vs baseline: 1.6107x; 1.0052x over previous
//
#include <hip/hip_runtime.h>
#include <hip/hip_bf16.h>

#define NN   19
#define DIN  100
#define HID  128
#define TT   250
#define BB   64
#define NC   4
#define FEAT 2432          // NN*HID

typedef __attribute__((ext_vector_type(8))) short s8v;
typedef __attribute__((ext_vector_type(4))) float f4v;
typedef _Float16 h8v __attribute__((ext_vector_type(8)));
typedef _Float16 h4v __attribute__((ext_vector_type(4)));
typedef unsigned int u4v __attribute__((ext_vector_type(4)));

// =============== V2 workspace layout (byte offsets) ===============
#define BFI_USH   1245184
#define V2_OFF_BFI  0ull
#define V2_OFF_BFH  2490368ull
#define V2_OFF_BIAS 4980736ull
#define V2_OFF_W1T  5019648ull
#define V2_OFF_HF   6264832ull
#define V2_NEED     6887424ull
#define PACK2_TOTAL (2*BFI_USH + 19*512 + FEAT*HID)

// =============== fallback (round-3) layout, float offsets =========
#define SZ_BF   (NN*8*4*8*512)
#define OFF_W1T_O (SZ_BF/2)
#define SZ_W1T  (FEAT*HID)
#define OFF_HF_O  (OFF_W1T_O + SZ_W1T)
#define PACK_TOTAL_O (SZ_BF + SZ_W1T)

// tile row stride: 136 f16 = 272 B = 68 words == 4 (mod 32 banks)
#define XSTR 272

__device__ __forceinline__ unsigned short f2bf(float x) {
    union { float f; unsigned u; } v; v.f = x;
    unsigned r = v.u + 0x7FFF + ((v.u >> 16) & 1);   // RNE
    return (unsigned short)(r >> 16);
}
#define LOG2E 1.4426950408889634f
__device__ __forceinline__ float sigf(float x) {
    return __builtin_amdgcn_rcpf(1.f + __builtin_amdgcn_exp2f(-LOG2E * x));
}
__device__ __forceinline__ float tnhf(float x) {
    return 1.f - 2.f * __builtin_amdgcn_rcpf(__builtin_amdgcn_exp2f(2.f * LOG2E * x) + 1.f);
}

// Pin a fragment in VGPRs (prevents rematerialize-by-reload).
__device__ __forceinline__ void pin8(h8v& v) {
    u4v u = __builtin_bit_cast(u4v, v);
    asm volatile("" : "+v"(u));
    v = __builtin_bit_cast(h8v, u);
}

// lgkm-only barrier: LDS ordered; global loads/stores stay in flight.
__device__ __forceinline__ void lgkm_barrier() {
    asm volatile("s_waitcnt lgkmcnt(0)" ::: "memory");
    __builtin_amdgcn_s_barrier();
    asm volatile("" ::: "memory");
}

// ======================= V2 kernels ===============================

// Pack W_ih frags, W_hh frags (f16), combined bias, W1T.
__global__ __launch_bounds__(256) void pack2_kernel(
        const float* __restrict__ W_ih, const float* __restrict__ W_hh,
        const float* __restrict__ b_ih, const float* __restrict__ b_hh,
        const float* __restrict__ W1, char* __restrict__ wsb) {
    int id = blockIdx.x * 256 + threadIdx.x;
    if (id < 2 * BFI_USH) {
        int which = id >= BFI_USH;                 // 0 = W_ih, 1 = W_hh
        int i = which ? id - BFI_USH : id;
        int e    = i & 7;
        int lane = (i >> 3) & 63;
        int kt   = (i >> 9) & 3;
        int nt   = (i >> 11) & 3;
        int hb   = (i >> 13) & 7;
        int n    = i >> 16;
        int k = kt * 32 + (lane >> 4) * 8 + e;
        int g = nt * 128 + hb * 16 + (lane & 15);
        float v;
        if (which) v = W_hh[((size_t)n * 512 + g) * HID + k];
        else       v = (k < DIN) ? W_ih[((size_t)n * 512 + g) * DIN + k] : 0.f;
        reinterpret_cast<_Float16*>(wsb)[id] = (_Float16)v;
        return;
    }
    int id2 = id - 2 * BFI_USH;
    if (id2 < NN * 512) {
        reinterpret_cast<float*>(wsb + V2_OFF_BIAS)[id2] = b_ih[id2] + b_hh[id2];
        return;
    }
    int id3 = id2 - NN * 512;
    if (id3 < FEAT * HID) {
        int j = id3 & 127, k = id3 >> 7;
        reinterpret_cast<float*>(wsb + V2_OFF_W1T)[id3] = W1[(size_t)j * FEAT + k];
    }
}

// Fused recurrence v15 = v14 (pair-step, in-place odd acc, x-frag
// cross-barrier prefetch) + scheduling micro-opts:
//  - even step's h-frag ds_reads hoisted ABOVE the x-MFMA cluster
//    (LDS latency hides under 16-MFMA issue)
//  - pair loop unrolled 2x (compile-time buffer parity)
//  - dead last-pair staging store skipped
// All arithmetic ops and their order unchanged -> bitwise-identical.
__global__ __launch_bounds__(512, 2) void lstm10q_kernel(
        const char* __restrict__ wsb, const float* __restrict__ inp,
        float* __restrict__ hf) {
    __shared__ alignas(16) _Float16 xt[2][16 * 136];   // 2 x 4.25 KB
    __shared__ alignas(16) _Float16 ht[2][16 * 136];   // 2 x 4.25 KB

    const int tid  = threadIdx.x;
    const int lane = tid & 63;
    const int w8   = tid >> 6;
    const int l15  = lane & 15;
    const int g4   = lane >> 4;
    const int n    = blockIdx.x >> 3;
    const int oct  = blockIdx.x & 7;
    const int bq   = oct >> 1;
    const int hi   = oct & 1;
    const int hb   = w8;
    const int j    = hb * 16 + l15;

    // W_hh + W_ih frags, pinned (32 h8v = 128 regs)
    h8v bf[4][4], bfx[4][4];
    {
        const _Float16* wph = reinterpret_cast<const _Float16*>(wsb + V2_OFF_BFH)
                              + (size_t)lane * 8;
        const _Float16* wpx = reinterpret_cast<const _Float16*>(wsb + V2_OFF_BFI)
                              + (size_t)lane * 8;
        #pragma unroll
        for (int nt = 0; nt < 4; ++nt)
            #pragma unroll
            for (int kt = 0; kt < 4; ++kt) {
                size_t off = ((size_t)((n * 8 + hb) * 16 + nt * 4 + kt)) * 512;
                bf[nt][kt]  = *reinterpret_cast<const h8v*>(wph + off);
                bfx[nt][kt] = *reinterpret_cast<const h8v*>(wpx + off);
            }
        #pragma unroll
        for (int nt = 0; nt < 4; ++nt)
            #pragma unroll
            for (int kt = 0; kt < 4; ++kt) {
                pin8(bf[nt][kt]);
                pin8(bfx[nt][kt]);
            }
    }
    float bs[4];
    #pragma unroll
    for (int nt = 0; nt < 4; ++nt)
        bs[nt] = reinterpret_cast<const float*>(wsb + V2_OFF_BIAS)[n * 512 + nt * 128 + j];

    // zero all tiles (x cols >=100, ht[0] rows {2,3}, ht[1] rows {0,1})
    for (int i = tid; i < 16 * 136; i += 512) {
        xt[0][i] = (_Float16)0.f; xt[1][i] = (_Float16)0.f;
        ht[0][i] = (_Float16)0.f; ht[1][i] = (_Float16)0.f;
    }

    // x staging: 400 threads cover 16 tile rows x 25 float4 per PAIR.
    const bool st = tid < 400;
    const int sr  = st ? tid / 25 : 0;
    const int d4  = st ? tid - sr * 25 : 0;
    const int g4s = sr >> 2, qs = sr & 3;
    const int tpo = qs >> 1;                               // 0 even, 1 odd
    const int Rr  = (g4s & 1) * 4 + (g4s >> 1) * 2 + (qs & 1);
    const float* xbp = inp + (size_t)((bq * 16 + hi * 8 + Rr) * NN + n) * (TT * DIN)
                       + d4 * 4;
    const int wofs_x = sr * XSTR + d4 * 8;

    const int arow = l15 * XSTR;
    // even writes h(t+1) -> ht[1] rows g4*4+{2,3}; odd writes -> ht[0] {0,1}
    const int wrE0 = (g4 * 4 + 2) * XSTR + 2 * j;
    const int wrE1 = (g4 * 4 + 3) * XSTR + 2 * j;
    const int wrO0 = (g4 * 4) * XSTR + 2 * j;
    const int wrO1 = (g4 * 4 + 1) * XSTR + 2 * j;

    float c2[2] = {0.f, 0.f};
    float h2[2] = {0.f, 0.f};

    __syncthreads();
    if (st) {   // prologue: stage x(0),x(1) into xt[0]
        float4 v = *reinterpret_cast<const float4*>(xbp + (size_t)tpo * DIN);
        h4v pk = {(_Float16)v.x, (_Float16)v.y, (_Float16)v.z, (_Float16)v.w};
        *reinterpret_cast<h4v*>(reinterpret_cast<char*>(xt[0]) + wofs_x) = pk;
    }
    __syncthreads();

    // preload pair-0 x-frags into registers
    h8v xf0, xf1, xf2, xf3;
    {
        const char* rx = reinterpret_cast<const char*>(xt[0]);
        xf0 = *reinterpret_cast<const h8v*>(rx + arow + (0 * 64 + g4 * 16));
        xf1 = *reinterpret_cast<const h8v*>(rx + arow + (1 * 64 + g4 * 16));
        xf2 = *reinterpret_cast<const h8v*>(rx + arow + (2 * 64 + g4 * 16));
        xf3 = *reinterpret_cast<const h8v*>(rx + arow + (3 * 64 + g4 * 16));
    }
    lgkm_barrier();

    #pragma unroll 2
    for (int tp = 0; tp < 125; ++tp) {
        char* wx = reinterpret_cast<char*>(xt[(tp + 1) & 1]);

        // prefetch next pair's x slice from global (in flight across barriers)
        float4 nxt = make_float4(0.f, 0.f, 0.f, 0.f);
        const bool stg = st && (tp < 124);
        if (stg)
            nxt = *reinterpret_cast<const float4*>(xbp + (size_t)(2 * tp + 2 + tpo) * DIN);

        // ================= EVEN step t = 2tp =================
        // h-frag reads issued FIRST: latency hides under the x-MFMA cluster
        const char* rh0 = reinterpret_cast<const char*>(ht[0]);
        h8v ah0 = *reinterpret_cast<const h8v*>(rh0 + arow + (0 * 64 + g4 * 16));
        h8v ah1 = *reinterpret_cast<const h8v*>(rh0 + arow + (1 * 64 + g4 * 16));
        h8v ah2 = *reinterpret_cast<const h8v*>(rh0 + arow + (2 * 64 + g4 * 16));
        h8v ah3 = *reinterpret_cast<const h8v*>(rh0 + arow + (3 * 64 + g4 * 16));

        f4v acc[4];
        #pragma unroll
        for (int nt = 0; nt < 4; ++nt)
            acc[nt] = (f4v){bs[nt], bs[nt], bs[nt], bs[nt]};

        // x-MFMA on register frags (no LDS on this path)
        #pragma unroll
        for (int nt = 0; nt < 4; ++nt) {
            acc[nt] = __builtin_amdgcn_mfma_f32_16x16x32_f16(xf0, bfx[nt][0], acc[nt], 0, 0, 0);
            acc[nt] = __builtin_amdgcn_mfma_f32_16x16x32_f16(xf1, bfx[nt][1], acc[nt], 0, 0, 0);
            acc[nt] = __builtin_amdgcn_mfma_f32_16x16x32_f16(xf2, bfx[nt][2], acc[nt], 0, 0, 0);
            acc[nt] = __builtin_amdgcn_mfma_f32_16x16x32_f16(xf3, bfx[nt][3], acc[nt], 0, 0, 0);
        }

        acc[0] = __builtin_amdgcn_mfma_f32_16x16x32_f16(ah0, bf[0][0], acc[0], 0, 0, 0);
        acc[0] = __builtin_amdgcn_mfma_f32_16x16x32_f16(ah1, bf[0][1], acc[0], 0, 0, 0);
        acc[0] = __builtin_amdgcn_mfma_f32_16x16x32_f16(ah2, bf[0][2], acc[0], 0, 0, 0);
        acc[0] = __builtin_amdgcn_mfma_f32_16x16x32_f16(ah3, bf[0][3], acc[0], 0, 0, 0);
        float ii0 = sigf(acc[0][0]);
        float ii1 = sigf(acc[0][1]);

        acc[1] = __builtin_amdgcn_mfma_f32_16x16x32_f16(ah0, bf[1][0], acc[1], 0, 0, 0);
        acc[1] = __builtin_amdgcn_mfma_f32_16x16x32_f16(ah1, bf[1][1], acc[1], 0, 0, 0);
        acc[1] = __builtin_amdgcn_mfma_f32_16x16x32_f16(ah2, bf[1][2], acc[1], 0, 0, 0);
        acc[1] = __builtin_amdgcn_mfma_f32_16x16x32_f16(ah3, bf[1][3], acc[1], 0, 0, 0);
        float ff0 = sigf(acc[1][0]);
        float ff1 = sigf(acc[1][1]);

        acc[2] = __builtin_amdgcn_mfma_f32_16x16x32_f16(ah0, bf[2][0], acc[2], 0, 0, 0);
        acc[2] = __builtin_amdgcn_mfma_f32_16x16x32_f16(ah1, bf[2][1], acc[2], 0, 0, 0);
        acc[2] = __builtin_amdgcn_mfma_f32_16x16x32_f16(ah2, bf[2][2], acc[2], 0, 0, 0);
        acc[2] = __builtin_amdgcn_mfma_f32_16x16x32_f16(ah3, bf[2][3], acc[2], 0, 0, 0);
        float gg0 = tnhf(acc[2][0]);
        float gg1 = tnhf(acc[2][1]);

        acc[3] = __builtin_amdgcn_mfma_f32_16x16x32_f16(ah0, bf[3][0], acc[3], 0, 0, 0);
        acc[3] = __builtin_amdgcn_mfma_f32_16x16x32_f16(ah1, bf[3][1], acc[3], 0, 0, 0);
        acc[3] = __builtin_amdgcn_mfma_f32_16x16x32_f16(ah2, bf[3][2], acc[3], 0, 0, 0);
        acc[3] = __builtin_amdgcn_mfma_f32_16x16x32_f16(ah3, bf[3][3], acc[3], 0, 0, 0);
        float oo0 = sigf(acc[3][0]);
        float oo1 = sigf(acc[3][1]);

        char* wh1 = reinterpret_cast<char*>(ht[1]);
        float cn0 = ff0 * c2[0] + ii0 * gg0;
        c2[0] = cn0;
        float hn0 = oo0 * tnhf(cn0);
        h2[0] = hn0;
        *reinterpret_cast<_Float16*>(wh1 + wrE0) = (_Float16)hn0;

        float cn1 = ff1 * c2[1] + ii1 * gg1;
        c2[1] = cn1;
        float hn1 = oo1 * tnhf(cn1);
        h2[1] = hn1;
        *reinterpret_cast<_Float16*>(wh1 + wrE1) = (_Float16)hn1;

        // stage next pair's x into the other x-buffer
        if (stg) {
            h4v pk = {(_Float16)nxt.x, (_Float16)nxt.y, (_Float16)nxt.z, (_Float16)nxt.w};
            *reinterpret_cast<h4v*>(wx + wofs_x) = pk;
        }
        lgkm_barrier();

        // ================= ODD step t = 2tp+1 =================
        // prefetch NEXT pair's x-frags (buffer complete since the barrier)
        {
            const char* rxn = reinterpret_cast<const char*>(xt[(tp + 1) & 1]);
            xf0 = *reinterpret_cast<const h8v*>(rxn + arow + (0 * 64 + g4 * 16));
            xf1 = *reinterpret_cast<const h8v*>(rxn + arow + (1 * 64 + g4 * 16));
            xf2 = *reinterpret_cast<const h8v*>(rxn + arow + (2 * 64 + g4 * 16));
            xf3 = *reinterpret_cast<const h8v*>(rxn + arow + (3 * 64 + g4 * 16));
        }

        const char* rh1 = reinterpret_cast<const char*>(ht[1]);
        h8v bh0 = *reinterpret_cast<const h8v*>(rh1 + arow + (0 * 64 + g4 * 16));
        h8v bh1 = *reinterpret_cast<const h8v*>(rh1 + arow + (1 * 64 + g4 * 16));
        h8v bh2 = *reinterpret_cast<const h8v*>(rh1 + arow + (2 * 64 + g4 * 16));
        h8v bh3 = *reinterpret_cast<const h8v*>(rh1 + arow + (3 * 64 + g4 * 16));

        // acc continues in place: slots {2,3} = bias + xpart(t+1);
        // slots {0,1} stale-dead (ht[1] rows {0,1} are zero -> +0)
        acc[0] = __builtin_amdgcn_mfma_f32_16x16x32_f16(bh0, bf[0][0], acc[0], 0, 0, 0);
        acc[0] = __builtin_amdgcn_mfma_f32_16x16x32_f16(bh1, bf[0][1], acc[0], 0, 0, 0);
        acc[0] = __builtin_amdgcn_mfma_f32_16x16x32_f16(bh2, bf[0][2], acc[0], 0, 0, 0);
        acc[0] = __builtin_amdgcn_mfma_f32_16x16x32_f16(bh3, bf[0][3], acc[0], 0, 0, 0);
        float jj0 = sigf(acc[0][2]);
        float jj1 = sigf(acc[0][3]);

        acc[1] = __builtin_amdgcn_mfma_f32_16x16x32_f16(bh0, bf[1][0], acc[1], 0, 0, 0);
        acc[1] = __builtin_amdgcn_mfma_f32_16x16x32_f16(bh1, bf[1][1], acc[1], 0, 0, 0);
        acc[1] = __builtin_amdgcn_mfma_f32_16x16x32_f16(bh2, bf[1][2], acc[1], 0, 0, 0);
        acc[1] = __builtin_amdgcn_mfma_f32_16x16x32_f16(bh3, bf[1][3], acc[1], 0, 0, 0);
        float kk0 = sigf(acc[1][2]);
        float kk1 = sigf(acc[1][3]);

        acc[2] = __builtin_amdgcn_mfma_f32_16x16x32_f16(bh0, bf[2][0], acc[2], 0, 0, 0);
        acc[2] = __builtin_amdgcn_mfma_f32_16x16x32_f16(bh1, bf[2][1], acc[2], 0, 0, 0);
        acc[2] = __builtin_amdgcn_mfma_f32_16x16x32_f16(bh2, bf[2][2], acc[2], 0, 0, 0);
        acc[2] = __builtin_amdgcn_mfma_f32_16x16x32_f16(bh3, bf[2][3], acc[2], 0, 0, 0);
        float ll0 = tnhf(acc[2][2]);
        float ll1 = tnhf(acc[2][3]);

        acc[3] = __builtin_amdgcn_mfma_f32_16x16x32_f16(bh0, bf[3][0], acc[3], 0, 0, 0);
        acc[3] = __builtin_amdgcn_mfma_f32_16x16x32_f16(bh1, bf[3][1], acc[3], 0, 0, 0);
        acc[3] = __builtin_amdgcn_mfma_f32_16x16x32_f16(bh2, bf[3][2], acc[3], 0, 0, 0);
        acc[3] = __builtin_amdgcn_mfma_f32_16x16x32_f16(bh3, bf[3][3], acc[3], 0, 0, 0);
        float mm0 = sigf(acc[3][2]);
        float mm1 = sigf(acc[3][3]);

        char* wh0 = reinterpret_cast<char*>(ht[0]);
        float dn0 = kk0 * c2[0] + jj0 * ll0;
        c2[0] = dn0;
        float gn0 = mm0 * tnhf(dn0);
        h2[0] = gn0;
        *reinterpret_cast<_Float16*>(wh0 + wrO0) = (_Float16)gn0;

        float dn1 = kk1 * c2[1] + jj1 * ll1;
        c2[1] = dn1;
        float gn1 = mm1 * tnhf(dn1);
        h2[1] = gn1;
        *reinterpret_cast<_Float16*>(wh0 + wrO1) = (_Float16)gn1;

        lgkm_barrier();
    }

    #pragma unroll
    for (int q = 0; q < 2; ++q) {
        int b = bq * 16 + hi * 8 + (g4 & 1) * 4 + (g4 >> 1) * 2 + q;
        hf[((size_t)b * NN + n) * HID + j] = h2[q];
    }
}

// Head: 64 blocks (one per batch row), 256 thr, split-K over 2 halves.
__global__ __launch_bounds__(256) void head2_kernel(
        const float* __restrict__ hf, const float* __restrict__ w1t,
        const float* __restrict__ b1, const float* __restrict__ W2,
        const float* __restrict__ b2, float* __restrict__ out) {
    __shared__ float comb[FEAT];
    __shared__ float par[2][HID];
    __shared__ float hid[HID];
    const int b = blockIdx.x;
    const int u  = threadIdx.x & 127;
    const int kk = threadIdx.x >> 7;
    const float* hfp = hf + (size_t)b * FEAT;
    for (int i = threadIdx.x; i < FEAT; i += 256) comb[i] = hfp[i];
    __syncthreads();

    const int k0 = kk * (FEAT / 2);
    float acc = 0.f;
    #pragma unroll 8
    for (int k = 0; k < FEAT / 2; ++k)
        acc = fmaf(comb[k0 + k], w1t[(size_t)(k0 + k) * HID + u], acc);
    par[kk][u] = acc;
    __syncthreads();
    if (kk == 0) hid[u] = fmaxf(par[0][u] + par[1][u] + b1[u], 0.f);
    __syncthreads();

    if (threadIdx.x < NC) {
        int cls = threadIdx.x;
        float a = b2[cls];
        #pragma unroll 4
        for (int k = 0; k < HID; ++k)
            a = fmaf(hid[k], W2[cls * HID + k], a);
        out[b * NC + cls] = a;
    }
}

// ======================= fallback (round-3) =======================
__global__ __launch_bounds__(256) void packfb_kernel(
        const float* __restrict__ W_ih, const float* __restrict__ W_hh,
        const float* __restrict__ W1,
        unsigned short* __restrict__ bfw, float* __restrict__ w1t) {
    int id = blockIdx.x * 256 + threadIdx.x;
    if (id < SZ_BF) {
        int e    = id & 7;
        int lane = (id >> 3) & 63;
        int kt   = (id >> 9) & 7;
        int nt   = (id >> 12) & 3;
        int hb   = (id >> 14) & 7;
        int n    = id >> 17;
        int k = kt * 32 + (lane >> 4) * 8 + e;
        int g = nt * 128 + hb * 16 + (lane & 15);
        float v = 0.f;
        if (k < DIN)       v = W_ih[((size_t)n * 512 + g) * DIN + k];
        else if (k < 228)  v = W_hh[((size_t)n * 512 + g) * HID + (k - DIN)];
        bfw[id] = f2bf(v);
        return;
    }
    int id3 = id - SZ_BF;
    if (id3 < SZ_W1T) {
        int j = id3 & 127, k = id3 >> 7;
        w1t[id3] = W1[(size_t)j * FEAT + k];
    }
}

__global__ __launch_bounds__(512, 2) void lstmfb_kernel(
        const float* __restrict__ inp,
        const float* __restrict__ b_ih, const float* __restrict__ b_hh,
        const unsigned short* __restrict__ bfw, float* __restrict__ hf) {
    __shared__ alignas(16) unsigned short xh[2][16 * 256];
    const int tid  = threadIdx.x;
    const int lane = tid & 63;
    const int w    = tid >> 6;
    const int l15  = lane & 15;
    const int g4   = lane >> 4;
    const int n    = blockIdx.x >> 2;
    const int bq   = blockIdx.x & 3;
    const int j    = w * 16 + l15;

    s8v bf[4][8];
    const unsigned short* wp = bfw + ((size_t)(n * 8 + w) * 32) * 512 + lane * 8;
    #pragma unroll
    for (int nt = 0; nt < 4; ++nt)
        #pragma unroll
        for (int kt = 0; kt < 8; ++kt)
            bf[nt][kt] = *reinterpret_cast<const s8v*>(wp + (nt * 8 + kt) * 512);

    float bs[4];
    #pragma unroll
    for (int nt = 0; nt < 4; ++nt)
        bs[nt] = b_ih[n * 512 + nt * 128 + j] + b_hh[n * 512 + nt * 128 + j];

    float c[4] = {0.f, 0.f, 0.f, 0.f};
    float h[4] = {0.f, 0.f, 0.f, 0.f};
    for (int i = tid; i < 2 * 16 * 256; i += 512) (&xh[0][0])[i] = 0;

    const bool st = tid < 400;
    const int row = st ? tid / 25 : 0;
    const int c4  = st ? tid - row * 25 : 0;
    const float* xb = inp + ((size_t)(bq * 16 + row) * NN + n) * (TT * DIN) + c4 * 4;
    const int wofs = row * 512 + ((c4 * 8) ^ ((row & 7) << 4));
    const int arow = l15 * 512;
    const int aswz = (l15 & 7) << 4;

    __syncthreads();
    if (st) {
        float4 v = *reinterpret_cast<const float4*>(xb);
        unsigned lo = f2bf(v.x) | ((unsigned)f2bf(v.y) << 16);
        unsigned hi = f2bf(v.z) | ((unsigned)f2bf(v.w) << 16);
        *reinterpret_cast<uint2*>(reinterpret_cast<char*>(xh[0]) + wofs) =
            make_uint2(lo, hi);
    }
    __syncthreads();

    for (int t = 0; t < TT; ++t) {
        char* rc = reinterpret_cast<char*>(xh[t & 1]);
        char* wc = reinterpret_cast<char*>(xh[(t + 1) & 1]);
        float4 nxt = make_float4(0.f, 0.f, 0.f, 0.f);
        if (t < TT - 1 && st)
            nxt = *reinterpret_cast<const float4*>(xb + (t + 1) * DIN);

        f4v acc[4];
        #pragma unroll
        for (int nt = 0; nt < 4; ++nt)
            acc[nt] = (f4v){bs[nt], bs[nt], bs[nt], bs[nt]};
        #pragma unroll
        for (int kt = 0; kt < 8; ++kt) {
            s8v a = *reinterpret_cast<const s8v*>(rc + arow + ((kt * 64 + g4 * 16) ^ aswz));
            #pragma unroll
            for (int nt = 0; nt < 4; ++nt)
                acc[nt] = __builtin_amdgcn_mfma_f32_16x16x32_bf16(a, bf[nt][kt], acc[nt], 0, 0, 0);
        }
        #pragma unroll
        for (int r = 0; r < 4; ++r) {
            float ii = sigf(acc[0][r]);
            float ff = sigf(acc[1][r]);
            float gg = tnhf(acc[2][r]);
            float oo = sigf(acc[3][r]);
            float cn = ff * c[r] + ii * gg;
            c[r] = cn;
            float hn = oo * tnhf(cn);
            h[r] = hn;
            int rr = g4 * 4 + r;
            *reinterpret_cast<unsigned short*>(
                wc + rr * 512 + (((DIN + j) * 2) ^ ((rr & 7) << 4))) = f2bf(hn);
        }
        if (t < TT - 1 && st) {
            unsigned lo = f2bf(nxt.x) | ((unsigned)f2bf(nxt.y) << 16);
            unsigned hi = f2bf(nxt.z) | ((unsigned)f2bf(nxt.w) << 16);
            *reinterpret_cast<uint2*>(wc + wofs) = make_uint2(lo, hi);
        }
        __syncthreads();
    }
    #pragma unroll
    for (int r = 0; r < 4; ++r) {
        int b = bq * 16 + g4 * 4 + r;
        hf[((size_t)b * NN + n) * HID + j] = h[r];
    }
}

// ============================ launch ==============================
extern "C" void kernel_launch(void* const* d_in, const int* in_sizes, int n_in,
                              void* d_out, int out_size, void* d_ws, size_t ws_size,
                              hipStream_t stream) {
    const float* inp  = (const float*)d_in[0];
    const float* W_ih = (const float*)d_in[2];
    const float* W_hh = (const float*)d_in[3];
    const float* b_ih = (const float*)d_in[4];
    const float* b_hh = (const float*)d_in[5];
    const float* W1   = (const float*)d_in[6];
    const float* b1   = (const float*)d_in[7];
    const float* W2   = (const float*)d_in[8];
    const float* b2   = (const float*)d_in[9];
    float* out = (float*)d_out;

    if (ws_size >= V2_NEED) {
        char* wsb = (char*)d_ws;
        float* hf  = (float*)(wsb + V2_OFF_HF);
        float* w1t = (float*)(wsb + V2_OFF_W1T);
        pack2_kernel<<<(PACK2_TOTAL + 255) / 256, 256, 0, stream>>>(
            W_ih, W_hh, b_ih, b_hh, W1, wsb);
        lstm10q_kernel<<<NN * 8, 512, 0, stream>>>(wsb, inp, hf);
        head2_kernel<<<BB, 256, 0, stream>>>(hf, w1t, b1, W2, b2, out);
    } else {
        float* ws = (float*)d_ws;
        unsigned short* bfw = (unsigned short*)d_ws;
        packfb_kernel<<<(PACK_TOTAL_O + 255) / 256, 256, 0, stream>>>(
            W_ih, W_hh, W1, bfw, ws + OFF_W1T_O);
        lstmfb_kernel<<<NN * 4, 512, 0, stream>>>(inp, b_ih, b_hh, bfw, ws + OFF_HF_O);
        head2_kernel<<<BB, 256, 0, stream>>>(ws + OFF_HF_O, ws + OFF_W1T_O,
                                             b1, W2, b2, out);
    }
}